// Round 4
// baseline (410.217 us; speedup 1.0000x reference)
//
#include <hip/hip_runtime.h>
#include <hip/hip_bf16.h>

#define AS1 __attribute__((address_space(1)))
#define AS3 __attribute__((address_space(3)))

typedef __bf16 bf16_t;
typedef __attribute__((ext_vector_type(8))) __bf16 bf16x8;
typedef __attribute__((ext_vector_type(4))) float f32x4;

static constexpr int BSZ = 4, SEQ = 2048, HID = 512, PROJ = 4096;
static constexpr long NROW = (long)BSZ * SEQ;  // 8192
static constexpr float SCALE = 0.125f;

__device__ __forceinline__ void gload_lds16(const void* g, void* l) {
  __builtin_amdgcn_global_load_lds((const AS1 void*)g, (AS3 void*)l, 16, 0, 0);
}

// map logical K index -> storage col for 2-wide [h|l] split buffers.
// MAP 0: identity. MAP 1: logical thirds (h,l,h). MAP 2: logical thirds (h,h,l).
template <int MAP>
__device__ __forceinline__ long mapk(long c, int s) {
  if (MAP == 0) return c;
  long w = c & ((1L << s) - 1);
  long t = c >> s;
  bool lo = (MAP == 1) ? (t == 1) : (t == 2);
  return (lo ? (1L << s) : 0) + w;
}

// ------------------------------------------------------------------
// GEMM: C[M,N] = epi(A[M,K] . B[N,K]^T), bf16, row strides lda/ldb,
// z batching (pointer strides sA/sB/sC; logical-K offset kz per z).
// OUTMODE 0: C = (acc + bias[col]) * scale        (OutT f32 or bf16)
// OUTMODE 1: C = exp(acc + ra[z*M+row] + rb[z*N+col]) (bf16) + column
//            partial sums -> part[(by*Z+z)*N + col]
// OUTMODE 2: h/l split write: C[row*2N+col]=h, C[row*2N+N+col]=l
// 128x128 tile, BK=64, 4 waves; LDS XOR swizzle; bijective XCD swizzle.
// ------------------------------------------------------------------
template <typename OutT, int OUTMODE, int AMAP, int BMAP>
__global__ __launch_bounds__(256) void gemm_bt(
    const bf16_t* __restrict__ A, const bf16_t* __restrict__ B,
    OutT* __restrict__ C, const float* __restrict__ bias,
    const float* __restrict__ ra, const float* __restrict__ rb,
    float* __restrict__ part, float scale,
    int M, int N, int K, long lda, long ldb,
    long sA, long sB, long sC, long kz, int sshift)
{
  __shared__ __align__(16) bf16_t As[128 * 64];
  __shared__ __align__(16) bf16_t Bs[128 * 64];
  const int z = blockIdx.z;
  A += (long)z * sA; B += (long)z * sB; C += (long)z * sC;

  // bijective XCD swizzle within the z-plane (m204)
  const int gx = gridDim.x;
  const int nwg = gx * gridDim.y;
  const int id = blockIdx.y * gx + blockIdx.x;
  const int qq = nwg >> 3, rr = nwg & 7;
  const int xcd = id & 7, jj = id >> 3;
  const int swz = (xcd < rr ? xcd * (qq + 1) : rr * (qq + 1) + (xcd - rr) * qq) + jj;
  const int bx = swz % gx, by = swz / gx;

  const int tid  = threadIdx.x;
  const int lane = tid & 63;
  const int wid  = tid >> 6;
  const int wr = (wid >> 1) * 64;
  const int wc = (wid & 1) * 64;
  const long rowBase = (long)by * 128;
  const long colBase = (long)bx * 128;

  f32x4 acc[4][4] = {};

  int srow[4], scol[4];
#pragma unroll
  for (int i = 0; i < 4; ++i) {
    int li = i * 256 + tid;
    int row = li >> 3;
    int inner = (li & 7) << 4;
    int src = inner ^ ((row & 7) << 4);
    srow[i] = row;
    scol[i] = src >> 1;
  }

  for (int k0 = 0; k0 < K; k0 += 64) {
    const long k0L = kz * z + k0;
    const long ka = mapk<AMAP>(k0L, sshift);
    const long kb = mapk<BMAP>(k0L, sshift);
    __syncthreads();
#pragma unroll
    for (int i = 0; i < 4; ++i) {
      int li = i * 256 + tid;
      gload_lds16(A + (rowBase + srow[i]) * lda + ka + scol[i], (char*)As + li * 16);
      gload_lds16(B + (colBase + srow[i]) * ldb + kb + scol[i], (char*)Bs + li * 16);
    }
    __syncthreads();
#pragma unroll
    for (int kk = 0; kk < 64; kk += 32) {
      const int kbyte = (kk + ((lane >> 4) << 3)) << 1;
      bf16x8 af[4], bfr[4];
#pragma unroll
      for (int m = 0; m < 4; ++m) {
        int row = wr + m * 16 + (lane & 15);
        int off = (row << 7) + (kbyte ^ ((row & 7) << 4));
        af[m] = *(const bf16x8*)((const char*)As + off);
      }
#pragma unroll
      for (int n = 0; n < 4; ++n) {
        int row = wc + n * 16 + (lane & 15);
        int off = (row << 7) + (kbyte ^ ((row & 7) << 4));
        bfr[n] = *(const bf16x8*)((const char*)Bs + off);
      }
#pragma unroll
      for (int m = 0; m < 4; ++m)
#pragma unroll
        for (int n = 0; n < 4; ++n)
          acc[m][n] = __builtin_amdgcn_mfma_f32_16x16x32_bf16(af[m], bfr[n], acc[m][n], 0, 0, 0);
    }
  }

  // epilogue; C layout per m89: col=lane&15 (+16n), row=(lane>>4)*4+e (+16m)
  if (OUTMODE == 1) {
    __syncthreads();  // done with As; reuse as colsum staging
    float* csLDS = (float*)As;  // [2][128]
    float ra_[4][4];
#pragma unroll
    for (int m = 0; m < 4; ++m)
#pragma unroll
      for (int e = 0; e < 4; ++e)
        ra_[m][e] = ra[(long)z * M + rowBase + wr + m * 16 + (lane >> 4) * 4 + e];
    float colAcc[4];
#pragma unroll
    for (int n = 0; n < 4; ++n) {
      const long col = colBase + wc + n * 16 + (lane & 15);
      const float rbv_ = rb[(long)z * N + col];
      float cs = 0.f;
#pragma unroll
      for (int m = 0; m < 4; ++m) {
#pragma unroll
        for (int e = 0; e < 4; ++e) {
          const long row = rowBase + wr + m * 16 + (lane >> 4) * 4 + e;
          float v = __expf(acc[m][n][e] + ra_[m][e] + rbv_);
          C[row * (long)N + col] = (OutT)v;
          cs += v;
        }
      }
      cs += __shfl_xor(cs, 16);
      cs += __shfl_xor(cs, 32);
      colAcc[n] = cs;
    }
    if (lane < 16) {
#pragma unroll
      for (int n = 0; n < 4; ++n)
        csLDS[(wid >> 1) * 128 + wc + n * 16 + lane] = colAcc[n];
    }
    __syncthreads();
    if (tid < 128) {
      float t2 = csLDS[tid] + csLDS[128 + tid];
      part[((long)by * gridDim.z + z) * N + colBase + tid] = t2;
    }
  } else if (OUTMODE == 2) {
#pragma unroll
    for (int n = 0; n < 4; ++n) {
      const long col = colBase + wc + n * 16 + (lane & 15);
#pragma unroll
      for (int m = 0; m < 4; ++m) {
#pragma unroll
        for (int e = 0; e < 4; ++e) {
          const long row = rowBase + wr + m * 16 + (lane >> 4) * 4 + e;
          float v = acc[m][n][e] * scale;
          bf16_t h = (bf16_t)v;
          bf16_t l = (bf16_t)(v - (float)h);
          C[row * (2L * N) + col] = (OutT)h;
          C[row * (2L * N) + N + col] = (OutT)l;
        }
      }
    }
  } else {
#pragma unroll
    for (int n = 0; n < 4; ++n) {
      const long col = colBase + wc + n * 16 + (lane & 15);
      const float bv_ = bias ? bias[col] : 0.0f;
#pragma unroll
      for (int m = 0; m < 4; ++m) {
#pragma unroll
        for (int e = 0; e < 4; ++e) {
          const long row = rowBase + wr + m * 16 + (lane >> 4) * 4 + e;
          C[row * (long)N + col] = (OutT)((acc[m][n][e] + bv_) * scale);
        }
      }
    }
  }
}

// f32 [R,C] -> bf16 [R,2C] = (h|l)
__global__ void split2(const float* __restrict__ in, bf16_t* __restrict__ out,
                       long n, int cshift) {
  long C = 1L << cshift;
  for (long i = (long)blockIdx.x * blockDim.x + threadIdx.x; i < n;
       i += (long)gridDim.x * blockDim.x) {
    long r = i >> cshift, c = i & (C - 1);
    float x = in[i];
    bf16_t h = (bf16_t)x;
    bf16_t l = (bf16_t)(x - (float)h);
    bf16_t* o = out + r * 2 * C + c;
    o[0] = h;
    o[C] = l;
  }
}

// f32 [R,C] -> bf16 [C,2R] = (h|l) of the transpose
__global__ void transpose_split2(const float* __restrict__ in, bf16_t* __restrict__ out,
                                 int R, int C) {
  __shared__ float tile[32][33];
  int c0 = blockIdx.x * 32, r0 = blockIdx.y * 32;
  int tx = threadIdx.x & 31, ty = threadIdx.x >> 5;
#pragma unroll
  for (int i = 0; i < 32; i += 8)
    tile[ty + i][tx] = in[(long)(r0 + ty + i) * C + (c0 + tx)];
  __syncthreads();
#pragma unroll
  for (int i = 0; i < 32; i += 8) {
    float x = tile[tx][ty + i];
    bf16_t h = (bf16_t)x;
    bf16_t l = (bf16_t)(x - (float)h);
    long o = (long)(c0 + ty + i) * 2 * R + (r0 + tx);
    out[o] = h;
    out[o + R] = l;
  }
}

// fp32 -> bf16 elementwise
__global__ void cast_f32_bf16(const float* __restrict__ in, bf16_t* __restrict__ out, long n) {
  long i0 = ((long)blockIdx.x * blockDim.x + threadIdx.x) * 4;
  long stride = (long)gridDim.x * blockDim.x * 4;
  for (long i = i0; i < n; i += stride) {
    float4 f = *(const float4*)(in + i);
    union { ushort4 u; bf16_t h[4]; } o;
    o.h[0] = (bf16_t)f.x; o.h[1] = (bf16_t)f.y; o.h[2] = (bf16_t)f.z; o.h[3] = (bf16_t)f.w;
    *(ushort4*)(out + i) = o.u;
  }
}

// Gt = scale*sum_p Gpart[p]; WvoTb = (bf16) sum_p WvoTp[p]
__global__ void reduce2(const float* __restrict__ gp, const float* __restrict__ wp,
                        float* __restrict__ Gt, bf16_t* __restrict__ WvoTb,
                        float scale, int nElem, int nParts) {
  int i = blockIdx.x * 256 + threadIdx.x;
  if (i < nElem) {
    float a = 0.f, b = 0.f;
    for (int p = 0; p < nParts; ++p) {
      a += gp[(long)p * nElem + i];
      b += wp[(long)p * nElem + i];
    }
    Gt[i] = scale * a;
    WvoTb[i] = (bf16_t)b;
  }
}

// rank-1 bias prep: y=0 wqbk=Wq.bk; y=1 wkbq=Wk.bq; y=2 bvo=Wo^T.bv; y=3 cdot=bq.bk
__global__ void rank1(const float* __restrict__ Wq, const float* __restrict__ bk,
                      const float* __restrict__ Wk, const float* __restrict__ bq,
                      const float* __restrict__ Wo, const float* __restrict__ bv,
                      float* __restrict__ wqbk, float* __restrict__ wkbq,
                      float* __restrict__ bvo, float* __restrict__ cdot) {
  __shared__ float red[256];
  int y = blockIdx.y, bx = blockIdx.x, t = threadIdx.x;
  if (y <= 1) {
    const float* M_ = y ? Wk : Wq;
    const float* b_ = y ? bq : bk;
    float s = 0.f;
    for (int j = t; j < PROJ; j += 256) s += M_[(long)bx * PROJ + j] * b_[j];
    red[t] = s; __syncthreads();
    for (int w = 128; w > 0; w >>= 1) {
      if (t < w) red[t] += red[t + w];
      __syncthreads();
    }
    if (t == 0) (y ? wkbq : wqbk)[bx] = red[0];
  } else if (y == 2) {
    if (bx < 2) {
      int d = bx * 256 + t;
      float s = 0.f;
      for (int p = 0; p < PROJ; ++p) s += Wo[(long)p * HID + d] * bv[p];
      bvo[d] = s;
    }
  } else {
    if (bx == 0) {
      float s = 0.f;
      for (int j = t; j < PROJ; j += 256) s += bq[j] * bk[j];
      red[t] = s; __syncthreads();
      for (int w = 128; w > 0; w >>= 1) {
        if (t < w) red[t] += red[t + w];
        __syncthreads();
      }
      if (t == 0) *cdot = red[0];
    }
  }
}

// y=0: rav[r]=SCALE*(q[r].wqbk + cdot); y=1: rbv[r]=SCALE*(k[r].wkbq)
__global__ void rowdot2(const float* __restrict__ q, const float* __restrict__ k,
                        const float* __restrict__ wqbk, const float* __restrict__ wkbq,
                        const float* __restrict__ cdot,
                        float* __restrict__ rav, float* __restrict__ rbv) {
  __shared__ float red[256];
  int r = blockIdx.x, y = blockIdx.y, t = threadIdx.x;
  const float* X = y ? k : q;
  const float* w_ = y ? wkbq : wqbk;
  float s = 0.f;
  for (int j = t; j < HID; j += 256) s += X[(long)r * HID + j] * w_[j];
  red[t] = s; __syncthreads();
  for (int w = 128; w > 0; w >>= 1) {
    if (t < w) red[t] += red[t + w];
    __syncthreads();
  }
  if (t == 0) {
    float v = red[0] + (y ? 0.f : *cdot);
    (y ? rbv : rav)[r] = SCALE * v;
  }
}

__global__ void colsum_final(const float* __restrict__ part, float* __restrict__ crcp,
                             int Nm, int nParts) {
  int b = blockIdx.y;
  int m = blockIdx.x * 256 + threadIdx.x;
  float s = 0.f;
  for (int p = 0; p < nParts; ++p)
    s += part[((long)p * gridDim.y + b) * Nm + m];
  crcp[(long)b * Nm + m] = 1.0f / s;
}

__device__ __forceinline__ float bf2f(unsigned short u) {
  union { unsigned u32; float f; } x; x.u32 = ((unsigned)u) << 16; return x.f;
}

// bf16 [R,C] -> bf16 [C,R], scaling input row r by crcp[z*R+r]
__global__ void transpose_scale_bf16(const bf16_t* __restrict__ in, const float* __restrict__ crcp,
                                     bf16_t* __restrict__ out, int R, int C, long sIn, long sOut) {
  __shared__ bf16_t tile[64][68];
  int z = blockIdx.z;
  const bf16_t* ip = in + (long)z * sIn;
  bf16_t* op = out + (long)z * sOut;
  const float* rc = crcp + (long)z * R;
  int c0 = blockIdx.x * 64, r0 = blockIdx.y * 64;
#pragma unroll
  for (int i = 0; i < 4; ++i) {
    int chunk = i * 256 + threadIdx.x;
    int r = chunk >> 4, c4 = (chunk & 15) << 2;
    float s = rc[r0 + r];
    ushort4 uv = *(const ushort4*)(ip + (long)(r0 + r) * C + (c0 + c4));
    tile[r][c4 + 0] = (bf16_t)(bf2f(uv.x) * s);
    tile[r][c4 + 1] = (bf16_t)(bf2f(uv.y) * s);
    tile[r][c4 + 2] = (bf16_t)(bf2f(uv.z) * s);
    tile[r][c4 + 3] = (bf16_t)(bf2f(uv.w) * s);
  }
  __syncthreads();
#pragma unroll
  for (int i = 0; i < 4; ++i) {
    int chunk = i * 256 + threadIdx.x;
    int oc = chunk >> 4, or4 = (chunk & 15) << 2;
    union { ushort4 u; bf16_t h[4]; } o;
    o.h[0] = tile[or4 + 0][oc];
    o.h[1] = tile[or4 + 1][oc];
    o.h[2] = tile[or4 + 2][oc];
    o.h[3] = tile[or4 + 3][oc];
    *(ushort4*)(op + (long)(c0 + oc) * R + (r0 + or4)) = o.u;
  }
}

extern "C" void kernel_launch(void* const* d_in, const int* in_sizes, int n_in,
                              void* d_out, int out_size, void* d_ws, size_t ws_size,
                              hipStream_t stream)
{
  (void)in_sizes; (void)n_in; (void)out_size; (void)ws_size;
  const float* q  = (const float*)d_in[0];
  const float* k  = (const float*)d_in[1];
  const float* v  = (const float*)d_in[2];
  const float* Wq = (const float*)d_in[3];
  const float* bq = (const float*)d_in[4];
  const float* Wk = (const float*)d_in[5];
  const float* bk = (const float*)d_in[6];
  const float* Wv = (const float*)d_in[7];
  const float* bv = (const float*)d_in[8];
  const float* Wo = (const float*)d_in[9];
  const float* bo = (const float*)d_in[10];
  float* out = (float*)d_out;

  char* ws = (char*)d_ws;
  const size_t MB = 1u << 20;
  // flat overlay, peak 172 MB, no aliasing:
  bf16_t* qcat  = (bf16_t*)(ws);              // [0,16)   [8192,1024] (h|l)
  bf16_t* kcat  = (bf16_t*)(ws + 16 * MB);    // [16,32)
  bf16_t* GA    = (bf16_t*)(ws + 32 * MB);    // [32,40)  Wk  [512,8192]
  bf16_t* GB    = (bf16_t*)(ws + 40 * MB);    // [40,48)  Wq
  bf16_t* WoS   = (bf16_t*)(ws + 48 * MB);    // [48,56)  Wo^T [512,8192]
  bf16_t* WvS   = (bf16_t*)(ws + 56 * MB);    // [56,64)  Wv
  float*  Gpart = (float*)(ws + 64 * MB);     // [64,80)  16x[512,512]
  float*  WvoTp = (float*)(ws + 80 * MB);     // [80,96)
  float*  Gt    = (float*)(ws + 96 * MB);     // [96,97)
  bf16_t* Gtcat = (bf16_t*)(ws + 97 * MB);    // [97,98)  [512,1024]
  bf16_t* WvoTb = (bf16_t*)(ws + 98 * MB);    // [98,98.5)
  float*  bvo   = (float*)(ws + 99 * MB);
  float*  wqbk  = (float*)(ws + 99 * MB + 16 * 1024);
  float*  wkbq  = (float*)(ws + 99 * MB + 32 * 1024);
  float*  cdot  = (float*)(ws + 99 * MB + 48 * 1024);
  float*  rav   = (float*)(ws + 99 * MB + 64 * 1024);   // 32 KB
  float*  rbv   = (float*)(ws + 99 * MB + 128 * 1024);  // 32 KB
  float*  crcp  = (float*)(ws + 99 * MB + 192 * 1024);  // 32 KB
  float*  part  = (float*)(ws + 99 * MB + 256 * 1024);  // 512 KB
  bf16_t* tcat  = (bf16_t*)(ws + 100 * MB);   // [100,116) [8192,1024]
  bf16_t* vbf   = (bf16_t*)(ws + 116 * MB);   // [116,124)
  bf16_t* vo    = (bf16_t*)(ws + 124 * MB);   // [124,132) [8192,512]
  bf16_t* vosT  = (bf16_t*)(ws + 132 * MB);   // [132,140) [B][512,2048]
  bf16_t* P     = (bf16_t*)(ws + 140 * MB);   // [140,172) [B][2048,2048]

  // splits
  split2<<<2048, 256, 0, stream>>>(q,  qcat, NROW * HID, 9);
  split2<<<2048, 256, 0, stream>>>(k,  kcat, NROW * HID, 9);
  split2<<<2048, 256, 0, stream>>>(Wk, GA, (long)HID * PROJ, 12);
  split2<<<2048, 256, 0, stream>>>(Wq, GB, (long)HID * PROJ, 12);
  split2<<<2048, 256, 0, stream>>>(Wv, WvS, (long)HID * PROJ, 12);
  transpose_split2<<<dim3(HID / 32, PROJ / 32), 256, 0, stream>>>(Wo, WoS, PROJ, HID);

  // Gt = SCALE*Wk.Wq^T and WvoT = Wo^T.Wv^T (accurate, K=12288 z-split 16)
  gemm_bt<float, 0, 1, 2><<<dim3(4, 4, 16), 256, 0, stream>>>(GA, GB, Gpart,
      nullptr, nullptr, nullptr, nullptr, 1.0f, HID, HID, 768, 2L * PROJ, 2L * PROJ,
      0, 0, (long)HID * HID, 768, 12);
  gemm_bt<float, 0, 1, 2><<<dim3(4, 4, 16), 256, 0, stream>>>(WoS, WvS, WvoTp,
      nullptr, nullptr, nullptr, nullptr, 1.0f, HID, HID, 768, 2L * PROJ, 2L * PROJ,
      0, 0, (long)HID * HID, 768, 12);
  reduce2<<<(HID * HID + 255) / 256, 256, 0, stream>>>(Gpart, WvoTp, Gt, WvoTb,
      SCALE, HID * HID, 16);
  split2<<<1024, 256, 0, stream>>>(Gt, Gtcat, (long)HID * HID, 9);

  // rank-1 bias terms
  rank1<<<dim3(HID, 4), 256, 0, stream>>>(Wq, bk, Wk, bq, Wo, bv, wqbk, wkbq, bvo, cdot);
  rowdot2<<<dim3((int)NROW, 2), 256, 0, stream>>>(q, k, wqbk, wkbq, cdot, rav, rbv);

  // t = q.Gt^T (split x split, K=1536), h/l split written directly
  gemm_bt<bf16_t, 2, 1, 2><<<dim3(4, 64, 1), 256, 0, stream>>>(qcat, Gtcat, tcat,
      nullptr, nullptr, nullptr, nullptr, 1.0f, (int)NROW, HID, 1536, 1024, 1024,
      0, 0, 0, 0, 9);

  cast_f32_bf16<<<2048, 256, 0, stream>>>(v, vbf, NROW * HID);

  // P = exp(t.k^T + ra + rb), fused column partial sums
  gemm_bt<bf16_t, 1, 1, 2><<<dim3(16, 16, BSZ), 256, 0, stream>>>(tcat, kcat, P,
      nullptr, rav, rbv, part, 1.0f, SEQ, SEQ, 1536, 1024, 1024,
      (long)SEQ * 1024, (long)SEQ * 1024, (long)SEQ * SEQ, 0, 9);
  colsum_final<<<dim3(SEQ / 256, BSZ), 256, 0, stream>>>(part, crcp, SEQ, 16);

  // vo = v.Wvo + bvo
  gemm_bt<bf16_t, 0, 0, 0><<<dim3(4, 64, 1), 256, 0, stream>>>(vbf, WvoTb, vo,
      bvo, nullptr, nullptr, nullptr, 1.0f, (int)NROW, HID, HID, HID, HID,
      0, 0, 0, 0, 0);
  // vosT[z][d,m] = vo[z][m,d] / csum[z][m]
  transpose_scale_bf16<<<dim3(HID / 64, SEQ / 64, BSZ), 256, 0, stream>>>(
      vo, crcp, vosT, SEQ, HID, (long)SEQ * HID, (long)HID * SEQ);

  // out = P.vosT^T + bo
  gemm_bt<float, 0, 0, 0><<<dim3(4, 16, BSZ), 256, 0, stream>>>(P, vosT, out,
      bo, nullptr, nullptr, nullptr, 1.0f, SEQ, HID, SEQ, SEQ, SEQ,
      (long)SEQ * SEQ, (long)HID * SEQ, (long)SEQ * HID, 0, 0);
}

// Round 5
// 279.268 us; speedup vs baseline: 1.4689x; 1.4689x over previous
//
#include <hip/hip_runtime.h>
#include <hip/hip_bf16.h>

#define AS1 __attribute__((address_space(1)))
#define AS3 __attribute__((address_space(3)))

typedef __bf16 bf16_t;
typedef __attribute__((ext_vector_type(8))) __bf16 bf16x8;
typedef __attribute__((ext_vector_type(4))) float f32x4;

static constexpr int BSZ = 4, SEQ = 2048, HID = 512, PROJ = 4096;
static constexpr long NROW = (long)BSZ * SEQ;  // 8192
static constexpr float SCALE = 0.125f;

__device__ __forceinline__ void gload_lds16(const void* g, void* l) {
  __builtin_amdgcn_global_load_lds((const AS1 void*)g, (AS3 void*)l, 16, 0, 0);
}

// map logical K index -> storage col for 2-wide [h|l] split buffers.
// MAP 0: identity. MAP 1: logical thirds (h,l,h). MAP 2: logical thirds (h,h,l).
template <int MAP>
__device__ __forceinline__ long mapk(long c, int s) {
  if (MAP == 0) return c;
  long w = c & ((1L << s) - 1);
  long t = c >> s;
  bool lo = (MAP == 1) ? (t == 1) : (t == 2);
  return (lo ? (1L << s) : 0) + w;
}

// ------------------------------------------------------------------
// GEMM: C[M,N] = epi(A[M,K] . B[N,K]^T), bf16, row strides lda/ldb,
// z batching (pointer strides sA/sB/sC; logical-K offset kz per z).
// OUTMODE 0: C = (acc + bias[col]) * scale
// OUTMODE 1: C = exp(acc + ra[z*M+row] + rb[z*N+col]) + fused col partial sums
// OUTMODE 2: h/l split write
// 128x128 tile, BK=64, 4 waves; LDS XOR swizzle; bijective XCD swizzle.
// ------------------------------------------------------------------
template <typename OutT, int OUTMODE, int AMAP, int BMAP>
__global__ __launch_bounds__(256) void gemm_bt(
    const bf16_t* __restrict__ A, const bf16_t* __restrict__ B,
    OutT* __restrict__ C, const float* __restrict__ bias,
    const float* __restrict__ ra, const float* __restrict__ rb,
    float* __restrict__ part, float scale,
    int M, int N, int K, long lda, long ldb,
    long sA, long sB, long sC, long kz, int sshift)
{
  __shared__ __align__(16) bf16_t As[128 * 64];
  __shared__ __align__(16) bf16_t Bs[128 * 64];
  const int z = blockIdx.z;
  A += (long)z * sA; B += (long)z * sB; C += (long)z * sC;

  // bijective XCD swizzle within the z-plane (m204)
  const int gx = gridDim.x;
  const int nwg = gx * gridDim.y;
  const int id = blockIdx.y * gx + blockIdx.x;
  const int qq = nwg >> 3, rr = nwg & 7;
  const int xcd = id & 7, jj = id >> 3;
  const int swz = (xcd < rr ? xcd * (qq + 1) : rr * (qq + 1) + (xcd - rr) * qq) + jj;
  const int bx = swz % gx, by = swz / gx;

  const int tid  = threadIdx.x;
  const int lane = tid & 63;
  const int wid  = tid >> 6;
  const int wr = (wid >> 1) * 64;
  const int wc = (wid & 1) * 64;
  const long rowBase = (long)by * 128;
  const long colBase = (long)bx * 128;

  f32x4 acc[4][4] = {};

  int srow[4], scol[4];
#pragma unroll
  for (int i = 0; i < 4; ++i) {
    int li = i * 256 + tid;
    int row = li >> 3;
    int inner = (li & 7) << 4;
    int src = inner ^ ((row & 7) << 4);
    srow[i] = row;
    scol[i] = src >> 1;
  }

  for (int k0 = 0; k0 < K; k0 += 64) {
    const long k0L = kz * z + k0;
    const long ka = mapk<AMAP>(k0L, sshift);
    const long kb = mapk<BMAP>(k0L, sshift);
    __syncthreads();
#pragma unroll
    for (int i = 0; i < 4; ++i) {
      int li = i * 256 + tid;
      gload_lds16(A + (rowBase + srow[i]) * lda + ka + scol[i], (char*)As + li * 16);
      gload_lds16(B + (colBase + srow[i]) * ldb + kb + scol[i], (char*)Bs + li * 16);
    }
    __syncthreads();
#pragma unroll
    for (int kk = 0; kk < 64; kk += 32) {
      const int kbyte = (kk + ((lane >> 4) << 3)) << 1;
      bf16x8 af[4], bfr[4];
#pragma unroll
      for (int m = 0; m < 4; ++m) {
        int row = wr + m * 16 + (lane & 15);
        int off = (row << 7) + (kbyte ^ ((row & 7) << 4));
        af[m] = *(const bf16x8*)((const char*)As + off);
      }
#pragma unroll
      for (int n = 0; n < 4; ++n) {
        int row = wc + n * 16 + (lane & 15);
        int off = (row << 7) + (kbyte ^ ((row & 7) << 4));
        bfr[n] = *(const bf16x8*)((const char*)Bs + off);
      }
#pragma unroll
      for (int m = 0; m < 4; ++m)
#pragma unroll
        for (int n = 0; n < 4; ++n)
          acc[m][n] = __builtin_amdgcn_mfma_f32_16x16x32_bf16(af[m], bfr[n], acc[m][n], 0, 0, 0);
    }
  }

  // epilogue; C layout per m89: col=lane&15 (+16n), row=(lane>>4)*4+e (+16m)
  if (OUTMODE == 1) {
    __syncthreads();  // done with As; reuse as colsum staging
    float* csLDS = (float*)As;  // [2][128]
    float ra_[4][4];
#pragma unroll
    for (int m = 0; m < 4; ++m)
#pragma unroll
      for (int e = 0; e < 4; ++e)
        ra_[m][e] = ra[(long)z * M + rowBase + wr + m * 16 + (lane >> 4) * 4 + e];
    float colAcc[4];
#pragma unroll
    for (int n = 0; n < 4; ++n) {
      const long col = colBase + wc + n * 16 + (lane & 15);
      const float rbv_ = rb[(long)z * N + col];
      float cs = 0.f;
#pragma unroll
      for (int m = 0; m < 4; ++m) {
#pragma unroll
        for (int e = 0; e < 4; ++e) {
          const long row = rowBase + wr + m * 16 + (lane >> 4) * 4 + e;
          float v = __expf(acc[m][n][e] + ra_[m][e] + rbv_);
          C[row * (long)N + col] = (OutT)v;
          cs += v;
        }
      }
      cs += __shfl_xor(cs, 16);
      cs += __shfl_xor(cs, 32);
      colAcc[n] = cs;
    }
    if (lane < 16) {
#pragma unroll
      for (int n = 0; n < 4; ++n)
        csLDS[(wid >> 1) * 128 + wc + n * 16 + lane] = colAcc[n];
    }
    __syncthreads();
    if (tid < 128) {
      float t2 = csLDS[tid] + csLDS[128 + tid];
      part[((long)by * gridDim.z + z) * N + colBase + tid] = t2;
    }
  } else if (OUTMODE == 2) {
#pragma unroll
    for (int n = 0; n < 4; ++n) {
      const long col = colBase + wc + n * 16 + (lane & 15);
#pragma unroll
      for (int m = 0; m < 4; ++m) {
#pragma unroll
        for (int e = 0; e < 4; ++e) {
          const long row = rowBase + wr + m * 16 + (lane >> 4) * 4 + e;
          float v = acc[m][n][e] * scale;
          bf16_t h = (bf16_t)v;
          bf16_t l = (bf16_t)(v - (float)h);
          C[row * (2L * N) + col] = (OutT)h;
          C[row * (2L * N) + N + col] = (OutT)l;
        }
      }
    }
  } else {
#pragma unroll
    for (int n = 0; n < 4; ++n) {
      const long col = colBase + wc + n * 16 + (lane & 15);
      const float bv_ = bias ? bias[col] : 0.0f;
#pragma unroll
      for (int m = 0; m < 4; ++m) {
#pragma unroll
        for (int e = 0; e < 4; ++e) {
          const long row = rowBase + wr + m * 16 + (lane >> 4) * 4 + e;
          C[row * (long)N + col] = (OutT)((acc[m][n][e] + bv_) * scale);
        }
      }
    }
  }
}

// f32 [R,C] -> bf16 [R,2C] = (h|l)
__global__ void split2(const float* __restrict__ in, bf16_t* __restrict__ out,
                       long n, int cshift) {
  long C = 1L << cshift;
  for (long i = (long)blockIdx.x * blockDim.x + threadIdx.x; i < n;
       i += (long)gridDim.x * blockDim.x) {
    long r = i >> cshift, c = i & (C - 1);
    float x = in[i];
    bf16_t h = (bf16_t)x;
    bf16_t l = (bf16_t)(x - (float)h);
    bf16_t* o = out + r * 2 * C + c;
    o[0] = h;
    o[C] = l;
  }
}

// f32 [R,C] -> bf16 [C,2R] = (h|l) of the transpose
__global__ void transpose_split2(const float* __restrict__ in, bf16_t* __restrict__ out,
                                 int R, int C) {
  __shared__ float tile[32][33];
  int c0 = blockIdx.x * 32, r0 = blockIdx.y * 32;
  int tx = threadIdx.x & 31, ty = threadIdx.x >> 5;
#pragma unroll
  for (int i = 0; i < 32; i += 8)
    tile[ty + i][tx] = in[(long)(r0 + ty + i) * C + (c0 + tx)];
  __syncthreads();
#pragma unroll
  for (int i = 0; i < 32; i += 8) {
    float x = tile[tx][ty + i];
    bf16_t h = (bf16_t)x;
    bf16_t l = (bf16_t)(x - (float)h);
    long o = (long)(c0 + ty + i) * 2 * R + (r0 + tx);
    out[o] = h;
    out[o + R] = l;
  }
}

// fp32 -> bf16 elementwise
__global__ void cast_f32_bf16(const float* __restrict__ in, bf16_t* __restrict__ out, long n) {
  long i0 = ((long)blockIdx.x * blockDim.x + threadIdx.x) * 4;
  long stride = (long)gridDim.x * blockDim.x * 4;
  for (long i = i0; i < n; i += stride) {
    float4 f = *(const float4*)(in + i);
    union { ushort4 u; bf16_t h[4]; } o;
    o.h[0] = (bf16_t)f.x; o.h[1] = (bf16_t)f.y; o.h[2] = (bf16_t)f.z; o.h[3] = (bf16_t)f.w;
    *(ushort4*)(out + i) = o.u;
  }
}

// Gt = scale*sum_p Gpart[p]; WvoTb = (bf16) sum_p WvoTp[p]
__global__ void reduce2(const float* __restrict__ gp, const float* __restrict__ wp,
                        float* __restrict__ Gt, bf16_t* __restrict__ WvoTb,
                        float scale, int nElem, int nParts) {
  int i = blockIdx.x * 256 + threadIdx.x;
  if (i < nElem) {
    float a = 0.f, b = 0.f;
    for (int p = 0; p < nParts; ++p) {
      a += gp[(long)p * nElem + i];
      b += wp[(long)p * nElem + i];
    }
    Gt[i] = scale * a;
    WvoTb[i] = (bf16_t)b;
  }
}

__device__ __forceinline__ float bf2f(unsigned short u) {
  union { unsigned u32; float f; } x; x.u32 = ((unsigned)u) << 16; return x.f;
}

// rank-1 bias prep (all branches one-block-per-output, coalesced):
// y=0 wqbk[bx]=Wq[bx,:].bk; y=1 wkbq[bx]=Wk[bx,:].bq;
// y=2 bvo[bx]=WoT[bx,:].bv via WoS (h+l reconstruct); y=3 cdot=bq.bk
__global__ void rank1(const float* __restrict__ Wq, const float* __restrict__ bk,
                      const float* __restrict__ Wk, const float* __restrict__ bq,
                      const bf16_t* __restrict__ WoS, const float* __restrict__ bv,
                      float* __restrict__ wqbk, float* __restrict__ wkbq,
                      float* __restrict__ bvo, float* __restrict__ cdot) {
  __shared__ float red[256];
  int y = blockIdx.y, bx = blockIdx.x, t = threadIdx.x;
  float s = 0.f;
  if (y == 0) {
    for (int j = t; j < PROJ; j += 256) s += Wq[(long)bx * PROJ + j] * bk[j];
  } else if (y == 1) {
    for (int j = t; j < PROJ; j += 256) s += Wk[(long)bx * PROJ + j] * bq[j];
  } else if (y == 2) {
    const bf16_t* row = WoS + (long)bx * 2 * PROJ;
    for (int j = t; j < PROJ; j += 256)
      s += ((float)row[j] + (float)row[PROJ + j]) * bv[j];
  } else {
    if (bx != 0) return;
    for (int j = t; j < PROJ; j += 256) s += bq[j] * bk[j];
  }
  red[t] = s; __syncthreads();
  for (int w = 128; w > 0; w >>= 1) {
    if (t < w) red[t] += red[t + w];
    __syncthreads();
  }
  if (t == 0) {
    if (y == 0) wqbk[bx] = red[0];
    else if (y == 1) wkbq[bx] = red[0];
    else if (y == 2) bvo[bx] = red[0];
    else *cdot = red[0];
  }
}

// y=0: rav[r]=SCALE*(q[r].wqbk + cdot); y=1: rbv[r]=SCALE*(k[r].wkbq)
__global__ void rowdot2(const float* __restrict__ q, const float* __restrict__ k,
                        const float* __restrict__ wqbk, const float* __restrict__ wkbq,
                        const float* __restrict__ cdot,
                        float* __restrict__ rav, float* __restrict__ rbv) {
  __shared__ float red[256];
  int r = blockIdx.x, y = blockIdx.y, t = threadIdx.x;
  const float* X = y ? k : q;
  const float* w_ = y ? wkbq : wqbk;
  float s = 0.f;
  for (int j = t; j < HID; j += 256) s += X[(long)r * HID + j] * w_[j];
  red[t] = s; __syncthreads();
  for (int w = 128; w > 0; w >>= 1) {
    if (t < w) red[t] += red[t + w];
    __syncthreads();
  }
  if (t == 0) {
    float v = red[0] + (y ? 0.f : *cdot);
    (y ? rbv : rav)[r] = SCALE * v;
  }
}

__global__ void colsum_final(const float* __restrict__ part, float* __restrict__ crcp,
                             int Nm, int nParts) {
  int b = blockIdx.y;
  int m = blockIdx.x * 256 + threadIdx.x;
  float s = 0.f;
  for (int p = 0; p < nParts; ++p)
    s += part[((long)p * gridDim.y + b) * Nm + m];
  crcp[(long)b * Nm + m] = 1.0f / s;
}

// bf16 [R,C] -> bf16 [C,R], scaling input row r by crcp[z*R+r]
__global__ void transpose_scale_bf16(const bf16_t* __restrict__ in, const float* __restrict__ crcp,
                                     bf16_t* __restrict__ out, int R, int C, long sIn, long sOut) {
  __shared__ bf16_t tile[64][68];
  int z = blockIdx.z;
  const bf16_t* ip = in + (long)z * sIn;
  bf16_t* op = out + (long)z * sOut;
  const float* rc = crcp + (long)z * R;
  int c0 = blockIdx.x * 64, r0 = blockIdx.y * 64;
#pragma unroll
  for (int i = 0; i < 4; ++i) {
    int chunk = i * 256 + threadIdx.x;
    int r = chunk >> 4, c4 = (chunk & 15) << 2;
    float s = rc[r0 + r];
    ushort4 uv = *(const ushort4*)(ip + (long)(r0 + r) * C + (c0 + c4));
    tile[r][c4 + 0] = (bf16_t)(bf2f(uv.x) * s);
    tile[r][c4 + 1] = (bf16_t)(bf2f(uv.y) * s);
    tile[r][c4 + 2] = (bf16_t)(bf2f(uv.z) * s);
    tile[r][c4 + 3] = (bf16_t)(bf2f(uv.w) * s);
  }
  __syncthreads();
#pragma unroll
  for (int i = 0; i < 4; ++i) {
    int chunk = i * 256 + threadIdx.x;
    int oc = chunk >> 4, or4 = (chunk & 15) << 2;
    union { ushort4 u; bf16_t h[4]; } o;
    o.h[0] = tile[or4 + 0][oc];
    o.h[1] = tile[or4 + 1][oc];
    o.h[2] = tile[or4 + 2][oc];
    o.h[3] = tile[or4 + 3][oc];
    *(ushort4*)(op + (long)(c0 + oc) * R + (r0 + or4)) = o.u;
  }
}

extern "C" void kernel_launch(void* const* d_in, const int* in_sizes, int n_in,
                              void* d_out, int out_size, void* d_ws, size_t ws_size,
                              hipStream_t stream)
{
  (void)in_sizes; (void)n_in; (void)out_size; (void)ws_size;
  const float* q  = (const float*)d_in[0];
  const float* k  = (const float*)d_in[1];
  const float* v  = (const float*)d_in[2];
  const float* Wq = (const float*)d_in[3];
  const float* bq = (const float*)d_in[4];
  const float* Wk = (const float*)d_in[5];
  const float* bk = (const float*)d_in[6];
  const float* Wv = (const float*)d_in[7];
  const float* bv = (const float*)d_in[8];
  const float* Wo = (const float*)d_in[9];
  const float* bo = (const float*)d_in[10];
  float* out = (float*)d_out;

  char* ws = (char*)d_ws;
  const size_t MB = 1u << 20;
  // flat overlay, peak 172 MB, no aliasing:
  bf16_t* qcat  = (bf16_t*)(ws);              // [0,16)   [8192,1024] (h|l)
  bf16_t* kcat  = (bf16_t*)(ws + 16 * MB);    // [16,32)
  bf16_t* GA    = (bf16_t*)(ws + 32 * MB);    // [32,40)  Wk  [512,8192]
  bf16_t* GB    = (bf16_t*)(ws + 40 * MB);    // [40,48)  Wq
  bf16_t* WoS   = (bf16_t*)(ws + 48 * MB);    // [48,56)  Wo^T [512,8192]
  bf16_t* WvS   = (bf16_t*)(ws + 56 * MB);    // [56,64)  Wv
  float*  Gpart = (float*)(ws + 64 * MB);     // [64,80)  16x[512,512]
  float*  WvoTp = (float*)(ws + 80 * MB);     // [80,96)
  float*  Gt    = (float*)(ws + 96 * MB);     // [96,97)
  bf16_t* Gtcat = (bf16_t*)(ws + 97 * MB);    // [97,98)  [512,1024]
  bf16_t* WvoTb = (bf16_t*)(ws + 98 * MB);    // [98,98.5)
  float*  bvo   = (float*)(ws + 99 * MB);
  float*  wqbk  = (float*)(ws + 99 * MB + 16 * 1024);
  float*  wkbq  = (float*)(ws + 99 * MB + 32 * 1024);
  float*  cdot  = (float*)(ws + 99 * MB + 48 * 1024);
  float*  rav   = (float*)(ws + 99 * MB + 64 * 1024);   // 32 KB
  float*  rbv   = (float*)(ws + 99 * MB + 128 * 1024);  // 32 KB
  float*  crcp  = (float*)(ws + 99 * MB + 192 * 1024);  // 32 KB
  float*  part  = (float*)(ws + 99 * MB + 256 * 1024);  // 512 KB
  bf16_t* tcat  = (bf16_t*)(ws + 100 * MB);   // [100,116) [8192,1024]
  bf16_t* vbf   = (bf16_t*)(ws + 116 * MB);   // [116,124)
  bf16_t* vo    = (bf16_t*)(ws + 124 * MB);   // [124,132) [8192,512]
  bf16_t* vosT  = (bf16_t*)(ws + 132 * MB);   // [132,140) [B][512,2048]
  bf16_t* P     = (bf16_t*)(ws + 140 * MB);   // [140,172) [B][2048,2048]

  // splits
  split2<<<2048, 256, 0, stream>>>(q,  qcat, NROW * HID, 9);
  split2<<<2048, 256, 0, stream>>>(k,  kcat, NROW * HID, 9);
  split2<<<2048, 256, 0, stream>>>(Wk, GA, (long)HID * PROJ, 12);
  split2<<<2048, 256, 0, stream>>>(Wq, GB, (long)HID * PROJ, 12);
  split2<<<2048, 256, 0, stream>>>(Wv, WvS, (long)HID * PROJ, 12);
  transpose_split2<<<dim3(HID / 32, PROJ / 32), 256, 0, stream>>>(Wo, WoS, PROJ, HID);

  // Gt = SCALE*Wk.Wq^T and WvoT = Wo^T.Wv^T (accurate, K=12288 z-split 16)
  gemm_bt<float, 0, 1, 2><<<dim3(4, 4, 16), 256, 0, stream>>>(GA, GB, Gpart,
      nullptr, nullptr, nullptr, nullptr, 1.0f, HID, HID, 768, 2L * PROJ, 2L * PROJ,
      0, 0, (long)HID * HID, 768, 12);
  gemm_bt<float, 0, 1, 2><<<dim3(4, 4, 16), 256, 0, stream>>>(WoS, WvS, WvoTp,
      nullptr, nullptr, nullptr, nullptr, 1.0f, HID, HID, 768, 2L * PROJ, 2L * PROJ,
      0, 0, (long)HID * HID, 768, 12);
  reduce2<<<(HID * HID + 255) / 256, 256, 0, stream>>>(Gpart, WvoTp, Gt, WvoTb,
      SCALE, HID * HID, 16);
  split2<<<1024, 256, 0, stream>>>(Gt, Gtcat, (long)HID * HID, 9);

  // rank-1 bias terms (bvo now via coalesced WoS rows, 512-block parallel)
  rank1<<<dim3(HID, 4), 256, 0, stream>>>(Wq, bk, Wk, bq, WoS, bv, wqbk, wkbq, bvo, cdot);
  rowdot2<<<dim3((int)NROW, 2), 256, 0, stream>>>(q, k, wqbk, wkbq, cdot, rav, rbv);

  // t = q.Gt^T (split x split, K=1536), h/l split written directly
  gemm_bt<bf16_t, 2, 1, 2><<<dim3(4, 64, 1), 256, 0, stream>>>(qcat, Gtcat, tcat,
      nullptr, nullptr, nullptr, nullptr, 1.0f, (int)NROW, HID, 1536, 1024, 1024,
      0, 0, 0, 0, 9);

  cast_f32_bf16<<<2048, 256, 0, stream>>>(v, vbf, NROW * HID);

  // P = exp(t.k^T + ra + rb), fused column partial sums
  gemm_bt<bf16_t, 1, 1, 2><<<dim3(16, 16, BSZ), 256, 0, stream>>>(tcat, kcat, P,
      nullptr, rav, rbv, part, 1.0f, SEQ, SEQ, 1536, 1024, 1024,
      (long)SEQ * 1024, (long)SEQ * 1024, (long)SEQ * SEQ, 0, 9);
  colsum_final<<<dim3(SEQ / 256, BSZ), 256, 0, stream>>>(part, crcp, SEQ, 16);

  // vo = v.Wvo + bvo
  gemm_bt<bf16_t, 0, 0, 0><<<dim3(4, 64, 1), 256, 0, stream>>>(vbf, WvoTb, vo,
      bvo, nullptr, nullptr, nullptr, 1.0f, (int)NROW, HID, HID, HID, HID,
      0, 0, 0, 0, 0);
  // vosT[z][d,m] = vo[z][m,d] / csum[z][m]
  transpose_scale_bf16<<<dim3(HID / 64, SEQ / 64, BSZ), 256, 0, stream>>>(
      vo, crcp, vosT, SEQ, HID, (long)SEQ * HID, (long)HID * SEQ);

  // out = P.vosT^T + bo
  gemm_bt<float, 0, 0, 0><<<dim3(4, 16, BSZ), 256, 0, stream>>>(P, vosT, out,
      bo, nullptr, nullptr, nullptr, 1.0f, SEQ, HID, SEQ, SEQ, SEQ,
      (long)SEQ * SEQ, (long)HID * SEQ, (long)SEQ * HID, 0, 0);
}

// Round 6
// 255.436 us; speedup vs baseline: 1.6059x; 1.0933x over previous
//
#include <hip/hip_runtime.h>
#include <hip/hip_bf16.h>

#define AS1 __attribute__((address_space(1)))
#define AS3 __attribute__((address_space(3)))

typedef __bf16 bf16_t;
typedef __attribute__((ext_vector_type(8))) __bf16 bf16x8;
typedef __attribute__((ext_vector_type(4))) float f32x4;

static constexpr int BSZ = 4, SEQ = 2048, HID = 512, PROJ = 4096;
static constexpr long NROW = (long)BSZ * SEQ;  // 8192
static constexpr float SCALE = 0.125f;

__device__ __forceinline__ void gload_lds16(const void* g, void* l) {
  __builtin_amdgcn_global_load_lds((const AS1 void*)g, (AS3 void*)l, 16, 0, 0);
}

// map logical K index -> storage col for 2-wide [h|l] split buffers.
// MAP 0: identity. MAP 1: logical thirds (h,l,h). MAP 2: logical thirds (h,h,l).
template <int MAP>
__device__ __forceinline__ long mapk(long c, int s) {
  if (MAP == 0) return c;
  long w = c & ((1L << s) - 1);
  long t = c >> s;
  bool lo = (MAP == 1) ? (t == 1) : (t == 2);
  return (lo ? (1L << s) : 0) + w;
}

// ==================================================================
// 8-phase 256x256 GEMM for P = exp(t.k^T + ra + rb) with fused column
// partial sums. A=tcat (thirds h,l,h), B=kcat (h,h,l), K=1536, z=4.
// 512 threads = 8 waves (2M x 4N), BK=64, LDS 128KB (2 dbuf x {A0,A1,B0,B1}
// half-tiles of 128x64 bf16). XOR swizzle byte^=((row&7)<<4) on source+read.
// Schedule per K-tile t (buf d=t&1): 4 phases = C-quadrants; stage issues
// ph0:Ah1(t+1), ph1:Bh0(t+1), ph2:Bh1(t+1), ph3:Ah0(t+2); boundary vmcnt(2).
// ==================================================================
__device__ __forceinline__ void stage_half8(
    const bf16_t* __restrict__ G, long ldg, long rcBase, long kcol,
    int half, bf16_t* dst, int tid)
{
#pragma unroll
  for (int it = 0; it < 2; ++it) {
    int li = it * 512 + tid;
    int row = li >> 3;
    int srcb = ((li & 7) << 4) ^ ((row & 7) << 4);
    gload_lds16(G + (rcBase + half * 128 + row) * ldg + kcol + (srcb >> 1),
                (char*)dst + li * 16);
  }
}

#define PH_PRE()  __builtin_amdgcn_s_barrier(); \
                  asm volatile("s_waitcnt lgkmcnt(0)" ::: "memory"); \
                  __builtin_amdgcn_sched_barrier(0); \
                  __builtin_amdgcn_s_setprio(1);
#define PH_POST() __builtin_amdgcn_s_setprio(0); \
                  __builtin_amdgcn_s_barrier(); \
                  __builtin_amdgcn_sched_barrier(0);

__global__ __launch_bounds__(512, 2) void gemm8exp(
    const bf16_t* __restrict__ A, const bf16_t* __restrict__ B,
    bf16_t* __restrict__ C, const float* __restrict__ ra,
    const float* __restrict__ rb, float* __restrict__ part)
{
  constexpr int NT = 24;            // K = 1536
  constexpr long LDA = 1024, LDB = 1024;
  constexpr int M = 2048, N = 2048;
  __shared__ __align__(16) bf16_t lds8[65536];  // 128 KB

  const int z = blockIdx.z;
  A += (long)z * SEQ * LDA;
  B += (long)z * SEQ * LDB;
  C += (long)z * (long)SEQ * SEQ;

  // bijective XCD swizzle (nwg=64 per plane, 64%8==0)
  const int id0 = blockIdx.y * 8 + blockIdx.x;
  const int swz = (id0 & 7) * 8 + (id0 >> 3);
  const int bx = swz & 7, by = swz >> 3;
  const long rowBase = (long)by * 256;
  const long colBase = (long)bx * 256;

  const int tid = threadIdx.x;
  const int lane = tid & 63;
  const int wid = tid >> 6;
  const int wm = wid >> 2;          // 0..1 (M)
  const int wn = wid & 3;           // 0..3 (N)
  const int l15 = lane & 15;
  const int kgb = (lane >> 4) << 4; // byte offset of lane's k-group

  f32x4 acc[8][4] = {};
  bf16x8 afr[4][2];                 // current quadrant-row A frags
  bf16x8 bfr[2][2][2];              // [qc][c][kk]

  // prologue: tile0 all 4 halves -> buf0; tile1 Ah0 -> buf1
  {
    long ka0 = mapk<1>(0, 9), kb0 = mapk<2>(0, 9);
    long ka1 = mapk<1>(64, 9);
    stage_half8(A, LDA, rowBase, ka0, 0, lds8 + 0 * 8192, tid);
    stage_half8(A, LDA, rowBase, ka0, 1, lds8 + 1 * 8192, tid);
    stage_half8(B, LDB, colBase, kb0, 0, lds8 + 2 * 8192, tid);
    stage_half8(B, LDB, colBase, kb0, 1, lds8 + 3 * 8192, tid);
    stage_half8(A, LDA, rowBase, ka1, 0, lds8 + 32768 + 0 * 8192, tid);
    asm volatile("s_waitcnt vmcnt(2)" ::: "memory");
    __builtin_amdgcn_s_barrier();
    __builtin_amdgcn_sched_barrier(0);
  }

  for (int t = 0; t < NT; ++t) {
    const int d = t & 1;
    bf16_t* bufc = lds8 + d * 32768;
    bf16_t* bufn = lds8 + (d ^ 1) * 32768;
    const bf16_t* Ah = bufc + wm * 8192;
    const bf16_t* Bh = bufc + 16384 + (wn >> 1) * 8192;
    const long ka1 = mapk<1>((long)(t + 1) * 64, 9);
    const long kb1 = mapk<2>((long)(t + 1) * 64, 9);
    const long ka2 = mapk<1>((long)(t + 2) * 64, 9);

    // ---- phase 0: read a(qr0)+b(qc0); issue Ah1(t+1); MFMA (0,0) ----
#pragma unroll
    for (int r = 0; r < 4; ++r)
#pragma unroll
      for (int kk = 0; kk < 2; ++kk) {
        int lrow = r * 16 + l15;
        int off = (lrow << 7) + (((kk << 6) + kgb) ^ ((lrow & 7) << 4));
        afr[r][kk] = *(const bf16x8*)((const char*)Ah + off);
      }
#pragma unroll
    for (int c = 0; c < 2; ++c)
#pragma unroll
      for (int kk = 0; kk < 2; ++kk) {
        int lrow = (wn & 1) * 64 + c * 16 + l15;
        int off = (lrow << 7) + (((kk << 6) + kgb) ^ ((lrow & 7) << 4));
        bfr[0][c][kk] = *(const bf16x8*)((const char*)Bh + off);
      }
    if (t + 1 < NT) stage_half8(A, LDA, rowBase, ka1, 1, bufn + 1 * 8192, tid);
    PH_PRE();
#pragma unroll
    for (int r = 0; r < 4; ++r)
#pragma unroll
      for (int c = 0; c < 2; ++c)
#pragma unroll
        for (int kk = 0; kk < 2; ++kk)
          acc[r][c] = __builtin_amdgcn_mfma_f32_16x16x32_bf16(
              afr[r][kk], bfr[0][c][kk], acc[r][c], 0, 0, 0);
    PH_POST();

    // ---- phase 1: read b(qc1); issue Bh0(t+1); MFMA (0,1) ----
#pragma unroll
    for (int c = 0; c < 2; ++c)
#pragma unroll
      for (int kk = 0; kk < 2; ++kk) {
        int lrow = (wn & 1) * 64 + 32 + c * 16 + l15;
        int off = (lrow << 7) + (((kk << 6) + kgb) ^ ((lrow & 7) << 4));
        bfr[1][c][kk] = *(const bf16x8*)((const char*)Bh + off);
      }
    if (t + 1 < NT) stage_half8(B, LDB, colBase, kb1, 0, bufn + 2 * 8192, tid);
    PH_PRE();
#pragma unroll
    for (int r = 0; r < 4; ++r)
#pragma unroll
      for (int c = 0; c < 2; ++c)
#pragma unroll
        for (int kk = 0; kk < 2; ++kk)
          acc[r][2 + c] = __builtin_amdgcn_mfma_f32_16x16x32_bf16(
              afr[r][kk], bfr[1][c][kk], acc[r][2 + c], 0, 0, 0);
    PH_POST();

    // ---- phase 2: read a(qr1); issue Bh1(t+1); MFMA (1,0) ----
#pragma unroll
    for (int r = 0; r < 4; ++r)
#pragma unroll
      for (int kk = 0; kk < 2; ++kk) {
        int lrow = 64 + r * 16 + l15;
        int off = (lrow << 7) + (((kk << 6) + kgb) ^ ((lrow & 7) << 4));
        afr[r][kk] = *(const bf16x8*)((const char*)Ah + off);
      }
    if (t + 1 < NT) stage_half8(B, LDB, colBase, kb1, 1, bufn + 3 * 8192, tid);
    PH_PRE();
#pragma unroll
    for (int r = 0; r < 4; ++r)
#pragma unroll
      for (int c = 0; c < 2; ++c)
#pragma unroll
        for (int kk = 0; kk < 2; ++kk)
          acc[4 + r][c] = __builtin_amdgcn_mfma_f32_16x16x32_bf16(
              afr[r][kk], bfr[0][c][kk], acc[4 + r][c], 0, 0, 0);
    PH_POST();

    // ---- phase 3: issue Ah0(t+2); MFMA (1,1); boundary vmcnt ----
    if (t + 2 < NT) stage_half8(A, LDA, rowBase, ka2, 0, bufc + 0 * 8192, tid);
    __builtin_amdgcn_s_barrier();
    __builtin_amdgcn_s_setprio(1);
#pragma unroll
    for (int r = 0; r < 4; ++r)
#pragma unroll
      for (int c = 0; c < 2; ++c)
#pragma unroll
        for (int kk = 0; kk < 2; ++kk)
          acc[4 + r][2 + c] = __builtin_amdgcn_mfma_f32_16x16x32_bf16(
              afr[r][kk], bfr[1][c][kk], acc[4 + r][2 + c], 0, 0, 0);
    __builtin_amdgcn_s_setprio(0);
    if (t < NT - 2) { asm volatile("s_waitcnt vmcnt(2)" ::: "memory"); }
    else            { asm volatile("s_waitcnt vmcnt(0)" ::: "memory"); }
    __builtin_amdgcn_s_barrier();
    __builtin_amdgcn_sched_barrier(0);
  }

  // ---- epilogue: exp + ra/rb + bf16 store + fused column partial sums ----
  __syncthreads();
  float* cs = (float*)lds8;  // [2][256]
  float rbv_[4];
#pragma unroll
  for (int cf = 0; cf < 4; ++cf)
    rbv_[cf] = rb[(long)z * N + colBase + wn * 64 + cf * 16 + l15];
  float csum[4] = {0.f, 0.f, 0.f, 0.f};
#pragma unroll
  for (int qr = 0; qr < 2; ++qr)
#pragma unroll
    for (int r = 0; r < 4; ++r) {
      long row0 = rowBase + wm * 128 + qr * 64 + r * 16 + ((lane >> 4) << 2);
      float4 ra4 = *(const float4*)(ra + (long)z * M + row0);
#pragma unroll
      for (int cf = 0; cf < 4; ++cf) {
        long col = colBase + wn * 64 + cf * 16 + l15;
        f32x4 v4 = acc[qr * 4 + r][cf];
        float rr[4] = {ra4.x, ra4.y, ra4.z, ra4.w};
#pragma unroll
        for (int e = 0; e < 4; ++e) {
          float v = __expf(v4[e] + rr[e] + rbv_[cf]);
          C[(row0 + e) * (long)N + col] = (bf16_t)v;
          csum[cf] += v;
        }
      }
    }
#pragma unroll
  for (int cf = 0; cf < 4; ++cf) {
    float s = csum[cf];
    s += __shfl_xor(s, 16);
    s += __shfl_xor(s, 32);
    if (lane < 16) cs[wm * 256 + wn * 64 + cf * 16 + lane] = s;
  }
  __syncthreads();
  if (tid < 256)
    part[((long)by * gridDim.z + z) * N + colBase + tid] = cs[tid] + cs[256 + tid];
}

// ------------------------------------------------------------------
// 128x128 m97-structure GEMM (unchanged) for the remaining ops.
// ------------------------------------------------------------------
template <typename OutT, int OUTMODE, int AMAP, int BMAP>
__global__ __launch_bounds__(256) void gemm_bt(
    const bf16_t* __restrict__ A, const bf16_t* __restrict__ B,
    OutT* __restrict__ C, const float* __restrict__ bias,
    float scale, int M, int N, int K, long lda, long ldb,
    long sA, long sB, long sC, long kz, int sshift)
{
  __shared__ __align__(16) bf16_t As[128 * 64];
  __shared__ __align__(16) bf16_t Bs[128 * 64];
  const int z = blockIdx.z;
  A += (long)z * sA; B += (long)z * sB; C += (long)z * sC;

  const int gx = gridDim.x;
  const int nwg = gx * gridDim.y;
  const int id = blockIdx.y * gx + blockIdx.x;
  const int qq = nwg >> 3, rr = nwg & 7;
  const int xcd = id & 7, jj = id >> 3;
  const int swz = (xcd < rr ? xcd * (qq + 1) : rr * (qq + 1) + (xcd - rr) * qq) + jj;
  const int bx = swz % gx, by = swz / gx;

  const int tid  = threadIdx.x;
  const int lane = tid & 63;
  const int wid  = tid >> 6;
  const int wr = (wid >> 1) * 64;
  const int wc = (wid & 1) * 64;
  const long rowBase = (long)by * 128;
  const long colBase = (long)bx * 128;

  f32x4 acc[4][4] = {};

  int srow[4], scol[4];
#pragma unroll
  for (int i = 0; i < 4; ++i) {
    int li = i * 256 + tid;
    int row = li >> 3;
    int inner = (li & 7) << 4;
    int src = inner ^ ((row & 7) << 4);
    srow[i] = row;
    scol[i] = src >> 1;
  }

  for (int k0 = 0; k0 < K; k0 += 64) {
    const long k0L = kz * z + k0;
    const long ka = mapk<AMAP>(k0L, sshift);
    const long kb = mapk<BMAP>(k0L, sshift);
    __syncthreads();
#pragma unroll
    for (int i = 0; i < 4; ++i) {
      int li = i * 256 + tid;
      gload_lds16(A + (rowBase + srow[i]) * lda + ka + scol[i], (char*)As + li * 16);
      gload_lds16(B + (colBase + srow[i]) * ldb + kb + scol[i], (char*)Bs + li * 16);
    }
    __syncthreads();
#pragma unroll
    for (int kk = 0; kk < 64; kk += 32) {
      const int kbyte = (kk + ((lane >> 4) << 3)) << 1;
      bf16x8 af[4], bfr[4];
#pragma unroll
      for (int m = 0; m < 4; ++m) {
        int row = wr + m * 16 + (lane & 15);
        int off = (row << 7) + (kbyte ^ ((row & 7) << 4));
        af[m] = *(const bf16x8*)((const char*)As + off);
      }
#pragma unroll
      for (int n = 0; n < 4; ++n) {
        int row = wc + n * 16 + (lane & 15);
        int off = (row << 7) + (kbyte ^ ((row & 7) << 4));
        bfr[n] = *(const bf16x8*)((const char*)Bs + off);
      }
#pragma unroll
      for (int m = 0; m < 4; ++m)
#pragma unroll
        for (int n = 0; n < 4; ++n)
          acc[m][n] = __builtin_amdgcn_mfma_f32_16x16x32_bf16(af[m], bfr[n], acc[m][n], 0, 0, 0);
    }
  }

  if (OUTMODE == 2) {
#pragma unroll
    for (int n = 0; n < 4; ++n) {
      const long col = colBase + wc + n * 16 + (lane & 15);
#pragma unroll
      for (int m = 0; m < 4; ++m) {
#pragma unroll
        for (int e = 0; e < 4; ++e) {
          const long row = rowBase + wr + m * 16 + (lane >> 4) * 4 + e;
          float v = acc[m][n][e] * scale;
          bf16_t h = (bf16_t)v;
          bf16_t l = (bf16_t)(v - (float)h);
          C[row * (2L * N) + col] = (OutT)h;
          C[row * (2L * N) + N + col] = (OutT)l;
        }
      }
    }
  } else {
#pragma unroll
    for (int n = 0; n < 4; ++n) {
      const long col = colBase + wc + n * 16 + (lane & 15);
      const float bv_ = bias ? bias[col] : 0.0f;
#pragma unroll
      for (int m = 0; m < 4; ++m) {
#pragma unroll
        for (int e = 0; e < 4; ++e) {
          const long row = rowBase + wr + m * 16 + (lane >> 4) * 4 + e;
          C[row * (long)N + col] = (OutT)((acc[m][n][e] + bv_) * scale);
        }
      }
    }
  }
}

// f32 [R,C] -> bf16 [R,2C] = (h|l), vectorized x4
__global__ void split2(const float* __restrict__ in, bf16_t* __restrict__ out,
                       long n, int cshift) {
  long C = 1L << cshift;
  long i0 = ((long)blockIdx.x * blockDim.x + threadIdx.x) * 4;
  long stride = (long)gridDim.x * blockDim.x * 4;
  for (long i = i0; i < n; i += stride) {
    float4 f = *(const float4*)(in + i);
    long r = i >> cshift, c = i & (C - 1);
    union { ushort4 u; bf16_t h[4]; } H, L;
    float fv[4] = {f.x, f.y, f.z, f.w};
#pragma unroll
    for (int j = 0; j < 4; ++j) {
      bf16_t h = (bf16_t)fv[j];
      H.h[j] = h;
      L.h[j] = (bf16_t)(fv[j] - (float)h);
    }
    *(ushort4*)(out + r * 2 * C + c) = H.u;
    *(ushort4*)(out + r * 2 * C + C + c) = L.u;
  }
}

// f32 [R,C] -> bf16 [C,2R] = (h|l) of the transpose
__global__ void transpose_split2(const float* __restrict__ in, bf16_t* __restrict__ out,
                                 int R, int C) {
  __shared__ float tile[32][33];
  int c0 = blockIdx.x * 32, r0 = blockIdx.y * 32;
  int tx = threadIdx.x & 31, ty = threadIdx.x >> 5;
#pragma unroll
  for (int i = 0; i < 32; i += 8)
    tile[ty + i][tx] = in[(long)(r0 + ty + i) * C + (c0 + tx)];
  __syncthreads();
#pragma unroll
  for (int i = 0; i < 32; i += 8) {
    float x = tile[tx][ty + i];
    bf16_t h = (bf16_t)x;
    bf16_t l = (bf16_t)(x - (float)h);
    long o = (long)(c0 + ty + i) * 2 * R + (r0 + tx);
    out[o] = h;
    out[o + R] = l;
  }
}

__global__ void cast_f32_bf16(const float* __restrict__ in, bf16_t* __restrict__ out, long n) {
  long i0 = ((long)blockIdx.x * blockDim.x + threadIdx.x) * 4;
  long stride = (long)gridDim.x * blockDim.x * 4;
  for (long i = i0; i < n; i += stride) {
    float4 f = *(const float4*)(in + i);
    union { ushort4 u; bf16_t h[4]; } o;
    o.h[0] = (bf16_t)f.x; o.h[1] = (bf16_t)f.y; o.h[2] = (bf16_t)f.z; o.h[3] = (bf16_t)f.w;
    *(ushort4*)(out + i) = o.u;
  }
}

__global__ void reduce2(const float* __restrict__ gp, const float* __restrict__ wp,
                        float* __restrict__ Gt, bf16_t* __restrict__ WvoTb,
                        float scale, int nElem, int nParts) {
  int i = blockIdx.x * 256 + threadIdx.x;
  if (i < nElem) {
    float a = 0.f, b = 0.f;
    for (int p = 0; p < nParts; ++p) {
      a += gp[(long)p * nElem + i];
      b += wp[(long)p * nElem + i];
    }
    Gt[i] = scale * a;
    WvoTb[i] = (bf16_t)b;
  }
}

__device__ __forceinline__ float bf2f(unsigned short u) {
  union { unsigned u32; float f; } x; x.u32 = ((unsigned)u) << 16; return x.f;
}

// rank-1 bias prep: y=0 wqbk=Wq.bk; y=1 wkbq=Wk.bq; y=2 bvo=WoT.bv (via WoS);
// y=3 cdot=bq.bk
__global__ void rank1(const float* __restrict__ Wq, const float* __restrict__ bk,
                      const float* __restrict__ Wk, const float* __restrict__ bq,
                      const bf16_t* __restrict__ WoS, const float* __restrict__ bv,
                      float* __restrict__ wqbk, float* __restrict__ wkbq,
                      float* __restrict__ bvo, float* __restrict__ cdot) {
  __shared__ float red[256];
  int y = blockIdx.y, bx = blockIdx.x, t = threadIdx.x;
  float s = 0.f;
  if (y == 0) {
    for (int j = t; j < PROJ; j += 256) s += Wq[(long)bx * PROJ + j] * bk[j];
  } else if (y == 1) {
    for (int j = t; j < PROJ; j += 256) s += Wk[(long)bx * PROJ + j] * bq[j];
  } else if (y == 2) {
    const bf16_t* row = WoS + (long)bx * 2 * PROJ;
    for (int j = t; j < PROJ; j += 256)
      s += ((float)row[j] + (float)row[PROJ + j]) * bv[j];
  } else {
    if (bx != 0) return;
    for (int j = t; j < PROJ; j += 256) s += bq[j] * bk[j];
  }
  red[t] = s; __syncthreads();
  for (int w = 128; w > 0; w >>= 1) {
    if (t < w) red[t] += red[t + w];
    __syncthreads();
  }
  if (t == 0) {
    if (y == 0) wqbk[bx] = red[0];
    else if (y == 1) wkbq[bx] = red[0];
    else if (y == 2) bvo[bx] = red[0];
    else *cdot = red[0];
  }
}

__global__ void rowdot2(const float* __restrict__ q, const float* __restrict__ k,
                        const float* __restrict__ wqbk, const float* __restrict__ wkbq,
                        const float* __restrict__ cdot,
                        float* __restrict__ rav, float* __restrict__ rbv) {
  __shared__ float red[256];
  int r = blockIdx.x, y = blockIdx.y, t = threadIdx.x;
  const float* X = y ? k : q;
  const float* w_ = y ? wkbq : wqbk;
  float s = 0.f;
  for (int j = t; j < HID; j += 256) s += X[(long)r * HID + j] * w_[j];
  red[t] = s; __syncthreads();
  for (int w = 128; w > 0; w >>= 1) {
    if (t < w) red[t] += red[t + w];
    __syncthreads();
  }
  if (t == 0) {
    float v = red[0] + (y ? 0.f : *cdot);
    (y ? rbv : rav)[r] = SCALE * v;
  }
}

__global__ void colsum_final(const float* __restrict__ part, float* __restrict__ crcp,
                             int Nm, int nParts) {
  int b = blockIdx.y;
  int m = blockIdx.x * 256 + threadIdx.x;
  float s = 0.f;
  for (int p = 0; p < nParts; ++p)
    s += part[((long)p * gridDim.y + b) * Nm + m];
  crcp[(long)b * Nm + m] = 1.0f / s;
}

__global__ void transpose_scale_bf16(const bf16_t* __restrict__ in, const float* __restrict__ crcp,
                                     bf16_t* __restrict__ out, int R, int C, long sIn, long sOut) {
  __shared__ bf16_t tile[64][68];
  int z = blockIdx.z;
  const bf16_t* ip = in + (long)z * sIn;
  bf16_t* op = out + (long)z * sOut;
  const float* rc = crcp + (long)z * R;
  int c0 = blockIdx.x * 64, r0 = blockIdx.y * 64;
#pragma unroll
  for (int i = 0; i < 4; ++i) {
    int chunk = i * 256 + threadIdx.x;
    int r = chunk >> 4, c4 = (chunk & 15) << 2;
    float s = rc[r0 + r];
    ushort4 uv = *(const ushort4*)(ip + (long)(r0 + r) * C + (c0 + c4));
    tile[r][c4 + 0] = (bf16_t)(bf2f(uv.x) * s);
    tile[r][c4 + 1] = (bf16_t)(bf2f(uv.y) * s);
    tile[r][c4 + 2] = (bf16_t)(bf2f(uv.z) * s);
    tile[r][c4 + 3] = (bf16_t)(bf2f(uv.w) * s);
  }
  __syncthreads();
#pragma unroll
  for (int i = 0; i < 4; ++i) {
    int chunk = i * 256 + threadIdx.x;
    int oc = chunk >> 4, or4 = (chunk & 15) << 2;
    union { ushort4 u; bf16_t h[4]; } o;
    o.h[0] = tile[or4 + 0][oc];
    o.h[1] = tile[or4 + 1][oc];
    o.h[2] = tile[or4 + 2][oc];
    o.h[3] = tile[or4 + 3][oc];
    *(ushort4*)(op + (long)(c0 + oc) * R + (r0 + or4)) = o.u;
  }
}

extern "C" void kernel_launch(void* const* d_in, const int* in_sizes, int n_in,
                              void* d_out, int out_size, void* d_ws, size_t ws_size,
                              hipStream_t stream)
{
  (void)in_sizes; (void)n_in; (void)out_size; (void)ws_size;
  const float* q  = (const float*)d_in[0];
  const float* k  = (const float*)d_in[1];
  const float* v  = (const float*)d_in[2];
  const float* Wq = (const float*)d_in[3];
  const float* bq = (const float*)d_in[4];
  const float* Wk = (const float*)d_in[5];
  const float* bk = (const float*)d_in[6];
  const float* Wv = (const float*)d_in[7];
  const float* bv = (const float*)d_in[8];
  const float* Wo = (const float*)d_in[9];
  const float* bo = (const float*)d_in[10];
  float* out = (float*)d_out;

  char* ws = (char*)d_ws;
  const size_t MB = 1u << 20;
  bf16_t* qcat  = (bf16_t*)(ws);              // [0,16)   [8192,1024] (h|l)
  bf16_t* kcat  = (bf16_t*)(ws + 16 * MB);    // [16,32)
  bf16_t* GA    = (bf16_t*)(ws + 32 * MB);    // [32,40)  Wk  [512,8192]
  bf16_t* GB    = (bf16_t*)(ws + 40 * MB);    // [40,48)  Wq
  bf16_t* WoS   = (bf16_t*)(ws + 48 * MB);    // [48,56)  Wo^T [512,8192]
  bf16_t* WvS   = (bf16_t*)(ws + 56 * MB);    // [56,64)  Wv
  float*  Gpart = (float*)(ws + 64 * MB);     // [64,80)  16x[512,512]
  float*  WvoTp = (float*)(ws + 80 * MB);     // [80,96)
  float*  Gt    = (float*)(ws + 96 * MB);     // [96,97)
  bf16_t* Gtcat = (bf16_t*)(ws + 97 * MB);    // [97,98)  [512,1024]
  bf16_t* WvoTb = (bf16_t*)(ws + 98 * MB);    // [98,98.5)
  float*  bvo   = (float*)(ws + 99 * MB);
  float*  wqbk  = (float*)(ws + 99 * MB + 16 * 1024);
  float*  wkbq  = (float*)(ws + 99 * MB + 32 * 1024);
  float*  cdot  = (float*)(ws + 99 * MB + 48 * 1024);
  float*  rav   = (float*)(ws + 99 * MB + 64 * 1024);   // 32 KB
  float*  rbv   = (float*)(ws + 99 * MB + 128 * 1024);  // 32 KB
  float*  crcp  = (float*)(ws + 99 * MB + 192 * 1024);  // 32 KB
  float*  part  = (float*)(ws + 99 * MB + 256 * 1024);  // 256 KB (8x4x2048 f32)
  bf16_t* tcat  = (bf16_t*)(ws + 100 * MB);   // [100,116) [8192,1024]
  bf16_t* vbf   = (bf16_t*)(ws + 116 * MB);   // [116,124)
  bf16_t* vo    = (bf16_t*)(ws + 124 * MB);   // [124,132) [8192,512]
  bf16_t* vosT  = (bf16_t*)(ws + 132 * MB);   // [132,140) [B][512,2048]
  bf16_t* P     = (bf16_t*)(ws + 140 * MB);   // [140,172) [B][2048,2048]

  // splits
  split2<<<2048, 256, 0, stream>>>(q,  qcat, NROW * HID, 9);
  split2<<<2048, 256, 0, stream>>>(k,  kcat, NROW * HID, 9);
  split2<<<2048, 256, 0, stream>>>(Wk, GA, (long)HID * PROJ, 12);
  split2<<<2048, 256, 0, stream>>>(Wq, GB, (long)HID * PROJ, 12);
  split2<<<2048, 256, 0, stream>>>(Wv, WvS, (long)HID * PROJ, 12);
  transpose_split2<<<dim3(HID / 32, PROJ / 32), 256, 0, stream>>>(Wo, WoS, PROJ, HID);

  // Gt = SCALE*Wk.Wq^T ; WvoT = Wo^T.Wv^T (K=12288 z-split 16)
  gemm_bt<float, 0, 1, 2><<<dim3(4, 4, 16), 256, 0, stream>>>(GA, GB, Gpart,
      nullptr, 1.0f, HID, HID, 768, 2L * PROJ, 2L * PROJ,
      0, 0, (long)HID * HID, 768, 12);
  gemm_bt<float, 0, 1, 2><<<dim3(4, 4, 16), 256, 0, stream>>>(WoS, WvS, WvoTp,
      nullptr, 1.0f, HID, HID, 768, 2L * PROJ, 2L * PROJ,
      0, 0, (long)HID * HID, 768, 12);
  reduce2<<<(HID * HID + 255) / 256, 256, 0, stream>>>(Gpart, WvoTp, Gt, WvoTb,
      SCALE, HID * HID, 16);
  split2<<<1024, 256, 0, stream>>>(Gt, Gtcat, (long)HID * HID, 9);

  // rank-1 bias terms
  rank1<<<dim3(HID, 4), 256, 0, stream>>>(Wq, bk, Wk, bq, WoS, bv, wqbk, wkbq, bvo, cdot);
  rowdot2<<<dim3((int)NROW, 2), 256, 0, stream>>>(q, k, wqbk, wkbq, cdot, rav, rbv);

  // t = q.Gt^T (split x split, K=1536), h/l split written directly
  gemm_bt<bf16_t, 2, 1, 2><<<dim3(4, 64, 1), 256, 0, stream>>>(qcat, Gtcat, tcat,
      nullptr, 1.0f, (int)NROW, HID, 1536, 1024, 1024, 0, 0, 0, 0, 9);

  cast_f32_bf16<<<2048, 256, 0, stream>>>(v, vbf, NROW * HID);

  // P = exp(t.k^T + ra + rb) — 8-phase 256^2 kernel, fused col partial sums
  gemm8exp<<<dim3(8, 8, BSZ), 512, 0, stream>>>(tcat, kcat, P, rav, rbv, part);
  colsum_final<<<dim3(SEQ / 256, BSZ), 256, 0, stream>>>(part, crcp, SEQ, 8);

  // vo = v.Wvo + bvo
  gemm_bt<bf16_t, 0, 0, 0><<<dim3(4, 64, 1), 256, 0, stream>>>(vbf, WvoTb, vo,
      bvo, 1.0f, (int)NROW, HID, HID, HID, HID, 0, 0, 0, 0, 0);
  // vosT[z][d,m] = vo[z][m,d] / csum[z][m]
  transpose_scale_bf16<<<dim3(HID / 64, SEQ / 64, BSZ), 256, 0, stream>>>(
      vo, crcp, vosT, SEQ, HID, (long)SEQ * HID, (long)HID * SEQ);

  // out = P.vosT^T + bo
  gemm_bt<float, 0, 0, 0><<<dim3(4, 16, BSZ), 256, 0, stream>>>(P, vosT, out,
      bo, 1.0f, SEQ, HID, SEQ, SEQ, SEQ,
      (long)SEQ * SEQ, (long)HID * SEQ, (long)SEQ * HID, 0, 0);
}

// Round 7
// 252.460 us; speedup vs baseline: 1.6249x; 1.0118x over previous
//
#include <hip/hip_runtime.h>
#include <hip/hip_bf16.h>

#define AS1 __attribute__((address_space(1)))
#define AS3 __attribute__((address_space(3)))

typedef __bf16 bf16_t;
typedef __attribute__((ext_vector_type(8))) __bf16 bf16x8;
typedef __attribute__((ext_vector_type(4))) float f32x4;

static constexpr int BSZ = 4, SEQ = 2048, HID = 512, PROJ = 4096;
static constexpr long NROW = (long)BSZ * SEQ;  // 8192
static constexpr float SCALE = 0.125f;

__device__ __forceinline__ void gload_lds16(const void* g, void* l) {
  __builtin_amdgcn_global_load_lds((const AS1 void*)g, (AS3 void*)l, 16, 0, 0);
}

// map logical K index -> storage col for 2-wide [h|l] split buffers.
// MAP 0: identity. MAP 1: logical thirds (h,l,h). MAP 2: logical thirds (h,h,l).
template <int MAP>
__device__ __forceinline__ long mapk(long c, int s) {
  if (MAP == 0) return c;
  long w = c & ((1L << s) - 1);
  long t = c >> s;
  bool lo = (MAP == 1) ? (t == 1) : (t == 2);
  return (lo ? (1L << s) : 0) + w;
}

// ==================================================================
// 8-phase 256x256 GEMM for P = exp(t.k^T + ra + rb) with fused column
// partial sums. A=tcat (thirds h,l,h), B=kcat (h,h,l), K=1536, z=4.
// 512 threads = 8 waves (2M x 4N), BK=64, LDS 128KB = 2 bufs x
// {A0,A1,B0,B1} half-tiles (128x64 bf16 = 16KB each).
// DEEP STAGING (r6): during tile t stage tile t+2 into the SAME buffer
// parity: B-halves at ph2 (B last ds_read at ph1), A-halves at ph3
// (A last ds_read at ph2). Boundary s_waitcnt vmcnt(8) keeps this
// tile's 4 stages (8 loads/wave) outstanding; issue-to-wait >= 4 phases.
// ==================================================================
__device__ __forceinline__ void stage_half8(
    const bf16_t* __restrict__ G, long ldg, long rcBase, long kcol,
    int half, bf16_t* dst, int tid)
{
#pragma unroll
  for (int it = 0; it < 2; ++it) {
    int li = it * 512 + tid;
    int row = li >> 3;
    int srcb = ((li & 7) << 4) ^ ((row & 7) << 4);
    gload_lds16(G + (rcBase + half * 128 + row) * ldg + kcol + (srcb >> 1),
                (char*)dst + li * 16);
  }
}

#define PH_PRE()  __builtin_amdgcn_s_barrier(); \
                  asm volatile("s_waitcnt lgkmcnt(0)" ::: "memory"); \
                  __builtin_amdgcn_sched_barrier(0); \
                  __builtin_amdgcn_s_setprio(1);
#define PH_POST() __builtin_amdgcn_s_setprio(0); \
                  __builtin_amdgcn_s_barrier(); \
                  __builtin_amdgcn_sched_barrier(0);

__global__ __launch_bounds__(512, 2) void gemm8exp(
    const bf16_t* __restrict__ A, const bf16_t* __restrict__ B,
    bf16_t* __restrict__ C, const float* __restrict__ ra,
    const float* __restrict__ rb, float* __restrict__ part)
{
  constexpr int NT = 24;            // K = 1536
  constexpr long LDA = 1024, LDB = 1024;
  constexpr int M = 2048, N = 2048;
  __shared__ __align__(16) bf16_t lds8[65536];  // 128 KB

  const int z = blockIdx.z;
  A += (long)z * SEQ * LDA;
  B += (long)z * SEQ * LDB;
  C += (long)z * (long)SEQ * SEQ;

  // bijective XCD swizzle (nwg=64 per plane): XCD c owns block-row by=c
  const int id0 = blockIdx.y * 8 + blockIdx.x;
  const int swz = (id0 & 7) * 8 + (id0 >> 3);
  const int bx = swz & 7, by = swz >> 3;
  const long rowBase = (long)by * 256;
  const long colBase = (long)bx * 256;

  const int tid = threadIdx.x;
  const int lane = tid & 63;
  const int wid = tid >> 6;
  const int wm = wid >> 2;          // 0..1 (M)
  const int wn = wid & 3;           // 0..3 (N)
  const int l15 = lane & 15;
  const int kgb = (lane >> 4) << 4; // byte offset of lane's k-group

  f32x4 acc[8][4] = {};
  bf16x8 afr[4][2];                 // current quadrant-row A frags
  bf16x8 bfr[2][2][2];              // [qc][c][kk]

  // prologue: tile0 -> buf0, tile1 -> buf1; drain tile0 (vmcnt(8))
  {
    const long ka0 = mapk<1>(0, 9), kb0 = mapk<2>(0, 9);
    const long ka1 = mapk<1>(64, 9), kb1 = mapk<2>(64, 9);
    stage_half8(B, LDB, colBase, kb0, 0, lds8 + 2 * 8192, tid);
    stage_half8(B, LDB, colBase, kb0, 1, lds8 + 3 * 8192, tid);
    stage_half8(A, LDA, rowBase, ka0, 0, lds8 + 0 * 8192, tid);
    stage_half8(A, LDA, rowBase, ka0, 1, lds8 + 1 * 8192, tid);
    stage_half8(B, LDB, colBase, kb1, 0, lds8 + 32768 + 2 * 8192, tid);
    stage_half8(B, LDB, colBase, kb1, 1, lds8 + 32768 + 3 * 8192, tid);
    stage_half8(A, LDA, rowBase, ka1, 0, lds8 + 32768 + 0 * 8192, tid);
    stage_half8(A, LDA, rowBase, ka1, 1, lds8 + 32768 + 1 * 8192, tid);
    asm volatile("s_waitcnt vmcnt(8)" ::: "memory");
    __builtin_amdgcn_s_barrier();
    __builtin_amdgcn_sched_barrier(0);
  }

  for (int t = 0; t < NT; ++t) {
    const int d = t & 1;
    bf16_t* bufc = lds8 + d * 32768;
    const bf16_t* Ah = bufc + wm * 8192;
    const bf16_t* Bh = bufc + 16384 + (wn >> 1) * 8192;
    const bool pf = (t + 2 < NT);
    const long ka2 = mapk<1>((long)(t + 2) * 64, 9);
    const long kb2 = mapk<2>((long)(t + 2) * 64, 9);

    // ---- phase 0: read a(qr0)+b(qc0); MFMA (0,0) ----
#pragma unroll
    for (int r = 0; r < 4; ++r)
#pragma unroll
      for (int kk = 0; kk < 2; ++kk) {
        int lrow = r * 16 + l15;
        int off = (lrow << 7) + (((kk << 6) + kgb) ^ ((lrow & 7) << 4));
        afr[r][kk] = *(const bf16x8*)((const char*)Ah + off);
      }
#pragma unroll
    for (int c = 0; c < 2; ++c)
#pragma unroll
      for (int kk = 0; kk < 2; ++kk) {
        int lrow = (wn & 1) * 64 + c * 16 + l15;
        int off = (lrow << 7) + (((kk << 6) + kgb) ^ ((lrow & 7) << 4));
        bfr[0][c][kk] = *(const bf16x8*)((const char*)Bh + off);
      }
    PH_PRE();
#pragma unroll
    for (int r = 0; r < 4; ++r)
#pragma unroll
      for (int c = 0; c < 2; ++c)
#pragma unroll
        for (int kk = 0; kk < 2; ++kk)
          acc[r][c] = __builtin_amdgcn_mfma_f32_16x16x32_bf16(
              afr[r][kk], bfr[0][c][kk], acc[r][c], 0, 0, 0);
    PH_POST();

    // ---- phase 1: read b(qc1); MFMA (0,1) ----
#pragma unroll
    for (int c = 0; c < 2; ++c)
#pragma unroll
      for (int kk = 0; kk < 2; ++kk) {
        int lrow = (wn & 1) * 64 + 32 + c * 16 + l15;
        int off = (lrow << 7) + (((kk << 6) + kgb) ^ ((lrow & 7) << 4));
        bfr[1][c][kk] = *(const bf16x8*)((const char*)Bh + off);
      }
    PH_PRE();
#pragma unroll
    for (int r = 0; r < 4; ++r)
#pragma unroll
      for (int c = 0; c < 2; ++c)
#pragma unroll
        for (int kk = 0; kk < 2; ++kk)
          acc[r][2 + c] = __builtin_amdgcn_mfma_f32_16x16x32_bf16(
              afr[r][kk], bfr[1][c][kk], acc[r][2 + c], 0, 0, 0);
    PH_POST();

    // ---- phase 2: issue B(t+2) into bufc (B last read was ph1);
    //      read a(qr1); MFMA (1,0) ----
    if (pf) {
      stage_half8(B, LDB, colBase, kb2, 0, bufc + 2 * 8192, tid);
      stage_half8(B, LDB, colBase, kb2, 1, bufc + 3 * 8192, tid);
    }
#pragma unroll
    for (int r = 0; r < 4; ++r)
#pragma unroll
      for (int kk = 0; kk < 2; ++kk) {
        int lrow = 64 + r * 16 + l15;
        int off = (lrow << 7) + (((kk << 6) + kgb) ^ ((lrow & 7) << 4));
        afr[r][kk] = *(const bf16x8*)((const char*)Ah + off);
      }
    PH_PRE();
#pragma unroll
    for (int r = 0; r < 4; ++r)
#pragma unroll
      for (int c = 0; c < 2; ++c)
#pragma unroll
        for (int kk = 0; kk < 2; ++kk)
          acc[4 + r][c] = __builtin_amdgcn_mfma_f32_16x16x32_bf16(
              afr[r][kk], bfr[0][c][kk], acc[4 + r][c], 0, 0, 0);
    PH_POST();

    // ---- phase 3: issue A(t+2) into bufc (A last read was ph2);
    //      MFMA (1,1); boundary vmcnt keeps this tile's stages in flight ----
    if (pf) {
      stage_half8(A, LDA, rowBase, ka2, 0, bufc + 0 * 8192, tid);
      stage_half8(A, LDA, rowBase, ka2, 1, bufc + 1 * 8192, tid);
    }
    __builtin_amdgcn_s_setprio(1);
#pragma unroll
    for (int r = 0; r < 4; ++r)
#pragma unroll
      for (int c = 0; c < 2; ++c)
#pragma unroll
        for (int kk = 0; kk < 2; ++kk)
          acc[4 + r][2 + c] = __builtin_amdgcn_mfma_f32_16x16x32_bf16(
              afr[r][kk], bfr[1][c][kk], acc[4 + r][2 + c], 0, 0, 0);
    __builtin_amdgcn_s_setprio(0);
    if (pf) { asm volatile("s_waitcnt vmcnt(8)" ::: "memory"); }
    else    { asm volatile("s_waitcnt vmcnt(0)" ::: "memory"); }
    __builtin_amdgcn_s_barrier();
    __builtin_amdgcn_sched_barrier(0);
  }

  // ---- epilogue: exp + ra/rb + bf16 store + fused column partial sums ----
  __syncthreads();
  float* cs = (float*)lds8;  // [2][256]
  float rbv_[4];
#pragma unroll
  for (int cf = 0; cf < 4; ++cf)
    rbv_[cf] = rb[(long)z * N + colBase + wn * 64 + cf * 16 + l15];
  float csum[4] = {0.f, 0.f, 0.f, 0.f};
#pragma unroll
  for (int qr = 0; qr < 2; ++qr)
#pragma unroll
    for (int r = 0; r < 4; ++r) {
      long row0 = rowBase + wm * 128 + qr * 64 + r * 16 + ((lane >> 4) << 2);
      float4 ra4 = *(const float4*)(ra + (long)z * M + row0);
#pragma unroll
      for (int cf = 0; cf < 4; ++cf) {
        long col = colBase + wn * 64 + cf * 16 + l15;
        f32x4 v4 = acc[qr * 4 + r][cf];
        float rr[4] = {ra4.x, ra4.y, ra4.z, ra4.w};
#pragma unroll
        for (int e = 0; e < 4; ++e) {
          float v = __expf(v4[e] + rr[e] + rbv_[cf]);
          C[(row0 + e) * (long)N + col] = (bf16_t)v;
          csum[cf] += v;
        }
      }
    }
#pragma unroll
  for (int cf = 0; cf < 4; ++cf) {
    float s = csum[cf];
    s += __shfl_xor(s, 16);
    s += __shfl_xor(s, 32);
    if (lane < 16) cs[wm * 256 + wn * 64 + cf * 16 + lane] = s;
  }
  __syncthreads();
  if (tid < 256)
    part[((long)by * gridDim.z + z) * N + colBase + tid] = cs[tid] + cs[256 + tid];
}

// ------------------------------------------------------------------
// 128x128 m97-structure GEMM for the remaining ops.
// ------------------------------------------------------------------
template <typename OutT, int OUTMODE, int AMAP, int BMAP>
__global__ __launch_bounds__(256) void gemm_bt(
    const bf16_t* __restrict__ A, const bf16_t* __restrict__ B,
    OutT* __restrict__ C, const float* __restrict__ bias,
    float scale, int M, int N, int K, long lda, long ldb,
    long sA, long sB, long sC, long kz, int sshift)
{
  __shared__ __align__(16) bf16_t As[128 * 64];
  __shared__ __align__(16) bf16_t Bs[128 * 64];
  const int z = blockIdx.z;
  A += (long)z * sA; B += (long)z * sB; C += (long)z * sC;

  const int gx = gridDim.x;
  const int nwg = gx * gridDim.y;
  const int id = blockIdx.y * gx + blockIdx.x;
  const int qq = nwg >> 3, rr = nwg & 7;
  const int xcd = id & 7, jj = id >> 3;
  const int swz = (xcd < rr ? xcd * (qq + 1) : rr * (qq + 1) + (xcd - rr) * qq) + jj;
  const int bx = swz % gx, by = swz / gx;

  const int tid  = threadIdx.x;
  const int lane = tid & 63;
  const int wid  = tid >> 6;
  const int wr = (wid >> 1) * 64;
  const int wc = (wid & 1) * 64;
  const long rowBase = (long)by * 128;
  const long colBase = (long)bx * 128;

  f32x4 acc[4][4] = {};

  int srow[4], scol[4];
#pragma unroll
  for (int i = 0; i < 4; ++i) {
    int li = i * 256 + tid;
    int row = li >> 3;
    int inner = (li & 7) << 4;
    int src = inner ^ ((row & 7) << 4);
    srow[i] = row;
    scol[i] = src >> 1;
  }

  for (int k0 = 0; k0 < K; k0 += 64) {
    const long k0L = kz * z + k0;
    const long ka = mapk<AMAP>(k0L, sshift);
    const long kb = mapk<BMAP>(k0L, sshift);
    __syncthreads();
#pragma unroll
    for (int i = 0; i < 4; ++i) {
      int li = i * 256 + tid;
      gload_lds16(A + (rowBase + srow[i]) * lda + ka + scol[i], (char*)As + li * 16);
      gload_lds16(B + (colBase + srow[i]) * ldb + kb + scol[i], (char*)Bs + li * 16);
    }
    __syncthreads();
#pragma unroll
    for (int kk = 0; kk < 64; kk += 32) {
      const int kbyte = (kk + ((lane >> 4) << 3)) << 1;
      bf16x8 af[4], bfr[4];
#pragma unroll
      for (int m = 0; m < 4; ++m) {
        int row = wr + m * 16 + (lane & 15);
        int off = (row << 7) + (kbyte ^ ((row & 7) << 4));
        af[m] = *(const bf16x8*)((const char*)As + off);
      }
#pragma unroll
      for (int n = 0; n < 4; ++n) {
        int row = wc + n * 16 + (lane & 15);
        int off = (row << 7) + (kbyte ^ ((row & 7) << 4));
        bfr[n] = *(const bf16x8*)((const char*)Bs + off);
      }
#pragma unroll
      for (int m = 0; m < 4; ++m)
#pragma unroll
        for (int n = 0; n < 4; ++n)
          acc[m][n] = __builtin_amdgcn_mfma_f32_16x16x32_bf16(af[m], bfr[n], acc[m][n], 0, 0, 0);
    }
  }

  if (OUTMODE == 2) {
#pragma unroll
    for (int n = 0; n < 4; ++n) {
      const long col = colBase + wc + n * 16 + (lane & 15);
#pragma unroll
      for (int m = 0; m < 4; ++m) {
#pragma unroll
        for (int e = 0; e < 4; ++e) {
          const long row = rowBase + wr + m * 16 + (lane >> 4) * 4 + e;
          float v = acc[m][n][e] * scale;
          bf16_t h = (bf16_t)v;
          bf16_t l = (bf16_t)(v - (float)h);
          C[row * (2L * N) + col] = (OutT)h;
          C[row * (2L * N) + N + col] = (OutT)l;
        }
      }
    }
  } else {
#pragma unroll
    for (int n = 0; n < 4; ++n) {
      const long col = colBase + wc + n * 16 + (lane & 15);
      const float bv_ = bias ? bias[col] : 0.0f;
#pragma unroll
      for (int m = 0; m < 4; ++m) {
#pragma unroll
        for (int e = 0; e < 4; ++e) {
          const long row = rowBase + wr + m * 16 + (lane >> 4) * 4 + e;
          C[row * (long)N + col] = (OutT)((acc[m][n][e] + bv_) * scale);
        }
      }
    }
  }
}

// f32 [R,C] -> bf16 [R,2C] = (h|l), vectorized x4; up to 3 tensors batched
// via blockIdx.y.
__global__ void split2_b3(const float* __restrict__ in0, const float* __restrict__ in1,
                          const float* __restrict__ in2,
                          bf16_t* __restrict__ o0, bf16_t* __restrict__ o1,
                          bf16_t* __restrict__ o2, long n, int cshift) {
  const float* in = (blockIdx.y == 0) ? in0 : (blockIdx.y == 1) ? in1 : in2;
  bf16_t* out = (blockIdx.y == 0) ? o0 : (blockIdx.y == 1) ? o1 : o2;
  long C = 1L << cshift;
  long i0 = ((long)blockIdx.x * blockDim.x + threadIdx.x) * 4;
  long stride = (long)gridDim.x * blockDim.x * 4;
  for (long i = i0; i < n; i += stride) {
    float4 f = *(const float4*)(in + i);
    long r = i >> cshift, c = i & (C - 1);
    union { ushort4 u; bf16_t h[4]; } H, L;
    float fv[4] = {f.x, f.y, f.z, f.w};
#pragma unroll
    for (int j = 0; j < 4; ++j) {
      bf16_t h = (bf16_t)fv[j];
      H.h[j] = h;
      L.h[j] = (bf16_t)(fv[j] - (float)h);
    }
    *(ushort4*)(out + r * 2 * C + c) = H.u;
    *(ushort4*)(out + r * 2 * C + C + c) = L.u;
  }
}

// f32 [R,C] -> bf16 [C,2R] = (h|l) of the transpose
__global__ void transpose_split2(const float* __restrict__ in, bf16_t* __restrict__ out,
                                 int R, int C) {
  __shared__ float tile[32][33];
  int c0 = blockIdx.x * 32, r0 = blockIdx.y * 32;
  int tx = threadIdx.x & 31, ty = threadIdx.x >> 5;
#pragma unroll
  for (int i = 0; i < 32; i += 8)
    tile[ty + i][tx] = in[(long)(r0 + ty + i) * C + (c0 + tx)];
  __syncthreads();
#pragma unroll
  for (int i = 0; i < 32; i += 8) {
    float x = tile[tx][ty + i];
    bf16_t h = (bf16_t)x;
    bf16_t l = (bf16_t)(x - (float)h);
    long o = (long)(c0 + ty + i) * 2 * R + (r0 + tx);
    out[o] = h;
    out[o + R] = l;
  }
}

__global__ void cast_f32_bf16(const float* __restrict__ in, bf16_t* __restrict__ out, long n) {
  long i0 = ((long)blockIdx.x * blockDim.x + threadIdx.x) * 4;
  long stride = (long)gridDim.x * blockDim.x * 4;
  for (long i = i0; i < n; i += stride) {
    float4 f = *(const float4*)(in + i);
    union { ushort4 u; bf16_t h[4]; } o;
    o.h[0] = (bf16_t)f.x; o.h[1] = (bf16_t)f.y; o.h[2] = (bf16_t)f.z; o.h[3] = (bf16_t)f.w;
    *(ushort4*)(out + i) = o.u;
  }
}

__global__ void reduce2(const float* __restrict__ gp, const float* __restrict__ wp,
                        float* __restrict__ Gt, bf16_t* __restrict__ WvoTb,
                        float scale, int nElem, int nParts) {
  int i = blockIdx.x * 256 + threadIdx.x;
  if (i < nElem) {
    float a = 0.f, b = 0.f;
    for (int p = 0; p < nParts; ++p) {
      a += gp[(long)p * nElem + i];
      b += wp[(long)p * nElem + i];
    }
    Gt[i] = scale * a;
    WvoTb[i] = (bf16_t)b;
  }
}

__device__ __forceinline__ float bf2f(unsigned short u) {
  union { unsigned u32; float f; } x; x.u32 = ((unsigned)u) << 16; return x.f;
}

// rank-1 bias prep: y=0 wqbk=Wq.bk; y=1 wkbq=Wk.bq; y=2 bvo=WoT.bv (via WoS);
// y=3 cdot=bq.bk
__global__ void rank1(const float* __restrict__ Wq, const float* __restrict__ bk,
                      const float* __restrict__ Wk, const float* __restrict__ bq,
                      const bf16_t* __restrict__ WoS, const float* __restrict__ bv,
                      float* __restrict__ wqbk, float* __restrict__ wkbq,
                      float* __restrict__ bvo, float* __restrict__ cdot) {
  __shared__ float red[256];
  int y = blockIdx.y, bx = blockIdx.x, t = threadIdx.x;
  float s = 0.f;
  if (y == 0) {
    for (int j = t; j < PROJ; j += 256) s += Wq[(long)bx * PROJ + j] * bk[j];
  } else if (y == 1) {
    for (int j = t; j < PROJ; j += 256) s += Wk[(long)bx * PROJ + j] * bq[j];
  } else if (y == 2) {
    const bf16_t* row = WoS + (long)bx * 2 * PROJ;
    for (int j = t; j < PROJ; j += 256)
      s += ((float)row[j] + (float)row[PROJ + j]) * bv[j];
  } else {
    if (bx != 0) return;
    for (int j = t; j < PROJ; j += 256) s += bq[j] * bk[j];
  }
  red[t] = s; __syncthreads();
  for (int w = 128; w > 0; w >>= 1) {
    if (t < w) red[t] += red[t + w];
    __syncthreads();
  }
  if (t == 0) {
    if (y == 0) wqbk[bx] = red[0];
    else if (y == 1) wkbq[bx] = red[0];
    else if (y == 2) bvo[bx] = red[0];
    else *cdot = red[0];
  }
}

__global__ void rowdot2(const float* __restrict__ q, const float* __restrict__ k,
                        const float* __restrict__ wqbk, const float* __restrict__ wkbq,
                        const float* __restrict__ cdot,
                        float* __restrict__ rav, float* __restrict__ rbv) {
  __shared__ float red[256];
  int r = blockIdx.x, y = blockIdx.y, t = threadIdx.x;
  const float* X = y ? k : q;
  const float* w_ = y ? wkbq : wqbk;
  float s = 0.f;
  for (int j = t; j < HID; j += 256) s += X[(long)r * HID + j] * w_[j];
  red[t] = s; __syncthreads();
  for (int w = 128; w > 0; w >>= 1) {
    if (t < w) red[t] += red[t + w];
    __syncthreads();
  }
  if (t == 0) {
    float v = red[0] + (y ? 0.f : *cdot);
    (y ? rbv : rav)[r] = SCALE * v;
  }
}

__global__ void colsum_final(const float* __restrict__ part, float* __restrict__ crcp,
                             int Nm, int nParts) {
  int b = blockIdx.y;
  int m = blockIdx.x * 256 + threadIdx.x;
  float s = 0.f;
  for (int p = 0; p < nParts; ++p)
    s += part[((long)p * gridDim.y + b) * Nm + m];
  crcp[(long)b * Nm + m] = 1.0f / s;
}

__global__ void transpose_scale_bf16(const bf16_t* __restrict__ in, const float* __restrict__ crcp,
                                     bf16_t* __restrict__ out, int R, int C, long sIn, long sOut) {
  __shared__ bf16_t tile[64][68];
  int z = blockIdx.z;
  const bf16_t* ip = in + (long)z * sIn;
  bf16_t* op = out + (long)z * sOut;
  const float* rc = crcp + (long)z * R;
  int c0 = blockIdx.x * 64, r0 = blockIdx.y * 64;
#pragma unroll
  for (int i = 0; i < 4; ++i) {
    int chunk = i * 256 + threadIdx.x;
    int r = chunk >> 4, c4 = (chunk & 15) << 2;
    float s = rc[r0 + r];
    ushort4 uv = *(const ushort4*)(ip + (long)(r0 + r) * C + (c0 + c4));
    tile[r][c4 + 0] = (bf16_t)(bf2f(uv.x) * s);
    tile[r][c4 + 1] = (bf16_t)(bf2f(uv.y) * s);
    tile[r][c4 + 2] = (bf16_t)(bf2f(uv.z) * s);
    tile[r][c4 + 3] = (bf16_t)(bf2f(uv.w) * s);
  }
  __syncthreads();
#pragma unroll
  for (int i = 0; i < 4; ++i) {
    int chunk = i * 256 + threadIdx.x;
    int oc = chunk >> 4, or4 = (chunk & 15) << 2;
    union { ushort4 u; bf16_t h[4]; } o;
    o.h[0] = tile[or4 + 0][oc];
    o.h[1] = tile[or4 + 1][oc];
    o.h[2] = tile[or4 + 2][oc];
    o.h[3] = tile[or4 + 3][oc];
    *(ushort4*)(op + (long)(c0 + oc) * R + (r0 + or4)) = o.u;
  }
}

extern "C" void kernel_launch(void* const* d_in, const int* in_sizes, int n_in,
                              void* d_out, int out_size, void* d_ws, size_t ws_size,
                              hipStream_t stream)
{
  (void)in_sizes; (void)n_in; (void)out_size; (void)ws_size;
  const float* q  = (const float*)d_in[0];
  const float* k  = (const float*)d_in[1];
  const float* v  = (const float*)d_in[2];
  const float* Wq = (const float*)d_in[3];
  const float* bq = (const float*)d_in[4];
  const float* Wk = (const float*)d_in[5];
  const float* bk = (const float*)d_in[6];
  const float* Wv = (const float*)d_in[7];
  const float* bv = (const float*)d_in[8];
  const float* Wo = (const float*)d_in[9];
  const float* bo = (const float*)d_in[10];
  float* out = (float*)d_out;

  char* ws = (char*)d_ws;
  const size_t MB = 1u << 20;
  bf16_t* qcat  = (bf16_t*)(ws);              // [0,16)   [8192,1024] (h|l)
  bf16_t* kcat  = (bf16_t*)(ws + 16 * MB);    // [16,32)
  bf16_t* GA    = (bf16_t*)(ws + 32 * MB);    // [32,40)  Wk  [512,8192]
  bf16_t* GB    = (bf16_t*)(ws + 40 * MB);    // [40,48)  Wq
  bf16_t* WoS   = (bf16_t*)(ws + 48 * MB);    // [48,56)  Wo^T [512,8192]
  bf16_t* WvS   = (bf16_t*)(ws + 56 * MB);    // [56,64)  Wv
  float*  Gpart = (float*)(ws + 64 * MB);     // [64,80)  16x[512,512]
  float*  WvoTp = (float*)(ws + 80 * MB);     // [80,96)
  float*  Gt    = (float*)(ws + 96 * MB);     // [96,97)
  bf16_t* Gtcat = (bf16_t*)(ws + 97 * MB);    // [97,98)  [512,1024]
  bf16_t* WvoTb = (bf16_t*)(ws + 98 * MB);    // [98,98.5)
  float*  bvo   = (float*)(ws + 99 * MB);
  float*  wqbk  = (float*)(ws + 99 * MB + 16 * 1024);
  float*  wkbq  = (float*)(ws + 99 * MB + 32 * 1024);
  float*  cdot  = (float*)(ws + 99 * MB + 48 * 1024);
  float*  rav   = (float*)(ws + 99 * MB + 64 * 1024);   // 32 KB
  float*  rbv   = (float*)(ws + 99 * MB + 128 * 1024);  // 32 KB
  float*  crcp  = (float*)(ws + 99 * MB + 192 * 1024);  // 32 KB
  float*  part  = (float*)(ws + 99 * MB + 256 * 1024);  // 256 KB
  bf16_t* tcat  = (bf16_t*)(ws + 100 * MB);   // [100,116) [8192,1024]
  bf16_t* vbf   = (bf16_t*)(ws + 116 * MB);   // [116,124)
  bf16_t* vo    = (bf16_t*)(ws + 124 * MB);   // [124,132) [8192,512]
  bf16_t* vosT  = (bf16_t*)(ws + 132 * MB);   // [132,140) [B][512,2048]
  bf16_t* P     = (bf16_t*)(ws + 140 * MB);   // [140,172) [B][2048,2048]

  // splits (batched)
  split2_b3<<<dim3(1024, 2), 256, 0, stream>>>(q, k, nullptr, qcat, kcat, nullptr,
      NROW * HID, 9);
  split2_b3<<<dim3(1024, 3), 256, 0, stream>>>(Wk, Wq, Wv, GA, GB, WvS,
      (long)HID * PROJ, 12);
  transpose_split2<<<dim3(HID / 32, PROJ / 32), 256, 0, stream>>>(Wo, WoS, PROJ, HID);

  // Gt = SCALE*Wk.Wq^T ; WvoT = Wo^T.Wv^T (K=12288 z-split 16)
  gemm_bt<float, 0, 1, 2><<<dim3(4, 4, 16), 256, 0, stream>>>(GA, GB, Gpart,
      nullptr, 1.0f, HID, HID, 768, 2L * PROJ, 2L * PROJ,
      0, 0, (long)HID * HID, 768, 12);
  gemm_bt<float, 0, 1, 2><<<dim3(4, 4, 16), 256, 0, stream>>>(WoS, WvS, WvoTp,
      nullptr, 1.0f, HID, HID, 768, 2L * PROJ, 2L * PROJ,
      0, 0, (long)HID * HID, 768, 12);
  reduce2<<<(HID * HID + 255) / 256, 256, 0, stream>>>(Gpart, WvoTp, Gt, WvoTb,
      SCALE, HID * HID, 16);
  split2_b3<<<dim3(512, 1), 256, 0, stream>>>(Gt, nullptr, nullptr, Gtcat, nullptr,
      nullptr, (long)HID * HID, 9);

  // rank-1 bias terms
  rank1<<<dim3(HID, 4), 256, 0, stream>>>(Wq, bk, Wk, bq, WoS, bv, wqbk, wkbq, bvo, cdot);
  rowdot2<<<dim3((int)NROW, 2), 256, 0, stream>>>(q, k, wqbk, wkbq, cdot, rav, rbv);

  // t = q.Gt^T (split x split, K=1536), h/l split written directly
  gemm_bt<bf16_t, 2, 1, 2><<<dim3(4, 64, 1), 256, 0, stream>>>(qcat, Gtcat, tcat,
      nullptr, 1.0f, (int)NROW, HID, 1536, 1024, 1024, 0, 0, 0, 0, 9);

  cast_f32_bf16<<<2048, 256, 0, stream>>>(v, vbf, NROW * HID);

  // P = exp(t.k^T + ra + rb) — deep-staged 8-phase 256^2, fused col sums
  gemm8exp<<<dim3(8, 8, BSZ), 512, 0, stream>>>(tcat, kcat, P, rav, rbv, part);
  colsum_final<<<dim3(SEQ / 256, BSZ), 256, 0, stream>>>(part, crcp, SEQ, 8);

  // vo = v.Wvo + bvo
  gemm_bt<bf16_t, 0, 0, 0><<<dim3(4, 64, 1), 256, 0, stream>>>(vbf, WvoTb, vo,
      bvo, 1.0f, (int)NROW, HID, HID, HID, HID, 0, 0, 0, 0, 0);
  // vosT[z][d,m] = vo[z][m,d] / csum[z][m]
  transpose_scale_bf16<<<dim3(HID / 64, SEQ / 64, BSZ), 256, 0, stream>>>(
      vo, crcp, vosT, SEQ, HID, (long)SEQ * HID, (long)HID * SEQ);

  // out = P.vosT^T + bo
  gemm_bt<float, 0, 0, 0><<<dim3(4, 16, BSZ), 256, 0, stream>>>(P, vosT, out,
      bo, 1.0f, SEQ, HID, SEQ, SEQ, SEQ,
      (long)SEQ * SEQ, (long)HID * SEQ, (long)SEQ * HID, 0, 0);
}

// Round 8
// 232.395 us; speedup vs baseline: 1.7652x; 1.0863x over previous
//
#include <hip/hip_runtime.h>
#include <hip/hip_bf16.h>

#define AS1 __attribute__((address_space(1)))
#define AS3 __attribute__((address_space(3)))

typedef __bf16 bf16_t;
typedef __attribute__((ext_vector_type(8))) __bf16 bf16x8;
typedef __attribute__((ext_vector_type(4))) float f32x4;

static constexpr int BSZ = 4, SEQ = 2048, HID = 512, PROJ = 4096;
static constexpr long NROW = (long)BSZ * SEQ;  // 8192
static constexpr float SCALE = 0.125f;

__device__ __forceinline__ void gload_lds16(const void* g, void* l) {
  __builtin_amdgcn_global_load_lds((const AS1 void*)g, (AS3 void*)l, 16, 0, 0);
}

// map logical K index -> storage col for 2-wide [h|l] split buffers.
// MAP 0: identity. MAP 1: logical thirds (h,l,h). MAP 2: logical thirds (h,h,l).
template <int MAP>
__device__ __forceinline__ long mapk(long c, int s) {
  if (MAP == 0) return c;
  long w = c & ((1L << s) - 1);
  long t = c >> s;
  bool lo = (MAP == 1) ? (t == 1) : (t == 2);
  return (lo ? (1L << s) : 0) + w;
}

// ==================================================================
// 8-phase 256x256 GEMM for P = exp(t.k^T + ra) with fused column
// partial sums. (rb term dropped: constant-per-column factors cancel
// in the axis=1 softmax normalization — exact algebra.)
// r6-proven schedule: stage t+1 halves at ph0/ph1/ph2 (opposite buf),
// Ah0(t+2) at ph3 (current buf); boundary vmcnt(2).
// ==================================================================
__device__ __forceinline__ void stage_half8(
    const bf16_t* __restrict__ G, long ldg, long rcBase, long kcol,
    int half, bf16_t* dst, int tid)
{
#pragma unroll
  for (int it = 0; it < 2; ++it) {
    int li = it * 512 + tid;
    int row = li >> 3;
    int srcb = ((li & 7) << 4) ^ ((row & 7) << 4);
    gload_lds16(G + (rcBase + half * 128 + row) * ldg + kcol + (srcb >> 1),
                (char*)dst + li * 16);
  }
}

#define PH_PRE()  __builtin_amdgcn_s_barrier(); \
                  asm volatile("s_waitcnt lgkmcnt(0)" ::: "memory"); \
                  __builtin_amdgcn_sched_barrier(0); \
                  __builtin_amdgcn_s_setprio(1);
#define PH_POST() __builtin_amdgcn_s_setprio(0); \
                  __builtin_amdgcn_s_barrier(); \
                  __builtin_amdgcn_sched_barrier(0);

__global__ __launch_bounds__(512, 2) void gemm8exp(
    const bf16_t* __restrict__ A, const bf16_t* __restrict__ B,
    bf16_t* __restrict__ C, const float* __restrict__ ra,
    float* __restrict__ part)
{
  constexpr int NT = 24;            // K = 1536
  constexpr long LDA = 1024, LDB = 1024;
  constexpr int M = 2048, N = 2048;
  __shared__ __align__(16) bf16_t lds8[65536];  // 128 KB

  const int z = blockIdx.z;
  A += (long)z * SEQ * LDA;
  B += (long)z * SEQ * LDB;
  C += (long)z * (long)SEQ * SEQ;

  // bijective XCD swizzle (nwg=64 per plane)
  const int id0 = blockIdx.y * 8 + blockIdx.x;
  const int swz = (id0 & 7) * 8 + (id0 >> 3);
  const int bx = swz & 7, by = swz >> 3;
  const long rowBase = (long)by * 256;
  const long colBase = (long)bx * 256;

  const int tid = threadIdx.x;
  const int lane = tid & 63;
  const int wid = tid >> 6;
  const int wm = wid >> 2;          // 0..1 (M)
  const int wn = wid & 3;           // 0..3 (N)
  const int l15 = lane & 15;
  const int kgb = (lane >> 4) << 4; // byte offset of lane's k-group

  f32x4 acc[8][4] = {};
  bf16x8 afr[4][2];                 // current quadrant-row A frags
  bf16x8 bfr[2][2][2];              // [qc][c][kk]

  // prologue: tile0 all 4 halves -> buf0; tile1 Ah0 -> buf1; vmcnt(2)
  {
    const long ka0 = mapk<1>(0, 9), kb0 = mapk<2>(0, 9);
    const long ka1 = mapk<1>(64, 9);
    stage_half8(A, LDA, rowBase, ka0, 0, lds8 + 0 * 8192, tid);
    stage_half8(A, LDA, rowBase, ka0, 1, lds8 + 1 * 8192, tid);
    stage_half8(B, LDB, colBase, kb0, 0, lds8 + 2 * 8192, tid);
    stage_half8(B, LDB, colBase, kb0, 1, lds8 + 3 * 8192, tid);
    stage_half8(A, LDA, rowBase, ka1, 0, lds8 + 32768 + 0 * 8192, tid);
    asm volatile("s_waitcnt vmcnt(2)" ::: "memory");
    __builtin_amdgcn_s_barrier();
    __builtin_amdgcn_sched_barrier(0);
  }

  for (int t = 0; t < NT; ++t) {
    const int d = t & 1;
    bf16_t* bufc = lds8 + d * 32768;
    bf16_t* bufn = lds8 + (d ^ 1) * 32768;
    const bf16_t* Ah = bufc + wm * 8192;
    const bf16_t* Bh = bufc + 16384 + (wn >> 1) * 8192;
    const long ka1 = mapk<1>((long)(t + 1) * 64, 9);
    const long kb1 = mapk<2>((long)(t + 1) * 64, 9);
    const long ka2 = mapk<1>((long)(t + 2) * 64, 9);

    // ---- phase 0: read a(qr0)+b(qc0); issue Ah1(t+1); MFMA (0,0) ----
#pragma unroll
    for (int r = 0; r < 4; ++r)
#pragma unroll
      for (int kk = 0; kk < 2; ++kk) {
        int lrow = r * 16 + l15;
        int off = (lrow << 7) + (((kk << 6) + kgb) ^ ((lrow & 7) << 4));
        afr[r][kk] = *(const bf16x8*)((const char*)Ah + off);
      }
#pragma unroll
    for (int c = 0; c < 2; ++c)
#pragma unroll
      for (int kk = 0; kk < 2; ++kk) {
        int lrow = (wn & 1) * 64 + c * 16 + l15;
        int off = (lrow << 7) + (((kk << 6) + kgb) ^ ((lrow & 7) << 4));
        bfr[0][c][kk] = *(const bf16x8*)((const char*)Bh + off);
      }
    if (t + 1 < NT) stage_half8(A, LDA, rowBase, ka1, 1, bufn + 1 * 8192, tid);
    PH_PRE();
#pragma unroll
    for (int r = 0; r < 4; ++r)
#pragma unroll
      for (int c = 0; c < 2; ++c)
#pragma unroll
        for (int kk = 0; kk < 2; ++kk)
          acc[r][c] = __builtin_amdgcn_mfma_f32_16x16x32_bf16(
              afr[r][kk], bfr[0][c][kk], acc[r][c], 0, 0, 0);
    PH_POST();

    // ---- phase 1: read b(qc1); issue Bh0(t+1); MFMA (0,1) ----
#pragma unroll
    for (int c = 0; c < 2; ++c)
#pragma unroll
      for (int kk = 0; kk < 2; ++kk) {
        int lrow = (wn & 1) * 64 + 32 + c * 16 + l15;
        int off = (lrow << 7) + (((kk << 6) + kgb) ^ ((lrow & 7) << 4));
        bfr[1][c][kk] = *(const bf16x8*)((const char*)Bh + off);
      }
    if (t + 1 < NT) stage_half8(B, LDB, colBase, kb1, 0, bufn + 2 * 8192, tid);
    PH_PRE();
#pragma unroll
    for (int r = 0; r < 4; ++r)
#pragma unroll
      for (int c = 0; c < 2; ++c)
#pragma unroll
        for (int kk = 0; kk < 2; ++kk)
          acc[r][2 + c] = __builtin_amdgcn_mfma_f32_16x16x32_bf16(
              afr[r][kk], bfr[1][c][kk], acc[r][2 + c], 0, 0, 0);
    PH_POST();

    // ---- phase 2: read a(qr1); issue Bh1(t+1); MFMA (1,0) ----
#pragma unroll
    for (int r = 0; r < 4; ++r)
#pragma unroll
      for (int kk = 0; kk < 2; ++kk) {
        int lrow = 64 + r * 16 + l15;
        int off = (lrow << 7) + (((kk << 6) + kgb) ^ ((lrow & 7) << 4));
        afr[r][kk] = *(const bf16x8*)((const char*)Ah + off);
      }
    if (t + 1 < NT) stage_half8(B, LDB, colBase, kb1, 1, bufn + 3 * 8192, tid);
    PH_PRE();
#pragma unroll
    for (int r = 0; r < 4; ++r)
#pragma unroll
      for (int c = 0; c < 2; ++c)
#pragma unroll
        for (int kk = 0; kk < 2; ++kk)
          acc[4 + r][c] = __builtin_amdgcn_mfma_f32_16x16x32_bf16(
              afr[r][kk], bfr[0][c][kk], acc[4 + r][c], 0, 0, 0);
    PH_POST();

    // ---- phase 3: issue Ah0(t+2) into bufc; MFMA (1,1); vmcnt(2) ----
    if (t + 2 < NT) stage_half8(A, LDA, rowBase, ka2, 0, bufc + 0 * 8192, tid);
    __builtin_amdgcn_s_barrier();
    __builtin_amdgcn_s_setprio(1);
#pragma unroll
    for (int r = 0; r < 4; ++r)
#pragma unroll
      for (int c = 0; c < 2; ++c)
#pragma unroll
        for (int kk = 0; kk < 2; ++kk)
          acc[4 + r][2 + c] = __builtin_amdgcn_mfma_f32_16x16x32_bf16(
              afr[r][kk], bfr[1][c][kk], acc[4 + r][2 + c], 0, 0, 0);
    __builtin_amdgcn_s_setprio(0);
    if (t < NT - 2) { asm volatile("s_waitcnt vmcnt(2)" ::: "memory"); }
    else            { asm volatile("s_waitcnt vmcnt(0)" ::: "memory"); }
    __builtin_amdgcn_s_barrier();
    __builtin_amdgcn_sched_barrier(0);
  }

  // ---- epilogue: exp + ra + bf16 store + fused column partial sums ----
  __syncthreads();
  float* cs = (float*)lds8;  // [2][256]
  float csum[4] = {0.f, 0.f, 0.f, 0.f};
#pragma unroll
  for (int qr = 0; qr < 2; ++qr)
#pragma unroll
    for (int r = 0; r < 4; ++r) {
      long row0 = rowBase + wm * 128 + qr * 64 + r * 16 + ((lane >> 4) << 2);
      float4 ra4 = *(const float4*)(ra + (long)z * M + row0);
#pragma unroll
      for (int cf = 0; cf < 4; ++cf) {
        long col = colBase + wn * 64 + cf * 16 + l15;
        f32x4 v4 = acc[qr * 4 + r][cf];
        float rr[4] = {ra4.x, ra4.y, ra4.z, ra4.w};
#pragma unroll
        for (int e = 0; e < 4; ++e) {
          float v = __expf(v4[e] + rr[e]);
          C[(row0 + e) * (long)N + col] = (bf16_t)v;
          csum[cf] += v;
        }
      }
    }
#pragma unroll
  for (int cf = 0; cf < 4; ++cf) {
    float s = csum[cf];
    s += __shfl_xor(s, 16);
    s += __shfl_xor(s, 32);
    if (lane < 16) cs[wm * 256 + wn * 64 + cf * 16 + lane] = s;
  }
  __syncthreads();
  if (tid < 256)
    part[((long)by * gridDim.z + z) * N + colBase + tid] = cs[tid] + cs[256 + tid];
}

// ------------------------------------------------------------------
// 128x128 m97-structure GEMM. Optional second matrix set (A2/B2/C2)
// selected for z >= zSplit (merges equal-shape dispatches).
// ------------------------------------------------------------------
template <typename OutT, int OUTMODE, int AMAP, int BMAP>
__global__ __launch_bounds__(256) void gemm_bt(
    const bf16_t* __restrict__ A, const bf16_t* __restrict__ B,
    OutT* __restrict__ C, const float* __restrict__ bias,
    float scale, int M, int N, int K, long lda, long ldb,
    long sA, long sB, long sC, long kz, int sshift,
    const bf16_t* __restrict__ A2, const bf16_t* __restrict__ B2,
    OutT* __restrict__ C2, int zSplit)
{
  __shared__ __align__(16) bf16_t As[128 * 64];
  __shared__ __align__(16) bf16_t Bs[128 * 64];
  int z = blockIdx.z;
  if (zSplit > 0 && z >= zSplit) { A = A2; B = B2; C = C2; z -= zSplit; }
  A += (long)z * sA; B += (long)z * sB; C += (long)z * sC;

  const int gx = gridDim.x;
  const int nwg = gx * gridDim.y;
  const int id = blockIdx.y * gx + blockIdx.x;
  const int qq = nwg >> 3, rr = nwg & 7;
  const int xcd = id & 7, jj = id >> 3;
  const int swz = (xcd < rr ? xcd * (qq + 1) : rr * (qq + 1) + (xcd - rr) * qq) + jj;
  const int bx = swz % gx, by = swz / gx;

  const int tid  = threadIdx.x;
  const int lane = tid & 63;
  const int wid  = tid >> 6;
  const int wr = (wid >> 1) * 64;
  const int wc = (wid & 1) * 64;
  const long rowBase = (long)by * 128;
  const long colBase = (long)bx * 128;

  f32x4 acc[4][4] = {};

  int srow[4], scol[4];
#pragma unroll
  for (int i = 0; i < 4; ++i) {
    int li = i * 256 + tid;
    int row = li >> 3;
    int inner = (li & 7) << 4;
    int src = inner ^ ((row & 7) << 4);
    srow[i] = row;
    scol[i] = src >> 1;
  }

  for (int k0 = 0; k0 < K; k0 += 64) {
    const long k0L = kz * z + k0;
    const long ka = mapk<AMAP>(k0L, sshift);
    const long kb = mapk<BMAP>(k0L, sshift);
    __syncthreads();
#pragma unroll
    for (int i = 0; i < 4; ++i) {
      int li = i * 256 + tid;
      gload_lds16(A + (rowBase + srow[i]) * lda + ka + scol[i], (char*)As + li * 16);
      gload_lds16(B + (colBase + srow[i]) * ldb + kb + scol[i], (char*)Bs + li * 16);
    }
    __syncthreads();
#pragma unroll
    for (int kk = 0; kk < 64; kk += 32) {
      const int kbyte = (kk + ((lane >> 4) << 3)) << 1;
      bf16x8 af[4], bfr[4];
#pragma unroll
      for (int m = 0; m < 4; ++m) {
        int row = wr + m * 16 + (lane & 15);
        int off = (row << 7) + (kbyte ^ ((row & 7) << 4));
        af[m] = *(const bf16x8*)((const char*)As + off);
      }
#pragma unroll
      for (int n = 0; n < 4; ++n) {
        int row = wc + n * 16 + (lane & 15);
        int off = (row << 7) + (kbyte ^ ((row & 7) << 4));
        bfr[n] = *(const bf16x8*)((const char*)Bs + off);
      }
#pragma unroll
      for (int m = 0; m < 4; ++m)
#pragma unroll
        for (int n = 0; n < 4; ++n)
          acc[m][n] = __builtin_amdgcn_mfma_f32_16x16x32_bf16(af[m], bfr[n], acc[m][n], 0, 0, 0);
    }
  }

  if (OUTMODE == 2) {
#pragma unroll
    for (int n = 0; n < 4; ++n) {
      const long col = colBase + wc + n * 16 + (lane & 15);
#pragma unroll
      for (int m = 0; m < 4; ++m) {
#pragma unroll
        for (int e = 0; e < 4; ++e) {
          const long row = rowBase + wr + m * 16 + (lane >> 4) * 4 + e;
          float v = acc[m][n][e] * scale;
          bf16_t h = (bf16_t)v;
          bf16_t l = (bf16_t)(v - (float)h);
          C[row * (2L * N) + col] = (OutT)h;
          C[row * (2L * N) + N + col] = (OutT)l;
        }
      }
    }
  } else {
#pragma unroll
    for (int n = 0; n < 4; ++n) {
      const long col = colBase + wc + n * 16 + (lane & 15);
      const float bv_ = bias ? bias[col] : 0.0f;
#pragma unroll
      for (int m = 0; m < 4; ++m) {
#pragma unroll
        for (int e = 0; e < 4; ++e) {
          const long row = rowBase + wr + m * 16 + (lane >> 4) * 4 + e;
          C[row * (long)N + col] = (OutT)((acc[m][n][e] + bv_) * scale);
        }
      }
    }
  }
}

// f32 [R,C] -> bf16 [R,2C] = (h|l), vectorized x4; up to 3 tensors batched.
__global__ void split2_b3(const float* __restrict__ in0, const float* __restrict__ in1,
                          const float* __restrict__ in2,
                          bf16_t* __restrict__ o0, bf16_t* __restrict__ o1,
                          bf16_t* __restrict__ o2, long n, int cshift) {
  const float* in = (blockIdx.y == 0) ? in0 : (blockIdx.y == 1) ? in1 : in2;
  bf16_t* out = (blockIdx.y == 0) ? o0 : (blockIdx.y == 1) ? o1 : o2;
  long C = 1L << cshift;
  long i0 = ((long)blockIdx.x * blockDim.x + threadIdx.x) * 4;
  long stride = (long)gridDim.x * blockDim.x * 4;
  for (long i = i0; i < n; i += stride) {
    float4 f = *(const float4*)(in + i);
    long r = i >> cshift, c = i & (C - 1);
    union { ushort4 u; bf16_t h[4]; } H, L;
    float fv[4] = {f.x, f.y, f.z, f.w};
#pragma unroll
    for (int j = 0; j < 4; ++j) {
      bf16_t h = (bf16_t)fv[j];
      H.h[j] = h;
      L.h[j] = (bf16_t)(fv[j] - (float)h);
    }
    *(ushort4*)(out + r * 2 * C + c) = H.u;
    *(ushort4*)(out + r * 2 * C + C + c) = L.u;
  }
}

// f32 [R,C] -> bf16 [C,2R] = (h|l) of the transpose
__global__ void transpose_split2(const float* __restrict__ in, bf16_t* __restrict__ out,
                                 int R, int C) {
  __shared__ float tile[32][33];
  int c0 = blockIdx.x * 32, r0 = blockIdx.y * 32;
  int tx = threadIdx.x & 31, ty = threadIdx.x >> 5;
#pragma unroll
  for (int i = 0; i < 32; i += 8)
    tile[ty + i][tx] = in[(long)(r0 + ty + i) * C + (c0 + tx)];
  __syncthreads();
#pragma unroll
  for (int i = 0; i < 32; i += 8) {
    float x = tile[tx][ty + i];
    bf16_t h = (bf16_t)x;
    bf16_t l = (bf16_t)(x - (float)h);
    long o = (long)(c0 + ty + i) * 2 * R + (r0 + tx);
    out[o] = h;
    out[o + R] = l;
  }
}

__global__ void cast_f32_bf16(const float* __restrict__ in, bf16_t* __restrict__ out, long n) {
  long i0 = ((long)blockIdx.x * blockDim.x + threadIdx.x) * 4;
  long stride = (long)gridDim.x * blockDim.x * 4;
  for (long i = i0; i < n; i += stride) {
    float4 f = *(const float4*)(in + i);
    union { ushort4 u; bf16_t h[4]; } o;
    o.h[0] = (bf16_t)f.x; o.h[1] = (bf16_t)f.y; o.h[2] = (bf16_t)f.z; o.h[3] = (bf16_t)f.w;
    *(ushort4*)(out + i) = o.u;
  }
}

// Gtcat (split h|l, scaled) and WvoTb (bf16) from K-split partials.
__global__ void reduce2(const float* __restrict__ gp, const float* __restrict__ wp,
                        bf16_t* __restrict__ Gtcat, bf16_t* __restrict__ WvoTb,
                        float scale, int nElem, int nParts) {
  int i = blockIdx.x * 256 + threadIdx.x;
  if (i < nElem) {
    float a = 0.f, b = 0.f;
    for (int p = 0; p < nParts; ++p) {
      a += gp[(long)p * nElem + i];
      b += wp[(long)p * nElem + i];
    }
    a *= scale;
    int r = i >> 9, c = i & 511;
    bf16_t h = (bf16_t)a;
    Gtcat[(long)r * 1024 + c] = h;
    Gtcat[(long)r * 1024 + 512 + c] = (bf16_t)(a - (float)h);
    WvoTb[i] = (bf16_t)b;
  }
}

// rank-1 prep: y=0 wqbk[bx]=Wq[bx,:].bk; y=1 bvo[bx]=WoT[bx,:].bv (via WoS);
// y=2 cdot=bq.bk   (wkbq/rb dropped: cancels in column softmax)
__global__ void rank1(const float* __restrict__ Wq, const float* __restrict__ bk,
                      const float* __restrict__ bq,
                      const bf16_t* __restrict__ WoS, const float* __restrict__ bv,
                      float* __restrict__ wqbk, float* __restrict__ bvo,
                      float* __restrict__ cdot) {
  __shared__ float red[256];
  int y = blockIdx.y, bx = blockIdx.x, t = threadIdx.x;
  float s = 0.f;
  if (y == 0) {
    for (int j = t; j < PROJ; j += 256) s += Wq[(long)bx * PROJ + j] * bk[j];
  } else if (y == 1) {
    const bf16_t* row = WoS + (long)bx * 2 * PROJ;
    for (int j = t; j < PROJ; j += 256)
      s += ((float)row[j] + (float)row[PROJ + j]) * bv[j];
  } else {
    if (bx != 0) return;
    for (int j = t; j < PROJ; j += 256) s += bq[j] * bk[j];
  }
  red[t] = s; __syncthreads();
  for (int w = 128; w > 0; w >>= 1) {
    if (t < w) red[t] += red[t + w];
    __syncthreads();
  }
  if (t == 0) {
    if (y == 0) wqbk[bx] = red[0];
    else if (y == 1) bvo[bx] = red[0];
    else *cdot = red[0];
  }
}

// rav[r] = SCALE*(q[r].wqbk + cdot)
__global__ void rowdot_rav(const float* __restrict__ q, const float* __restrict__ wqbk,
                           const float* __restrict__ cdot, float* __restrict__ rav) {
  __shared__ float red[256];
  int r = blockIdx.x, t = threadIdx.x;
  float s = 0.f;
  for (int j = t; j < HID; j += 256) s += q[(long)r * HID + j] * wqbk[j];
  red[t] = s; __syncthreads();
  for (int w = 128; w > 0; w >>= 1) {
    if (t < w) red[t] += red[t + w];
    __syncthreads();
  }
  if (t == 0) rav[r] = SCALE * (red[0] + *cdot);
}

__global__ void colsum_final(const float* __restrict__ part, float* __restrict__ crcp,
                             int Nm, int nParts) {
  int b = blockIdx.y;
  int m = blockIdx.x * 256 + threadIdx.x;
  float s = 0.f;
  for (int p = 0; p < nParts; ++p)
    s += part[((long)p * gridDim.y + b) * Nm + m];
  crcp[(long)b * Nm + m] = 1.0f / s;
}

__device__ __forceinline__ float bf2f(unsigned short u) {
  union { unsigned u32; float f; } x; x.u32 = ((unsigned)u) << 16; return x.f;
}

__global__ void transpose_scale_bf16(const bf16_t* __restrict__ in, const float* __restrict__ crcp,
                                     bf16_t* __restrict__ out, int R, int C, long sIn, long sOut) {
  __shared__ bf16_t tile[64][68];
  int z = blockIdx.z;
  const bf16_t* ip = in + (long)z * sIn;
  bf16_t* op = out + (long)z * sOut;
  const float* rc = crcp + (long)z * R;
  int c0 = blockIdx.x * 64, r0 = blockIdx.y * 64;
#pragma unroll
  for (int i = 0; i < 4; ++i) {
    int chunk = i * 256 + threadIdx.x;
    int r = chunk >> 4, c4 = (chunk & 15) << 2;
    float s = rc[r0 + r];
    ushort4 uv = *(const ushort4*)(ip + (long)(r0 + r) * C + (c0 + c4));
    tile[r][c4 + 0] = (bf16_t)(bf2f(uv.x) * s);
    tile[r][c4 + 1] = (bf16_t)(bf2f(uv.y) * s);
    tile[r][c4 + 2] = (bf16_t)(bf2f(uv.z) * s);
    tile[r][c4 + 3] = (bf16_t)(bf2f(uv.w) * s);
  }
  __syncthreads();
#pragma unroll
  for (int i = 0; i < 4; ++i) {
    int chunk = i * 256 + threadIdx.x;
    int oc = chunk >> 4, or4 = (chunk & 15) << 2;
    union { ushort4 u; bf16_t h[4]; } o;
    o.h[0] = tile[or4 + 0][oc];
    o.h[1] = tile[or4 + 1][oc];
    o.h[2] = tile[or4 + 2][oc];
    o.h[3] = tile[or4 + 3][oc];
    *(ushort4*)(op + (long)(c0 + oc) * R + (r0 + or4)) = o.u;
  }
}

extern "C" void kernel_launch(void* const* d_in, const int* in_sizes, int n_in,
                              void* d_out, int out_size, void* d_ws, size_t ws_size,
                              hipStream_t stream)
{
  (void)in_sizes; (void)n_in; (void)out_size; (void)ws_size;
  const float* q  = (const float*)d_in[0];
  const float* k  = (const float*)d_in[1];
  const float* v  = (const float*)d_in[2];
  const float* Wq = (const float*)d_in[3];
  const float* bq = (const float*)d_in[4];
  const float* Wk = (const float*)d_in[5];
  const float* bk = (const float*)d_in[6];
  const float* Wv = (const float*)d_in[7];
  const float* bv = (const float*)d_in[8];
  const float* Wo = (const float*)d_in[9];
  const float* bo = (const float*)d_in[10];
  float* out = (float*)d_out;

  char* ws = (char*)d_ws;
  const size_t MB = 1u << 20;
  bf16_t* qcat  = (bf16_t*)(ws);              // [0,16)   [8192,1024] (h|l)
  bf16_t* kcat  = (bf16_t*)(ws + 16 * MB);    // [16,32)
  bf16_t* GA    = (bf16_t*)(ws + 32 * MB);    // [32,40)  Wk  [512,8192]
  bf16_t* GB    = (bf16_t*)(ws + 40 * MB);    // [40,48)  Wq
  bf16_t* WoS   = (bf16_t*)(ws + 48 * MB);    // [48,56)  Wo^T [512,8192]
  bf16_t* WvS   = (bf16_t*)(ws + 56 * MB);    // [56,64)  Wv
  float*  Gpart = (float*)(ws + 64 * MB);     // [64,80)  16x[512,512]
  float*  WvoTp = (float*)(ws + 80 * MB);     // [80,96)
  bf16_t* Gtcat = (bf16_t*)(ws + 97 * MB);    // [97,98)  [512,1024]
  bf16_t* WvoTb = (bf16_t*)(ws + 98 * MB);    // [98,98.5)
  float*  bvo   = (float*)(ws + 99 * MB);
  float*  wqbk  = (float*)(ws + 99 * MB + 16 * 1024);
  float*  cdot  = (float*)(ws + 99 * MB + 48 * 1024);
  float*  rav   = (float*)(ws + 99 * MB + 64 * 1024);   // 32 KB
  float*  crcp  = (float*)(ws + 99 * MB + 192 * 1024);  // 32 KB
  float*  part  = (float*)(ws + 99 * MB + 256 * 1024);  // 256 KB
  bf16_t* tcat  = (bf16_t*)(ws + 100 * MB);   // [100,116) [8192,1024]
  bf16_t* vbf   = (bf16_t*)(ws + 116 * MB);   // [116,124)
  bf16_t* vo    = (bf16_t*)(ws + 124 * MB);   // [124,132) [8192,512]
  bf16_t* vosT  = (bf16_t*)(ws + 132 * MB);   // [132,140) [B][512,2048]
  bf16_t* P     = (bf16_t*)(ws + 140 * MB);   // [140,172) [B][2048,2048]

  // splits (batched)
  split2_b3<<<dim3(1024, 2), 256, 0, stream>>>(q, k, nullptr, qcat, kcat, nullptr,
      NROW * HID, 9);
  split2_b3<<<dim3(1024, 3), 256, 0, stream>>>(Wk, Wq, Wv, GA, GB, WvS,
      (long)HID * PROJ, 12);
  transpose_split2<<<dim3(HID / 32, PROJ / 32), 256, 0, stream>>>(Wo, WoS, PROJ, HID);

  // merged: z<16 -> Gt partials (Wk.Wq^T); z>=16 -> WvoT partials (Wo^T.Wv^T)
  gemm_bt<float, 0, 1, 2><<<dim3(4, 4, 32), 256, 0, stream>>>(GA, GB, Gpart,
      nullptr, 1.0f, HID, HID, 768, 2L * PROJ, 2L * PROJ,
      0, 0, (long)HID * HID, 768, 12, WoS, WvS, WvoTp, 16);
  reduce2<<<(HID * HID + 255) / 256, 256, 0, stream>>>(Gpart, WvoTp, Gtcat, WvoTb,
      SCALE, HID * HID, 16);

  // rank-1 bias terms (rb path dropped — cancels in column softmax)
  rank1<<<dim3(HID, 3), 256, 0, stream>>>(Wq, bk, bq, WoS, bv, wqbk, bvo, cdot);
  rowdot_rav<<<(int)NROW, 256, 0, stream>>>(q, wqbk, cdot, rav);

  // t = q.Gt^T (split x split, K=1536), h/l split written directly
  gemm_bt<bf16_t, 2, 1, 2><<<dim3(4, 64, 1), 256, 0, stream>>>(qcat, Gtcat, tcat,
      nullptr, 1.0f, (int)NROW, HID, 1536, 1024, 1024, 0, 0, 0, 0, 9,
      nullptr, nullptr, nullptr, 0);

  cast_f32_bf16<<<2048, 256, 0, stream>>>(v, vbf, NROW * HID);

  // P = exp(t.k^T + ra) — r6-proven 8-phase 256^2, fused col partial sums
  gemm8exp<<<dim3(8, 8, BSZ), 512, 0, stream>>>(tcat, kcat, P, rav, part);
  colsum_final<<<dim3(SEQ / 256, BSZ), 256, 0, stream>>>(part, crcp, SEQ, 8);

  // vo = v.Wvo + bvo
  gemm_bt<bf16_t, 0, 0, 0><<<dim3(4, 64, 1), 256, 0, stream>>>(vbf, WvoTb, vo,
      bvo, 1.0f, (int)NROW, HID, HID, HID, HID, 0, 0, 0, 0, 0,
      nullptr, nullptr, nullptr, 0);
  // vosT[z][d,m] = vo[z][m,d] / csum[z][m]
  transpose_scale_bf16<<<dim3(HID / 64, SEQ / 64, BSZ), 256, 0, stream>>>(
      vo, crcp, vosT, SEQ, HID, (long)SEQ * HID, (long)HID * SEQ);

  // out = P.vosT^T + bo
  gemm_bt<float, 0, 0, 0><<<dim3(4, 16, BSZ), 256, 0, stream>>>(P, vosT, out,
      bo, 1.0f, SEQ, HID, SEQ, SEQ, SEQ,
      (long)SEQ * SEQ, (long)HID * SEQ, (long)SEQ * HID, 0, 0,
      nullptr, nullptr, nullptr, 0);
}

// Round 9
// 210.154 us; speedup vs baseline: 1.9520x; 1.1058x over previous
//
#include <hip/hip_runtime.h>
#include <hip/hip_bf16.h>

#define AS1 __attribute__((address_space(1)))
#define AS3 __attribute__((address_space(3)))

typedef __bf16 bf16_t;
typedef __attribute__((ext_vector_type(8))) __bf16 bf16x8;
typedef __attribute__((ext_vector_type(4))) float f32x4;

static constexpr int BSZ = 4, SEQ = 2048, HID = 512, PROJ = 4096;
static constexpr long NROW = (long)BSZ * SEQ;  // 8192
static constexpr float SCALE = 0.125f;

__device__ __forceinline__ void gload_lds16(const void* g, void* l) {
  __builtin_amdgcn_global_load_lds((const AS1 void*)g, (AS3 void*)l, 16, 0, 0);
}

// map logical K index -> storage col for 2-wide [h|l] split buffers.
// MAP 0: identity. MAP 1: logical thirds (h,l,h). MAP 2: logical thirds (h,h,l).
template <int MAP>
__device__ __forceinline__ long mapk(long c, int s) {
  if (MAP == 0) return c;
  long w = c & ((1L << s) - 1);
  long t = c >> s;
  bool lo = (MAP == 1) ? (t == 1) : (t == 2);
  return (lo ? (1L << s) : 0) + w;
}

// ==================================================================
// 8-phase 256x256 GEMM for P = exp(t.k^T + ra) with fused column
// partial sums (r6-proven schedule; rb dropped — cancels in axis=1
// softmax normalization, exact algebra).
// ==================================================================
__device__ __forceinline__ void stage_half8(
    const bf16_t* __restrict__ G, long ldg, long rcBase, long kcol,
    int half, bf16_t* dst, int tid)
{
#pragma unroll
  for (int it = 0; it < 2; ++it) {
    int li = it * 512 + tid;
    int row = li >> 3;
    int srcb = ((li & 7) << 4) ^ ((row & 7) << 4);
    gload_lds16(G + (rcBase + half * 128 + row) * ldg + kcol + (srcb >> 1),
                (char*)dst + li * 16);
  }
}

#define PH_PRE()  __builtin_amdgcn_s_barrier(); \
                  asm volatile("s_waitcnt lgkmcnt(0)" ::: "memory"); \
                  __builtin_amdgcn_sched_barrier(0); \
                  __builtin_amdgcn_s_setprio(1);
#define PH_POST() __builtin_amdgcn_s_setprio(0); \
                  __builtin_amdgcn_s_barrier(); \
                  __builtin_amdgcn_sched_barrier(0);

__global__ __launch_bounds__(512, 2) void gemm8exp(
    const bf16_t* __restrict__ A, const bf16_t* __restrict__ B,
    bf16_t* __restrict__ C, const float* __restrict__ ra,
    float* __restrict__ part)
{
  constexpr int NT = 24;            // K = 1536
  constexpr long LDA = 1024, LDB = 1024;
  constexpr int M = 2048, N = 2048;
  __shared__ __align__(16) bf16_t lds8[65536];  // 128 KB

  const int z = blockIdx.z;
  A += (long)z * SEQ * LDA;
  B += (long)z * SEQ * LDB;
  C += (long)z * (long)SEQ * SEQ;

  const int id0 = blockIdx.y * 8 + blockIdx.x;
  const int swz = (id0 & 7) * 8 + (id0 >> 3);
  const int bx = swz & 7, by = swz >> 3;
  const long rowBase = (long)by * 256;
  const long colBase = (long)bx * 256;

  const int tid = threadIdx.x;
  const int lane = tid & 63;
  const int wid = tid >> 6;
  const int wm = wid >> 2;
  const int wn = wid & 3;
  const int l15 = lane & 15;
  const int kgb = (lane >> 4) << 4;

  f32x4 acc[8][4] = {};
  bf16x8 afr[4][2];
  bf16x8 bfr[2][2][2];

  {
    const long ka0 = mapk<1>(0, 9), kb0 = mapk<2>(0, 9);
    const long ka1 = mapk<1>(64, 9);
    stage_half8(A, LDA, rowBase, ka0, 0, lds8 + 0 * 8192, tid);
    stage_half8(A, LDA, rowBase, ka0, 1, lds8 + 1 * 8192, tid);
    stage_half8(B, LDB, colBase, kb0, 0, lds8 + 2 * 8192, tid);
    stage_half8(B, LDB, colBase, kb0, 1, lds8 + 3 * 8192, tid);
    stage_half8(A, LDA, rowBase, ka1, 0, lds8 + 32768 + 0 * 8192, tid);
    asm volatile("s_waitcnt vmcnt(2)" ::: "memory");
    __builtin_amdgcn_s_barrier();
    __builtin_amdgcn_sched_barrier(0);
  }

  for (int t = 0; t < NT; ++t) {
    const int d = t & 1;
    bf16_t* bufc = lds8 + d * 32768;
    bf16_t* bufn = lds8 + (d ^ 1) * 32768;
    const bf16_t* Ah = bufc + wm * 8192;
    const bf16_t* Bh = bufc + 16384 + (wn >> 1) * 8192;
    const long ka1 = mapk<1>((long)(t + 1) * 64, 9);
    const long kb1 = mapk<2>((long)(t + 1) * 64, 9);
    const long ka2 = mapk<1>((long)(t + 2) * 64, 9);

    // phase 0
#pragma unroll
    for (int r = 0; r < 4; ++r)
#pragma unroll
      for (int kk = 0; kk < 2; ++kk) {
        int lrow = r * 16 + l15;
        int off = (lrow << 7) + (((kk << 6) + kgb) ^ ((lrow & 7) << 4));
        afr[r][kk] = *(const bf16x8*)((const char*)Ah + off);
      }
#pragma unroll
    for (int c = 0; c < 2; ++c)
#pragma unroll
      for (int kk = 0; kk < 2; ++kk) {
        int lrow = (wn & 1) * 64 + c * 16 + l15;
        int off = (lrow << 7) + (((kk << 6) + kgb) ^ ((lrow & 7) << 4));
        bfr[0][c][kk] = *(const bf16x8*)((const char*)Bh + off);
      }
    if (t + 1 < NT) stage_half8(A, LDA, rowBase, ka1, 1, bufn + 1 * 8192, tid);
    PH_PRE();
#pragma unroll
    for (int r = 0; r < 4; ++r)
#pragma unroll
      for (int c = 0; c < 2; ++c)
#pragma unroll
        for (int kk = 0; kk < 2; ++kk)
          acc[r][c] = __builtin_amdgcn_mfma_f32_16x16x32_bf16(
              afr[r][kk], bfr[0][c][kk], acc[r][c], 0, 0, 0);
    PH_POST();

    // phase 1
#pragma unroll
    for (int c = 0; c < 2; ++c)
#pragma unroll
      for (int kk = 0; kk < 2; ++kk) {
        int lrow = (wn & 1) * 64 + 32 + c * 16 + l15;
        int off = (lrow << 7) + (((kk << 6) + kgb) ^ ((lrow & 7) << 4));
        bfr[1][c][kk] = *(const bf16x8*)((const char*)Bh + off);
      }
    if (t + 1 < NT) stage_half8(B, LDB, colBase, kb1, 0, bufn + 2 * 8192, tid);
    PH_PRE();
#pragma unroll
    for (int r = 0; r < 4; ++r)
#pragma unroll
      for (int c = 0; c < 2; ++c)
#pragma unroll
        for (int kk = 0; kk < 2; ++kk)
          acc[r][2 + c] = __builtin_amdgcn_mfma_f32_16x16x32_bf16(
              afr[r][kk], bfr[1][c][kk], acc[r][2 + c], 0, 0, 0);
    PH_POST();

    // phase 2
#pragma unroll
    for (int r = 0; r < 4; ++r)
#pragma unroll
      for (int kk = 0; kk < 2; ++kk) {
        int lrow = 64 + r * 16 + l15;
        int off = (lrow << 7) + (((kk << 6) + kgb) ^ ((lrow & 7) << 4));
        afr[r][kk] = *(const bf16x8*)((const char*)Ah + off);
      }
    if (t + 1 < NT) stage_half8(B, LDB, colBase, kb1, 1, bufn + 3 * 8192, tid);
    PH_PRE();
#pragma unroll
    for (int r = 0; r < 4; ++r)
#pragma unroll
      for (int c = 0; c < 2; ++c)
#pragma unroll
        for (int kk = 0; kk < 2; ++kk)
          acc[4 + r][c] = __builtin_amdgcn_mfma_f32_16x16x32_bf16(
              afr[r][kk], bfr[0][c][kk], acc[4 + r][c], 0, 0, 0);
    PH_POST();

    // phase 3
    if (t + 2 < NT) stage_half8(A, LDA, rowBase, ka2, 0, bufc + 0 * 8192, tid);
    __builtin_amdgcn_s_barrier();
    __builtin_amdgcn_s_setprio(1);
#pragma unroll
    for (int r = 0; r < 4; ++r)
#pragma unroll
      for (int c = 0; c < 2; ++c)
#pragma unroll
        for (int kk = 0; kk < 2; ++kk)
          acc[4 + r][2 + c] = __builtin_amdgcn_mfma_f32_16x16x32_bf16(
              afr[r][kk], bfr[1][c][kk], acc[4 + r][2 + c], 0, 0, 0);
    __builtin_amdgcn_s_setprio(0);
    if (t < NT - 2) { asm volatile("s_waitcnt vmcnt(2)" ::: "memory"); }
    else            { asm volatile("s_waitcnt vmcnt(0)" ::: "memory"); }
    __builtin_amdgcn_s_barrier();
    __builtin_amdgcn_sched_barrier(0);
  }

  // epilogue: exp + ra + store + fused column partial sums
  __syncthreads();
  float* cs = (float*)lds8;
  float csum[4] = {0.f, 0.f, 0.f, 0.f};
#pragma unroll
  for (int qr = 0; qr < 2; ++qr)
#pragma unroll
    for (int r = 0; r < 4; ++r) {
      long row0 = rowBase + wm * 128 + qr * 64 + r * 16 + ((lane >> 4) << 2);
      float4 ra4 = *(const float4*)(ra + (long)z * M + row0);
#pragma unroll
      for (int cf = 0; cf < 4; ++cf) {
        long col = colBase + wn * 64 + cf * 16 + l15;
        f32x4 v4 = acc[qr * 4 + r][cf];
        float rr[4] = {ra4.x, ra4.y, ra4.z, ra4.w};
#pragma unroll
        for (int e = 0; e < 4; ++e) {
          float v = __expf(v4[e] + rr[e]);
          C[(row0 + e) * (long)N + col] = (bf16_t)v;
          csum[cf] += v;
        }
      }
    }
#pragma unroll
  for (int cf = 0; cf < 4; ++cf) {
    float s = csum[cf];
    s += __shfl_xor(s, 16);
    s += __shfl_xor(s, 32);
    if (lane < 16) cs[wm * 256 + wn * 64 + cf * 16 + lane] = s;
  }
  __syncthreads();
  if (tid < 256)
    part[((long)by * gridDim.z + z) * N + colBase + tid] = cs[tid] + cs[256 + tid];
}

// ------------------------------------------------------------------
// 128x128 m97-structure GEMM; runtime outm (0: (acc+bias)*scale,
// 2: h/l split write). Second param set selected for z >= zSplit.
// ------------------------------------------------------------------
template <typename OutT, int AMAP, int BMAP>
__global__ __launch_bounds__(256) void gemm_bt(
    const bf16_t* __restrict__ A, const bf16_t* __restrict__ B,
    OutT* __restrict__ C, const float* __restrict__ bias,
    float scale, int M, int N, int K, long lda, long ldb,
    long sA, long sB, long sC, long kz, int sshift, int outm,
    const bf16_t* __restrict__ A2, const bf16_t* __restrict__ B2,
    OutT* __restrict__ C2, const float* __restrict__ bias2,
    int K2, long lda2, long ldb2, int outm2, int zSplit)
{
  __shared__ __align__(16) bf16_t As[128 * 64];
  __shared__ __align__(16) bf16_t Bs[128 * 64];
  int z = blockIdx.z;
  if (zSplit > 0 && z >= zSplit) {
    A = A2; B = B2; C = C2; bias = bias2;
    K = K2; lda = lda2; ldb = ldb2; outm = outm2;
    z -= zSplit;
  }
  A += (long)z * sA; B += (long)z * sB; C += (long)z * sC;

  const int gx = gridDim.x;
  const int nwg = gx * gridDim.y;
  const int id = blockIdx.y * gx + blockIdx.x;
  const int qq = nwg >> 3, rr = nwg & 7;
  const int xcd = id & 7, jj = id >> 3;
  const int swz = (xcd < rr ? xcd * (qq + 1) : rr * (qq + 1) + (xcd - rr) * qq) + jj;
  const int bx = swz % gx, by = swz / gx;

  const int tid  = threadIdx.x;
  const int lane = tid & 63;
  const int wid  = tid >> 6;
  const int wr = (wid >> 1) * 64;
  const int wc = (wid & 1) * 64;
  const long rowBase = (long)by * 128;
  const long colBase = (long)bx * 128;

  f32x4 acc[4][4] = {};

  int srow[4], scol[4];
#pragma unroll
  for (int i = 0; i < 4; ++i) {
    int li = i * 256 + tid;
    int row = li >> 3;
    int inner = (li & 7) << 4;
    int src = inner ^ ((row & 7) << 4);
    srow[i] = row;
    scol[i] = src >> 1;
  }

  for (int k0 = 0; k0 < K; k0 += 64) {
    const long k0L = kz * z + k0;
    const long ka = mapk<AMAP>(k0L, sshift);
    const long kb = mapk<BMAP>(k0L, sshift);
    __syncthreads();
#pragma unroll
    for (int i = 0; i < 4; ++i) {
      int li = i * 256 + tid;
      gload_lds16(A + (rowBase + srow[i]) * lda + ka + scol[i], (char*)As + li * 16);
      gload_lds16(B + (colBase + srow[i]) * ldb + kb + scol[i], (char*)Bs + li * 16);
    }
    __syncthreads();
#pragma unroll
    for (int kk = 0; kk < 64; kk += 32) {
      const int kbyte = (kk + ((lane >> 4) << 3)) << 1;
      bf16x8 af[4], bfr[4];
#pragma unroll
      for (int m = 0; m < 4; ++m) {
        int row = wr + m * 16 + (lane & 15);
        int off = (row << 7) + (kbyte ^ ((row & 7) << 4));
        af[m] = *(const bf16x8*)((const char*)As + off);
      }
#pragma unroll
      for (int n = 0; n < 4; ++n) {
        int row = wc + n * 16 + (lane & 15);
        int off = (row << 7) + (kbyte ^ ((row & 7) << 4));
        bfr[n] = *(const bf16x8*)((const char*)Bs + off);
      }
#pragma unroll
      for (int m = 0; m < 4; ++m)
#pragma unroll
        for (int n = 0; n < 4; ++n)
          acc[m][n] = __builtin_amdgcn_mfma_f32_16x16x32_bf16(af[m], bfr[n], acc[m][n], 0, 0, 0);
    }
  }

  if (outm == 2) {
#pragma unroll
    for (int n = 0; n < 4; ++n) {
      const long col = colBase + wc + n * 16 + (lane & 15);
#pragma unroll
      for (int m = 0; m < 4; ++m) {
#pragma unroll
        for (int e = 0; e < 4; ++e) {
          const long row = rowBase + wr + m * 16 + (lane >> 4) * 4 + e;
          float v = acc[m][n][e] * scale;
          bf16_t h = (bf16_t)v;
          bf16_t l = (bf16_t)(v - (float)h);
          C[row * (2L * N) + col] = (OutT)h;
          C[row * (2L * N) + N + col] = (OutT)l;
        }
      }
    }
  } else {
#pragma unroll
    for (int n = 0; n < 4; ++n) {
      const long col = colBase + wc + n * 16 + (lane & 15);
      const float bv_ = bias ? bias[col] : 0.0f;
#pragma unroll
      for (int m = 0; m < 4; ++m) {
#pragma unroll
        for (int e = 0; e < 4; ++e) {
          const long row = rowBase + wr + m * 16 + (lane >> 4) * 4 + e;
          C[row * (long)N + col] = (OutT)((acc[m][n][e] + bv_) * scale);
        }
      }
    }
  }
}

// f32 -> bf16 h/l split [R,2C] (or plain cast if castMask bit set),
// vectorized x4; up to 3 tensors batched via blockIdx.y.
__global__ void split2_b3(const float* __restrict__ in0, const float* __restrict__ in1,
                          const float* __restrict__ in2,
                          bf16_t* __restrict__ o0, bf16_t* __restrict__ o1,
                          bf16_t* __restrict__ o2, long n, int cshift, int castMask) {
  const float* in = (blockIdx.y == 0) ? in0 : (blockIdx.y == 1) ? in1 : in2;
  bf16_t* out = (blockIdx.y == 0) ? o0 : (blockIdx.y == 1) ? o1 : o2;
  const bool castOnly = (castMask >> blockIdx.y) & 1;
  long C = 1L << cshift;
  long i0 = ((long)blockIdx.x * blockDim.x + threadIdx.x) * 4;
  long stride = (long)gridDim.x * blockDim.x * 4;
  for (long i = i0; i < n; i += stride) {
    float4 f = *(const float4*)(in + i);
    union { ushort4 u; bf16_t h[4]; } H, L;
    float fv[4] = {f.x, f.y, f.z, f.w};
#pragma unroll
    for (int j = 0; j < 4; ++j) {
      bf16_t h = (bf16_t)fv[j];
      H.h[j] = h;
      L.h[j] = (bf16_t)(fv[j] - (float)h);
    }
    if (castOnly) {
      *(ushort4*)(out + i) = H.u;
    } else {
      long r = i >> cshift, c = i & (C - 1);
      *(ushort4*)(out + r * 2 * C + c) = H.u;
      *(ushort4*)(out + r * 2 * C + C + c) = L.u;
    }
  }
}

// f32 [R,C] -> bf16 [C,2R] = (h|l) of the transpose
__global__ void transpose_split2(const float* __restrict__ in, bf16_t* __restrict__ out,
                                 int R, int C) {
  __shared__ float tile[32][33];
  int c0 = blockIdx.x * 32, r0 = blockIdx.y * 32;
  int tx = threadIdx.x & 31, ty = threadIdx.x >> 5;
#pragma unroll
  for (int i = 0; i < 32; i += 8)
    tile[ty + i][tx] = in[(long)(r0 + ty + i) * C + (c0 + tx)];
  __syncthreads();
#pragma unroll
  for (int i = 0; i < 32; i += 8) {
    float x = tile[tx][ty + i];
    bf16_t h = (bf16_t)x;
    bf16_t l = (bf16_t)(x - (float)h);
    long o = (long)(c0 + ty + i) * 2 * R + (r0 + tx);
    out[o] = h;
    out[o + R] = l;
  }
}

// Gtcat (split h|l, scaled, 16 parts) and WvoTb (bf16, 6 parts).
__global__ void reduce2(const float* __restrict__ gp, const float* __restrict__ wp,
                        bf16_t* __restrict__ Gtcat, bf16_t* __restrict__ WvoTb,
                        float scale, int nElem, int nP1, int nP2) {
  int i = blockIdx.x * 256 + threadIdx.x;
  if (i < nElem) {
    float a = 0.f, b = 0.f;
    for (int p = 0; p < nP1; ++p) a += gp[(long)p * nElem + i];
    for (int p = 0; p < nP2; ++p) b += wp[(long)p * nElem + i];
    a *= scale;
    int r = i >> 9, c = i & 511;
    bf16_t h = (bf16_t)a;
    Gtcat[(long)r * 1024 + c] = h;
    Gtcat[(long)r * 1024 + 512 + c] = (bf16_t)(a - (float)h);
    WvoTb[i] = (bf16_t)b;
  }
}

// rank-1 prep: y=0 wqbk[bx]=Wq[bx,:].bk; y=1 bvo[bx]=WoT[bx,:].bv (via WoS);
// y=2 cdot=bq.bk
__global__ void rank1(const float* __restrict__ Wq, const float* __restrict__ bk,
                      const float* __restrict__ bq,
                      const bf16_t* __restrict__ WoS, const float* __restrict__ bv,
                      float* __restrict__ wqbk, float* __restrict__ bvo,
                      float* __restrict__ cdot) {
  __shared__ float red[256];
  int y = blockIdx.y, bx = blockIdx.x, t = threadIdx.x;
  float s = 0.f;
  if (y == 0) {
    for (int j = t; j < PROJ; j += 256) s += Wq[(long)bx * PROJ + j] * bk[j];
  } else if (y == 1) {
    const bf16_t* row = WoS + (long)bx * 2 * PROJ;
    for (int j = t; j < PROJ; j += 256)
      s += ((float)row[j] + (float)row[PROJ + j]) * bv[j];
  } else {
    if (bx != 0) return;
    for (int j = t; j < PROJ; j += 256) s += bq[j] * bk[j];
  }
  red[t] = s; __syncthreads();
  for (int w = 128; w > 0; w >>= 1) {
    if (t < w) red[t] += red[t + w];
    __syncthreads();
  }
  if (t == 0) {
    if (y == 0) wqbk[bx] = red[0];
    else if (y == 1) bvo[bx] = red[0];
    else *cdot = red[0];
  }
}

// rav[r] = SCALE*(q[r].wqbk + cdot)
__global__ void rowdot_rav(const float* __restrict__ q, const float* __restrict__ wqbk,
                           const float* __restrict__ cdot, float* __restrict__ rav) {
  __shared__ float red[256];
  int r = blockIdx.x, t = threadIdx.x;
  float s = 0.f;
  for (int j = t; j < HID; j += 256) s += q[(long)r * HID + j] * wqbk[j];
  red[t] = s; __syncthreads();
  for (int w = 128; w > 0; w >>= 1) {
    if (t < w) red[t] += red[t + w];
    __syncthreads();
  }
  if (t == 0) rav[r] = SCALE * (red[0] + *cdot);
}

__global__ void colsum_final(const float* __restrict__ part, float* __restrict__ crcp,
                             int Nm, int nParts) {
  int b = blockIdx.y;
  int m = blockIdx.x * 256 + threadIdx.x;
  float s = 0.f;
  for (int p = 0; p < nParts; ++p)
    s += part[((long)p * gridDim.y + b) * Nm + m];
  crcp[(long)b * Nm + m] = 1.0f / s;
}

__device__ __forceinline__ float bf2f(unsigned short u) {
  union { unsigned u32; float f; } x; x.u32 = ((unsigned)u) << 16; return x.f;
}

__global__ void transpose_scale_bf16(const bf16_t* __restrict__ in, const float* __restrict__ crcp,
                                     bf16_t* __restrict__ out, int R, int C, long sIn, long sOut) {
  __shared__ bf16_t tile[64][68];
  int z = blockIdx.z;
  const bf16_t* ip = in + (long)z * sIn;
  bf16_t* op = out + (long)z * sOut;
  const float* rc = crcp + (long)z * R;
  int c0 = blockIdx.x * 64, r0 = blockIdx.y * 64;
#pragma unroll
  for (int i = 0; i < 4; ++i) {
    int chunk = i * 256 + threadIdx.x;
    int r = chunk >> 4, c4 = (chunk & 15) << 2;
    float s = rc[r0 + r];
    ushort4 uv = *(const ushort4*)(ip + (long)(r0 + r) * C + (c0 + c4));
    tile[r][c4 + 0] = (bf16_t)(bf2f(uv.x) * s);
    tile[r][c4 + 1] = (bf16_t)(bf2f(uv.y) * s);
    tile[r][c4 + 2] = (bf16_t)(bf2f(uv.z) * s);
    tile[r][c4 + 3] = (bf16_t)(bf2f(uv.w) * s);
  }
  __syncthreads();
#pragma unroll
  for (int i = 0; i < 4; ++i) {
    int chunk = i * 256 + threadIdx.x;
    int oc = chunk >> 4, or4 = (chunk & 15) << 2;
    union { ushort4 u; bf16_t h[4]; } o;
    o.h[0] = tile[or4 + 0][oc];
    o.h[1] = tile[or4 + 1][oc];
    o.h[2] = tile[or4 + 2][oc];
    o.h[3] = tile[or4 + 3][oc];
    *(ushort4*)(op + (long)(c0 + oc) * R + (r0 + or4)) = o.u;
  }
}

extern "C" void kernel_launch(void* const* d_in, const int* in_sizes, int n_in,
                              void* d_out, int out_size, void* d_ws, size_t ws_size,
                              hipStream_t stream)
{
  (void)in_sizes; (void)n_in; (void)out_size; (void)ws_size;
  const float* q  = (const float*)d_in[0];
  const float* k  = (const float*)d_in[1];
  const float* v  = (const float*)d_in[2];
  const float* Wq = (const float*)d_in[3];
  const float* bq = (const float*)d_in[4];
  const float* Wk = (const float*)d_in[5];
  const float* bk = (const float*)d_in[6];
  const float* Wv = (const float*)d_in[7];
  const float* bv = (const float*)d_in[8];
  const float* Wo = (const float*)d_in[9];
  const float* bo = (const float*)d_in[10];
  float* out = (float*)d_out;

  char* ws = (char*)d_ws;
  const size_t MB = 1u << 20;
  bf16_t* qcat  = (bf16_t*)(ws);              // [0,16)   [8192,1024] (h|l)
  bf16_t* kcat  = (bf16_t*)(ws + 16 * MB);    // [16,32)
  bf16_t* GA    = (bf16_t*)(ws + 32 * MB);    // [32,40)  Wk  [512,8192]
  bf16_t* GB    = (bf16_t*)(ws + 40 * MB);    // [40,48)  Wq
  bf16_t* WoS   = (bf16_t*)(ws + 48 * MB);    // [48,56)  Wo^T [512,8192]
  bf16_t* WvS   = (bf16_t*)(ws + 56 * MB);    // [56,64)  Wv
  float*  Gpart = (float*)(ws + 64 * MB);     // [64,80)  16x[512,512]
  float*  WvoTp = (float*)(ws + 80 * MB);     // [80,96)  6x[512,512]
  bf16_t* Gtcat = (bf16_t*)(ws + 97 * MB);    // [97,98)  [512,1024]
  bf16_t* WvoTb = (bf16_t*)(ws + 98 * MB);    // [98,98.5)
  float*  bvo   = (float*)(ws + 99 * MB);
  float*  wqbk  = (float*)(ws + 99 * MB + 16 * 1024);
  float*  cdot  = (float*)(ws + 99 * MB + 48 * 1024);
  float*  rav   = (float*)(ws + 99 * MB + 64 * 1024);   // 32 KB
  float*  crcp  = (float*)(ws + 99 * MB + 192 * 1024);  // 32 KB
  float*  part  = (float*)(ws + 99 * MB + 256 * 1024);  // 256 KB
  bf16_t* tcat  = (bf16_t*)(ws + 100 * MB);   // [100,116) [8192,1024]
  bf16_t* vbf   = (bf16_t*)(ws + 116 * MB);   // [116,124)
  bf16_t* vo    = (bf16_t*)(ws + 124 * MB);   // [124,132) [8192,512]
  bf16_t* vosT  = (bf16_t*)(ws + 132 * MB);   // [132,140) [B][512,2048]
  bf16_t* P     = (bf16_t*)(ws + 140 * MB);   // [140,172) [B][2048,2048]

  // splits + v cast (batched)
  split2_b3<<<dim3(1024, 3), 256, 0, stream>>>(q, k, v, qcat, kcat, vbf,
      NROW * HID, 9, 0b100);
  split2_b3<<<dim3(1024, 3), 256, 0, stream>>>(Wk, Wq, Wv, GA, GB, WvS,
      (long)HID * PROJ, 12, 0);
  transpose_split2<<<dim3(HID / 32, PROJ / 32), 256, 0, stream>>>(Wo, WoS, PROJ, HID);

  // merged weight GEMM: z<16 -> Gt partials (3-term, K=12288 total);
  // z>=16 -> WvoT partials (single-term h*h, 6x768 chunks; the 512-col
  // overshoot adds only lo-scale junk ~7e-4 rel, below bf16 storage).
  gemm_bt<float, 1, 2><<<dim3(4, 4, 22), 256, 0, stream>>>(GA, GB, Gpart,
      nullptr, 1.0f, HID, HID, 768, 2L * PROJ, 2L * PROJ,
      0, 0, (long)HID * HID, 768, 12, 0,
      WoS, WvS, WvoTp, nullptr, 768, 2L * PROJ, 2L * PROJ, 0, 16);
  reduce2<<<(HID * HID + 255) / 256, 256, 0, stream>>>(Gpart, WvoTp, Gtcat, WvoTb,
      SCALE, HID * HID, 16, 6);

  // rank-1 bias terms
  rank1<<<dim3(HID, 3), 256, 0, stream>>>(Wq, bk, bq, WoS, bv, wqbk, bvo, cdot);
  rowdot_rav<<<(int)NROW, 256, 0, stream>>>(q, wqbk, cdot, rav);

  // merged: z=0 t = q.Gt^T (K=1536, h/l split out); z=1 vo = v.Wvo + bvo
  gemm_bt<bf16_t, 1, 2><<<dim3(4, 64, 2), 256, 0, stream>>>(qcat, Gtcat, tcat,
      nullptr, 1.0f, (int)NROW, HID, 1536, 1024, 1024, 0, 0, 0, 0, 9, 2,
      vbf, WvoTb, vo, bvo, HID, HID, HID, 0, 1);

  // P = exp(t.k^T + ra) — 8-phase 256^2, fused col partial sums
  gemm8exp<<<dim3(8, 8, BSZ), 512, 0, stream>>>(tcat, kcat, P, rav, part);
  colsum_final<<<dim3(SEQ / 256, BSZ), 256, 0, stream>>>(part, crcp, SEQ, 8);

  // vosT[z][d,m] = vo[z][m,d] / csum[z][m]
  transpose_scale_bf16<<<dim3(HID / 64, SEQ / 64, BSZ), 256, 0, stream>>>(
      vo, crcp, vosT, SEQ, HID, (long)SEQ * HID, (long)HID * SEQ);

  // out = P.vosT^T + bo
  gemm_bt<float, 0, 0><<<dim3(4, 16, BSZ), 256, 0, stream>>>(P, vosT, out,
      bo, 1.0f, SEQ, HID, SEQ, SEQ, SEQ,
      (long)SEQ * SEQ, (long)HID * SEQ, (long)SEQ * HID, 0, 0, 0,
      nullptr, nullptr, nullptr, nullptr, 0, 0, 0, 0, 0);
}

// Round 10
// 203.766 us; speedup vs baseline: 2.0132x; 1.0313x over previous
//
#include <hip/hip_runtime.h>
#include <hip/hip_bf16.h>

#define AS1 __attribute__((address_space(1)))
#define AS3 __attribute__((address_space(3)))

typedef __bf16 bf16_t;
typedef __attribute__((ext_vector_type(8))) __bf16 bf16x8;
typedef __attribute__((ext_vector_type(4))) float f32x4;

static constexpr int BSZ = 4, SEQ = 2048, HID = 512, PROJ = 4096;
static constexpr long NROW = (long)BSZ * SEQ;  // 8192
static constexpr float SCALE = 0.125f;

__device__ __forceinline__ void gload_lds16(const void* g, void* l) {
  __builtin_amdgcn_global_load_lds((const AS1 void*)g, (AS3 void*)l, 16, 0, 0);
}

// map logical K index -> storage col for 2-wide [h|l] split buffers.
// MAP 0: identity. MAP 1: logical thirds (h,l,h). MAP 2: logical thirds (h,h,l).
template <int MAP>
__device__ __forceinline__ long mapk(long c, int s) {
  if (MAP == 0) return c;
  long w = c & ((1L << s) - 1);
  long t = c >> s;
  bool lo = (MAP == 1) ? (t == 1) : (t == 2);
  return (lo ? (1L << s) : 0) + w;
}

// ==================================================================
// 8-phase 256x256 GEMM for P = exp(t.k^T + ra) with fused column
// partial sums (r6-proven schedule).
// ==================================================================
__device__ __forceinline__ void stage_half8(
    const bf16_t* __restrict__ G, long ldg, long rcBase, long kcol,
    int half, bf16_t* dst, int tid)
{
#pragma unroll
  for (int it = 0; it < 2; ++it) {
    int li = it * 512 + tid;
    int row = li >> 3;
    int srcb = ((li & 7) << 4) ^ ((row & 7) << 4);
    gload_lds16(G + (rcBase + half * 128 + row) * ldg + kcol + (srcb >> 1),
                (char*)dst + li * 16);
  }
}

#define PH_PRE()  __builtin_amdgcn_s_barrier(); \
                  asm volatile("s_waitcnt lgkmcnt(0)" ::: "memory"); \
                  __builtin_amdgcn_sched_barrier(0); \
                  __builtin_amdgcn_s_setprio(1);
#define PH_POST() __builtin_amdgcn_s_setprio(0); \
                  __builtin_amdgcn_s_barrier(); \
                  __builtin_amdgcn_sched_barrier(0);

__global__ __launch_bounds__(512, 2) void gemm8exp(
    const bf16_t* __restrict__ A, const bf16_t* __restrict__ B,
    bf16_t* __restrict__ C, const float* __restrict__ ra,
    float* __restrict__ part)
{
  constexpr int NT = 24;            // K = 1536
  constexpr long LDA = 1024, LDB = 1024;
  constexpr int M = 2048, N = 2048;
  __shared__ __align__(16) bf16_t lds8[65536];  // 128 KB

  const int z = blockIdx.z;
  A += (long)z * SEQ * LDA;
  B += (long)z * SEQ * LDB;
  C += (long)z * (long)SEQ * SEQ;

  const int id0 = blockIdx.y * 8 + blockIdx.x;
  const int swz = (id0 & 7) * 8 + (id0 >> 3);
  const int bx = swz & 7, by = swz >> 3;
  const long rowBase = (long)by * 256;
  const long colBase = (long)bx * 256;

  const int tid = threadIdx.x;
  const int lane = tid & 63;
  const int wid = tid >> 6;
  const int wm = wid >> 2;
  const int wn = wid & 3;
  const int l15 = lane & 15;
  const int kgb = (lane >> 4) << 4;

  f32x4 acc[8][4] = {};
  bf16x8 afr[4][2];
  bf16x8 bfr[2][2][2];

  {
    const long ka0 = mapk<1>(0, 9), kb0 = mapk<2>(0, 9);
    const long ka1 = mapk<1>(64, 9);
    stage_half8(A, LDA, rowBase, ka0, 0, lds8 + 0 * 8192, tid);
    stage_half8(A, LDA, rowBase, ka0, 1, lds8 + 1 * 8192, tid);
    stage_half8(B, LDB, colBase, kb0, 0, lds8 + 2 * 8192, tid);
    stage_half8(B, LDB, colBase, kb0, 1, lds8 + 3 * 8192, tid);
    stage_half8(A, LDA, rowBase, ka1, 0, lds8 + 32768 + 0 * 8192, tid);
    asm volatile("s_waitcnt vmcnt(2)" ::: "memory");
    __builtin_amdgcn_s_barrier();
    __builtin_amdgcn_sched_barrier(0);
  }

  for (int t = 0; t < NT; ++t) {
    const int d = t & 1;
    bf16_t* bufc = lds8 + d * 32768;
    bf16_t* bufn = lds8 + (d ^ 1) * 32768;
    const bf16_t* Ah = bufc + wm * 8192;
    const bf16_t* Bh = bufc + 16384 + (wn >> 1) * 8192;
    const long ka1 = mapk<1>((long)(t + 1) * 64, 9);
    const long kb1 = mapk<2>((long)(t + 1) * 64, 9);
    const long ka2 = mapk<1>((long)(t + 2) * 64, 9);

    // phase 0
#pragma unroll
    for (int r = 0; r < 4; ++r)
#pragma unroll
      for (int kk = 0; kk < 2; ++kk) {
        int lrow = r * 16 + l15;
        int off = (lrow << 7) + (((kk << 6) + kgb) ^ ((lrow & 7) << 4));
        afr[r][kk] = *(const bf16x8*)((const char*)Ah + off);
      }
#pragma unroll
    for (int c = 0; c < 2; ++c)
#pragma unroll
      for (int kk = 0; kk < 2; ++kk) {
        int lrow = (wn & 1) * 64 + c * 16 + l15;
        int off = (lrow << 7) + (((kk << 6) + kgb) ^ ((lrow & 7) << 4));
        bfr[0][c][kk] = *(const bf16x8*)((const char*)Bh + off);
      }
    if (t + 1 < NT) stage_half8(A, LDA, rowBase, ka1, 1, bufn + 1 * 8192, tid);
    PH_PRE();
#pragma unroll
    for (int r = 0; r < 4; ++r)
#pragma unroll
      for (int c = 0; c < 2; ++c)
#pragma unroll
        for (int kk = 0; kk < 2; ++kk)
          acc[r][c] = __builtin_amdgcn_mfma_f32_16x16x32_bf16(
              afr[r][kk], bfr[0][c][kk], acc[r][c], 0, 0, 0);
    PH_POST();

    // phase 1
#pragma unroll
    for (int c = 0; c < 2; ++c)
#pragma unroll
      for (int kk = 0; kk < 2; ++kk) {
        int lrow = (wn & 1) * 64 + 32 + c * 16 + l15;
        int off = (lrow << 7) + (((kk << 6) + kgb) ^ ((lrow & 7) << 4));
        bfr[1][c][kk] = *(const bf16x8*)((const char*)Bh + off);
      }
    if (t + 1 < NT) stage_half8(B, LDB, colBase, kb1, 0, bufn + 2 * 8192, tid);
    PH_PRE();
#pragma unroll
    for (int r = 0; r < 4; ++r)
#pragma unroll
      for (int c = 0; c < 2; ++c)
#pragma unroll
        for (int kk = 0; kk < 2; ++kk)
          acc[r][2 + c] = __builtin_amdgcn_mfma_f32_16x16x32_bf16(
              afr[r][kk], bfr[1][c][kk], acc[r][2 + c], 0, 0, 0);
    PH_POST();

    // phase 2
#pragma unroll
    for (int r = 0; r < 4; ++r)
#pragma unroll
      for (int kk = 0; kk < 2; ++kk) {
        int lrow = 64 + r * 16 + l15;
        int off = (lrow << 7) + (((kk << 6) + kgb) ^ ((lrow & 7) << 4));
        afr[r][kk] = *(const bf16x8*)((const char*)Ah + off);
      }
    if (t + 1 < NT) stage_half8(B, LDB, colBase, kb1, 1, bufn + 3 * 8192, tid);
    PH_PRE();
#pragma unroll
    for (int r = 0; r < 4; ++r)
#pragma unroll
      for (int c = 0; c < 2; ++c)
#pragma unroll
        for (int kk = 0; kk < 2; ++kk)
          acc[4 + r][c] = __builtin_amdgcn_mfma_f32_16x16x32_bf16(
              afr[r][kk], bfr[0][c][kk], acc[4 + r][c], 0, 0, 0);
    PH_POST();

    // phase 3
    if (t + 2 < NT) stage_half8(A, LDA, rowBase, ka2, 0, bufc + 0 * 8192, tid);
    __builtin_amdgcn_s_barrier();
    __builtin_amdgcn_s_setprio(1);
#pragma unroll
    for (int r = 0; r < 4; ++r)
#pragma unroll
      for (int c = 0; c < 2; ++c)
#pragma unroll
        for (int kk = 0; kk < 2; ++kk)
          acc[4 + r][2 + c] = __builtin_amdgcn_mfma_f32_16x16x32_bf16(
              afr[r][kk], bfr[1][c][kk], acc[4 + r][2 + c], 0, 0, 0);
    __builtin_amdgcn_s_setprio(0);
    if (t < NT - 2) { asm volatile("s_waitcnt vmcnt(2)" ::: "memory"); }
    else            { asm volatile("s_waitcnt vmcnt(0)" ::: "memory"); }
    __builtin_amdgcn_s_barrier();
    __builtin_amdgcn_sched_barrier(0);
  }

  // epilogue: exp + ra + store + fused column partial sums
  __syncthreads();
  float* cs = (float*)lds8;
  float csum[4] = {0.f, 0.f, 0.f, 0.f};
#pragma unroll
  for (int qr = 0; qr < 2; ++qr)
#pragma unroll
    for (int r = 0; r < 4; ++r) {
      long row0 = rowBase + wm * 128 + qr * 64 + r * 16 + ((lane >> 4) << 2);
      float4 ra4 = *(const float4*)(ra + (long)z * M + row0);
#pragma unroll
      for (int cf = 0; cf < 4; ++cf) {
        long col = colBase + wn * 64 + cf * 16 + l15;
        f32x4 v4 = acc[qr * 4 + r][cf];
        float rr[4] = {ra4.x, ra4.y, ra4.z, ra4.w};
#pragma unroll
        for (int e = 0; e < 4; ++e) {
          float v = __expf(v4[e] + rr[e]);
          C[(row0 + e) * (long)N + col] = (bf16_t)v;
          csum[cf] += v;
        }
      }
    }
#pragma unroll
  for (int cf = 0; cf < 4; ++cf) {
    float s = csum[cf];
    s += __shfl_xor(s, 16);
    s += __shfl_xor(s, 32);
    if (lane < 16) cs[wm * 256 + wn * 64 + cf * 16 + lane] = s;
  }
  __syncthreads();
  if (tid < 256)
    part[((long)by * gridDim.z + z) * N + colBase + tid] = cs[tid] + cs[256 + tid];
}

// ------------------------------------------------------------------
// 128x128 m97-structure GEMM; runtime outm (0: (acc+bias)*scale,
// 2: h/l split write). Second param set selected for z >= zSplit.
// ------------------------------------------------------------------
template <typename OutT, int AMAP, int BMAP>
__global__ __launch_bounds__(256) void gemm_bt(
    const bf16_t* __restrict__ A, const bf16_t* __restrict__ B,
    OutT* __restrict__ C, const float* __restrict__ bias,
    float scale, int M, int N, int K, long lda, long ldb,
    long sA, long sB, long sC, long kz, int sshift, int outm,
    const bf16_t* __restrict__ A2, const bf16_t* __restrict__ B2,
    OutT* __restrict__ C2, const float* __restrict__ bias2,
    int K2, long lda2, long ldb2, int outm2, int zSplit)
{
  __shared__ __align__(16) bf16_t As[128 * 64];
  __shared__ __align__(16) bf16_t Bs[128 * 64];
  int z = blockIdx.z;
  if (zSplit > 0 && z >= zSplit) {
    A = A2; B = B2; C = C2; bias = bias2;
    K = K2; lda = lda2; ldb = ldb2; outm = outm2;
    z -= zSplit;
  }
  A += (long)z * sA; B += (long)z * sB; C += (long)z * sC;

  const int gx = gridDim.x;
  const int nwg = gx * gridDim.y;
  const int id = blockIdx.y * gx + blockIdx.x;
  const int qq = nwg >> 3, rr = nwg & 7;
  const int xcd = id & 7, jj = id >> 3;
  const int swz = (xcd < rr ? xcd * (qq + 1) : rr * (qq + 1) + (xcd - rr) * qq) + jj;
  const int bx = swz % gx, by = swz / gx;

  const int tid  = threadIdx.x;
  const int lane = tid & 63;
  const int wid  = tid >> 6;
  const int wr = (wid >> 1) * 64;
  const int wc = (wid & 1) * 64;
  const long rowBase = (long)by * 128;
  const long colBase = (long)bx * 128;

  f32x4 acc[4][4] = {};

  int srow[4], scol[4];
#pragma unroll
  for (int i = 0; i < 4; ++i) {
    int li = i * 256 + tid;
    int row = li >> 3;
    int inner = (li & 7) << 4;
    int src = inner ^ ((row & 7) << 4);
    srow[i] = row;
    scol[i] = src >> 1;
  }

  for (int k0 = 0; k0 < K; k0 += 64) {
    const long k0L = kz * z + k0;
    const long ka = mapk<AMAP>(k0L, sshift);
    const long kb = mapk<BMAP>(k0L, sshift);
    __syncthreads();
#pragma unroll
    for (int i = 0; i < 4; ++i) {
      int li = i * 256 + tid;
      gload_lds16(A + (rowBase + srow[i]) * lda + ka + scol[i], (char*)As + li * 16);
      gload_lds16(B + (colBase + srow[i]) * ldb + kb + scol[i], (char*)Bs + li * 16);
    }
    __syncthreads();
#pragma unroll
    for (int kk = 0; kk < 64; kk += 32) {
      const int kbyte = (kk + ((lane >> 4) << 3)) << 1;
      bf16x8 af[4], bfr[4];
#pragma unroll
      for (int m = 0; m < 4; ++m) {
        int row = wr + m * 16 + (lane & 15);
        int off = (row << 7) + (kbyte ^ ((row & 7) << 4));
        af[m] = *(const bf16x8*)((const char*)As + off);
      }
#pragma unroll
      for (int n = 0; n < 4; ++n) {
        int row = wc + n * 16 + (lane & 15);
        int off = (row << 7) + (kbyte ^ ((row & 7) << 4));
        bfr[n] = *(const bf16x8*)((const char*)Bs + off);
      }
#pragma unroll
      for (int m = 0; m < 4; ++m)
#pragma unroll
        for (int n = 0; n < 4; ++n)
          acc[m][n] = __builtin_amdgcn_mfma_f32_16x16x32_bf16(af[m], bfr[n], acc[m][n], 0, 0, 0);
    }
  }

  if (outm == 2) {
#pragma unroll
    for (int n = 0; n < 4; ++n) {
      const long col = colBase + wc + n * 16 + (lane & 15);
#pragma unroll
      for (int m = 0; m < 4; ++m) {
#pragma unroll
        for (int e = 0; e < 4; ++e) {
          const long row = rowBase + wr + m * 16 + (lane >> 4) * 4 + e;
          float v = acc[m][n][e] * scale;
          bf16_t h = (bf16_t)v;
          bf16_t l = (bf16_t)(v - (float)h);
          C[row * (2L * N) + col] = (OutT)h;
          C[row * (2L * N) + N + col] = (OutT)l;
        }
      }
    }
  } else {
#pragma unroll
    for (int n = 0; n < 4; ++n) {
      const long col = colBase + wc + n * 16 + (lane & 15);
      const float bv_ = bias ? bias[col] : 0.0f;
#pragma unroll
      for (int m = 0; m < 4; ++m) {
#pragma unroll
        for (int e = 0; e < 4; ++e) {
          const long row = rowBase + wr + m * 16 + (lane >> 4) * 4 + e;
          C[row * (long)N + col] = (OutT)((acc[m][n][e] + bv_) * scale);
        }
      }
    }
  }
}

// f32 -> bf16 h/l split [R,2C] (or plain cast if castMask bit set),
// vectorized x4; up to 3 tensors batched via blockIdx.y.
__global__ void split2_b3(const float* __restrict__ in0, const float* __restrict__ in1,
                          const float* __restrict__ in2,
                          bf16_t* __restrict__ o0, bf16_t* __restrict__ o1,
                          bf16_t* __restrict__ o2, long n, int cshift, int castMask) {
  const float* in = (blockIdx.y == 0) ? in0 : (blockIdx.y == 1) ? in1 : in2;
  bf16_t* out = (blockIdx.y == 0) ? o0 : (blockIdx.y == 1) ? o1 : o2;
  const bool castOnly = (castMask >> blockIdx.y) & 1;
  long C = 1L << cshift;
  long i0 = ((long)blockIdx.x * blockDim.x + threadIdx.x) * 4;
  long stride = (long)gridDim.x * blockDim.x * 4;
  for (long i = i0; i < n; i += stride) {
    float4 f = *(const float4*)(in + i);
    union { ushort4 u; bf16_t h[4]; } H, L;
    float fv[4] = {f.x, f.y, f.z, f.w};
#pragma unroll
    for (int j = 0; j < 4; ++j) {
      bf16_t h = (bf16_t)fv[j];
      H.h[j] = h;
      L.h[j] = (bf16_t)(fv[j] - (float)h);
    }
    if (castOnly) {
      *(ushort4*)(out + i) = H.u;
    } else {
      long r = i >> cshift, c = i & (C - 1);
      *(ushort4*)(out + r * 2 * C + c) = H.u;
      *(ushort4*)(out + r * 2 * C + C + c) = L.u;
    }
  }
}

// merged weight prep: y<3 -> h/l split of Wk/Wq/Wv; y=3 -> transpose-split Wo.
__global__ void splitW(const float* __restrict__ Wk, const float* __restrict__ Wq,
                       const float* __restrict__ Wv, const float* __restrict__ Wo,
                       bf16_t* __restrict__ GA, bf16_t* __restrict__ GB,
                       bf16_t* __restrict__ WvS, bf16_t* __restrict__ WoS) {
  __shared__ float tile[32][33];
  const int y = blockIdx.y;
  if (y < 3) {
    const float* in = (y == 0) ? Wk : (y == 1) ? Wq : Wv;
    bf16_t* out = (y == 0) ? GA : (y == 1) ? GB : WvS;
    const long n = (long)HID * PROJ;
    long i0 = ((long)blockIdx.x * blockDim.x + threadIdx.x) * 4;
    long stride = (long)gridDim.x * blockDim.x * 4;
    for (long i = i0; i < n; i += stride) {
      float4 f = *(const float4*)(in + i);
      union { ushort4 u; bf16_t h[4]; } H, L;
      float fv[4] = {f.x, f.y, f.z, f.w};
#pragma unroll
      for (int j = 0; j < 4; ++j) {
        bf16_t h = (bf16_t)fv[j];
        H.h[j] = h;
        L.h[j] = (bf16_t)(fv[j] - (float)h);
      }
      long r = i >> 12, c = i & (PROJ - 1);
      *(ushort4*)(out + r * 2 * PROJ + c) = H.u;
      *(ushort4*)(out + r * 2 * PROJ + PROJ + c) = L.u;
    }
  } else {
    // Wo [PROJ, HID] -> WoS [HID, 2*PROJ] (h|l); grid.x = 16*128 = 2048
    int bx = blockIdx.x;
    int c0 = (bx & 15) * 32, r0 = (bx >> 4) * 32;
    int tx = threadIdx.x & 31, ty = threadIdx.x >> 5;
#pragma unroll
    for (int i = 0; i < 32; i += 8)
      tile[ty + i][tx] = Wo[(long)(r0 + ty + i) * HID + (c0 + tx)];
    __syncthreads();
#pragma unroll
    for (int i = 0; i < 32; i += 8) {
      float x = tile[tx][ty + i];
      bf16_t h = (bf16_t)x;
      bf16_t l = (bf16_t)(x - (float)h);
      long o = (long)(c0 + ty + i) * 2 * PROJ + (r0 + tx);
      WoS[o] = h;
      WoS[o + PROJ] = l;
    }
  }
}

// merged: y=0 -> reduce partials into Gtcat (h|l, scaled) + WvoTb (bf16);
// y=1 wqbk[bx]=Wq[bx,:].bk; y=2 bvo[bx]=WoT[bx,:].bv; y=3 cdot=bq.bk
__global__ void reduce2rank1(const float* __restrict__ gp, const float* __restrict__ wp,
                             bf16_t* __restrict__ Gtcat, bf16_t* __restrict__ WvoTb,
                             const float* __restrict__ Wq, const float* __restrict__ bk,
                             const float* __restrict__ bq,
                             const bf16_t* __restrict__ WoS, const float* __restrict__ bv,
                             float* __restrict__ wqbk, float* __restrict__ bvo,
                             float* __restrict__ cdot,
                             float scale, int nElem, int nP1, int nP2) {
  __shared__ float red[256];
  const int y = blockIdx.y, bx = blockIdx.x, t = threadIdx.x;
  if (y == 0) {
    int i = bx * 256 + t;
    if (i < nElem) {
      float a = 0.f, b = 0.f;
      for (int p = 0; p < nP1; ++p) a += gp[(long)p * nElem + i];
      for (int p = 0; p < nP2; ++p) b += wp[(long)p * nElem + i];
      a *= scale;
      int r = i >> 9, c = i & 511;
      bf16_t h = (bf16_t)a;
      Gtcat[(long)r * 1024 + c] = h;
      Gtcat[(long)r * 1024 + 512 + c] = (bf16_t)(a - (float)h);
      WvoTb[i] = (bf16_t)b;
    }
    return;
  }
  if (bx >= HID || (y == 3 && bx != 0)) return;
  float s = 0.f;
  if (y == 1) {
    for (int j = t; j < PROJ; j += 256) s += Wq[(long)bx * PROJ + j] * bk[j];
  } else if (y == 2) {
    const bf16_t* row = WoS + (long)bx * 2 * PROJ;
    for (int j = t; j < PROJ; j += 256)
      s += ((float)row[j] + (float)row[PROJ + j]) * bv[j];
  } else {
    for (int j = t; j < PROJ; j += 256) s += bq[j] * bk[j];
  }
  red[t] = s; __syncthreads();
  for (int w = 128; w > 0; w >>= 1) {
    if (t < w) red[t] += red[t + w];
    __syncthreads();
  }
  if (t == 0) {
    if (y == 1) wqbk[bx] = red[0];
    else if (y == 2) bvo[bx] = red[0];
    else *cdot = red[0];
  }
}

// rav[r] = SCALE*(q[r].wqbk + cdot)
__global__ void rowdot_rav(const float* __restrict__ q, const float* __restrict__ wqbk,
                           const float* __restrict__ cdot, float* __restrict__ rav) {
  __shared__ float red[256];
  int r = blockIdx.x, t = threadIdx.x;
  float s = 0.f;
  for (int j = t; j < HID; j += 256) s += q[(long)r * HID + j] * wqbk[j];
  red[t] = s; __syncthreads();
  for (int w = 128; w > 0; w >>= 1) {
    if (t < w) red[t] += red[t + w];
    __syncthreads();
  }
  if (t == 0) rav[r] = SCALE * (red[0] + *cdot);
}

__device__ __forceinline__ float bf2f(unsigned short u) {
  union { unsigned u32; float f; } x; x.u32 = ((unsigned)u) << 16; return x.f;
}

// bf16 [R,C] -> bf16 [C,R], scaling input row r by 1/csum[r] where
// csum is reduced inline from the 8 column-sum partials (fused colsum_final).
__global__ void transpose_scale_cs(const bf16_t* __restrict__ in,
                                   const float* __restrict__ part,
                                   bf16_t* __restrict__ out, int R, int C,
                                   long sIn, long sOut, int nParts) {
  __shared__ bf16_t tile[64][68];
  __shared__ float rcL[64];
  int z = blockIdx.z;
  const bf16_t* ip = in + (long)z * sIn;
  bf16_t* op = out + (long)z * sOut;
  int c0 = blockIdx.x * 64, r0 = blockIdx.y * 64;
  if (threadIdx.x < 64) {
    int m = r0 + threadIdx.x;
    float s = 0.f;
    for (int p = 0; p < nParts; ++p)
      s += part[((long)p * gridDim.z + z) * R + m];
    rcL[threadIdx.x] = 1.0f / s;
  }
  __syncthreads();
#pragma unroll
  for (int i = 0; i < 4; ++i) {
    int chunk = i * 256 + threadIdx.x;
    int r = chunk >> 4, c4 = (chunk & 15) << 2;
    float s = rcL[r];
    ushort4 uv = *(const ushort4*)(ip + (long)(r0 + r) * C + (c0 + c4));
    tile[r][c4 + 0] = (bf16_t)(bf2f(uv.x) * s);
    tile[r][c4 + 1] = (bf16_t)(bf2f(uv.y) * s);
    tile[r][c4 + 2] = (bf16_t)(bf2f(uv.z) * s);
    tile[r][c4 + 3] = (bf16_t)(bf2f(uv.w) * s);
  }
  __syncthreads();
#pragma unroll
  for (int i = 0; i < 4; ++i) {
    int chunk = i * 256 + threadIdx.x;
    int oc = chunk >> 4, or4 = (chunk & 15) << 2;
    union { ushort4 u; bf16_t h[4]; } o;
    o.h[0] = tile[or4 + 0][oc];
    o.h[1] = tile[or4 + 1][oc];
    o.h[2] = tile[or4 + 2][oc];
    o.h[3] = tile[or4 + 3][oc];
    *(ushort4*)(op + (long)(c0 + oc) * R + (r0 + or4)) = o.u;
  }
}

extern "C" void kernel_launch(void* const* d_in, const int* in_sizes, int n_in,
                              void* d_out, int out_size, void* d_ws, size_t ws_size,
                              hipStream_t stream)
{
  (void)in_sizes; (void)n_in; (void)out_size; (void)ws_size;
  const float* q  = (const float*)d_in[0];
  const float* k  = (const float*)d_in[1];
  const float* v  = (const float*)d_in[2];
  const float* Wq = (const float*)d_in[3];
  const float* bq = (const float*)d_in[4];
  const float* Wk = (const float*)d_in[5];
  const float* bk = (const float*)d_in[6];
  const float* Wv = (const float*)d_in[7];
  const float* bv = (const float*)d_in[8];
  const float* Wo = (const float*)d_in[9];
  const float* bo = (const float*)d_in[10];
  float* out = (float*)d_out;

  char* ws = (char*)d_ws;
  const size_t MB = 1u << 20;
  bf16_t* qcat  = (bf16_t*)(ws);              // [0,16)   [8192,1024] (h|l)
  bf16_t* kcat  = (bf16_t*)(ws + 16 * MB);    // [16,32)
  bf16_t* GA    = (bf16_t*)(ws + 32 * MB);    // [32,40)  Wk  [512,8192]
  bf16_t* GB    = (bf16_t*)(ws + 40 * MB);    // [40,48)  Wq
  bf16_t* WoS   = (bf16_t*)(ws + 48 * MB);    // [48,56)  Wo^T [512,8192]
  bf16_t* WvS   = (bf16_t*)(ws + 56 * MB);    // [56,64)  Wv
  float*  Gpart = (float*)(ws + 64 * MB);     // [64,80)  16x[512,512]
  float*  WvoTp = (float*)(ws + 80 * MB);     // [80,96)  6x[512,512]
  bf16_t* Gtcat = (bf16_t*)(ws + 97 * MB);    // [97,98)  [512,1024]
  bf16_t* WvoTb = (bf16_t*)(ws + 98 * MB);    // [98,98.5)
  float*  bvo   = (float*)(ws + 99 * MB);
  float*  wqbk  = (float*)(ws + 99 * MB + 16 * 1024);
  float*  cdot  = (float*)(ws + 99 * MB + 48 * 1024);
  float*  rav   = (float*)(ws + 99 * MB + 64 * 1024);   // 32 KB
  float*  part  = (float*)(ws + 99 * MB + 256 * 1024);  // 256 KB
  bf16_t* tcat  = (bf16_t*)(ws + 100 * MB);   // [100,116) [8192,1024]
  bf16_t* vbf   = (bf16_t*)(ws + 116 * MB);   // [116,124)
  bf16_t* vo    = (bf16_t*)(ws + 124 * MB);   // [124,132) [8192,512]
  bf16_t* vosT  = (bf16_t*)(ws + 132 * MB);   // [132,140) [B][512,2048]
  bf16_t* P     = (bf16_t*)(ws + 140 * MB);   // [140,172) [B][2048,2048]

  // q/k split + v cast (batched)
  split2_b3<<<dim3(1024, 3), 256, 0, stream>>>(q, k, v, qcat, kcat, vbf,
      NROW * HID, 9, 0b100);
  // weight splits + Wo transpose-split, one dispatch
  splitW<<<dim3(2048, 4), 256, 0, stream>>>(Wk, Wq, Wv, Wo, GA, GB, WvS, WoS);

  // merged weight GEMM: z<16 -> Gt partials (3-term); z>=16 -> WvoT (h*h)
  gemm_bt<float, 1, 2><<<dim3(4, 4, 22), 256, 0, stream>>>(GA, GB, Gpart,
      nullptr, 1.0f, HID, HID, 768, 2L * PROJ, 2L * PROJ,
      0, 0, (long)HID * HID, 768, 12, 0,
      WoS, WvS, WvoTp, nullptr, 768, 2L * PROJ, 2L * PROJ, 0, 16);
  // reduce partials + rank-1 bias prep, one dispatch
  reduce2rank1<<<dim3(1024, 4), 256, 0, stream>>>(Gpart, WvoTp, Gtcat, WvoTb,
      Wq, bk, bq, WoS, bv, wqbk, bvo, cdot, SCALE, HID * HID, 16, 6);
  rowdot_rav<<<(int)NROW, 256, 0, stream>>>(q, wqbk, cdot, rav);

  // merged: z=0 t = q.Gt^T (K=1536, h/l split out); z=1 vo = v.Wvo + bvo
  gemm_bt<bf16_t, 1, 2><<<dim3(4, 64, 2), 256, 0, stream>>>(qcat, Gtcat, tcat,
      nullptr, 1.0f, (int)NROW, HID, 1536, 1024, 1024, 0, 0, 0, 0, 9, 2,
      vbf, WvoTb, vo, bvo, HID, HID, HID, 0, 1);

  // P = exp(t.k^T + ra) — 8-phase 256^2, fused col partial sums
  gemm8exp<<<dim3(8, 8, BSZ), 512, 0, stream>>>(tcat, kcat, P, rav, part);

  // vosT[z][d,m] = vo[z][m,d] / csum[z][m]  (csum reduced inline from part)
  transpose_scale_cs<<<dim3(HID / 64, SEQ / 64, BSZ), 256, 0, stream>>>(
      vo, part, vosT, SEQ, HID, (long)SEQ * HID, (long)HID * SEQ, 8);

  // out = P.vosT^T + bo
  gemm_bt<float, 0, 0><<<dim3(4, 16, BSZ), 256, 0, stream>>>(P, vosT, out,
      bo, 1.0f, SEQ, HID, SEQ, SEQ, SEQ,
      (long)SEQ * SEQ, (long)HID * SEQ, (long)SEQ * HID, 0, 0, 0,
      nullptr, nullptr, nullptr, nullptr, 0, 0, 0, 0, 0);
}

// Round 11
// 195.940 us; speedup vs baseline: 2.0936x; 1.0399x over previous
//
#include <hip/hip_runtime.h>
#include <hip/hip_bf16.h>

#define AS1 __attribute__((address_space(1)))
#define AS3 __attribute__((address_space(3)))

typedef __bf16 bf16_t;
typedef __attribute__((ext_vector_type(8))) __bf16 bf16x8;
typedef __attribute__((ext_vector_type(4))) float f32x4;

static constexpr int BSZ = 4, SEQ = 2048, HID = 512, PROJ = 4096;
static constexpr long NROW = (long)BSZ * SEQ;  // 8192
static constexpr float SCALE = 0.125f;

__device__ __forceinline__ void gload_lds16(const void* g, void* l) {
  __builtin_amdgcn_global_load_lds((const AS1 void*)g, (AS3 void*)l, 16, 0, 0);
}

// map logical K index -> storage col for 2-wide [h|l] split buffers.
// MAP 0: identity. MAP 1: logical thirds (h,l,h). MAP 2: logical thirds (h,h,l).
template <int MAP>
__device__ __forceinline__ long mapk(long c, int s) {
  if (MAP == 0) return c;
  long w = c & ((1L << s) - 1);
  long t = c >> s;
  bool lo = (MAP == 1) ? (t == 1) : (t == 2);
  return (lo ? (1L << s) : 0) + w;
}

// ==================================================================
// 8-phase 256x256 GEMM for P = exp(t.k^T + ra) with fused column
// partial sums (r6-proven schedule).
// ==================================================================
__device__ __forceinline__ void stage_half8(
    const bf16_t* __restrict__ G, long ldg, long rcBase, long kcol,
    int half, bf16_t* dst, int tid)
{
#pragma unroll
  for (int it = 0; it < 2; ++it) {
    int li = it * 512 + tid;
    int row = li >> 3;
    int srcb = ((li & 7) << 4) ^ ((row & 7) << 4);
    gload_lds16(G + (rcBase + half * 128 + row) * ldg + kcol + (srcb >> 1),
                (char*)dst + li * 16);
  }
}

#define PH_PRE()  __builtin_amdgcn_s_barrier(); \
                  asm volatile("s_waitcnt lgkmcnt(0)" ::: "memory"); \
                  __builtin_amdgcn_sched_barrier(0); \
                  __builtin_amdgcn_s_setprio(1);
#define PH_POST() __builtin_amdgcn_s_setprio(0); \
                  __builtin_amdgcn_s_barrier(); \
                  __builtin_amdgcn_sched_barrier(0);

__global__ __launch_bounds__(512, 2) void gemm8exp(
    const bf16_t* __restrict__ A, const bf16_t* __restrict__ B,
    bf16_t* __restrict__ C, const float* __restrict__ ra,
    float* __restrict__ part)
{
  constexpr int NT = 24;            // K = 1536
  constexpr long LDA = 1024, LDB = 1024;
  constexpr int M = 2048, N = 2048;
  __shared__ __align__(16) bf16_t lds8[65536];  // 128 KB

  const int z = blockIdx.z;
  A += (long)z * SEQ * LDA;
  B += (long)z * SEQ * LDB;
  C += (long)z * (long)SEQ * SEQ;

  const int id0 = blockIdx.y * 8 + blockIdx.x;
  const int swz = (id0 & 7) * 8 + (id0 >> 3);
  const int bx = swz & 7, by = swz >> 3;
  const long rowBase = (long)by * 256;
  const long colBase = (long)bx * 256;

  const int tid = threadIdx.x;
  const int lane = tid & 63;
  const int wid = tid >> 6;
  const int wm = wid >> 2;
  const int wn = wid & 3;
  const int l15 = lane & 15;
  const int kgb = (lane >> 4) << 4;

  f32x4 acc[8][4] = {};
  bf16x8 afr[4][2];
  bf16x8 bfr[2][2][2];

  {
    const long ka0 = mapk<1>(0, 9), kb0 = mapk<2>(0, 9);
    const long ka1 = mapk<1>(64, 9);
    stage_half8(A, LDA, rowBase, ka0, 0, lds8 + 0 * 8192, tid);
    stage_half8(A, LDA, rowBase, ka0, 1, lds8 + 1 * 8192, tid);
    stage_half8(B, LDB, colBase, kb0, 0, lds8 + 2 * 8192, tid);
    stage_half8(B, LDB, colBase, kb0, 1, lds8 + 3 * 8192, tid);
    stage_half8(A, LDA, rowBase, ka1, 0, lds8 + 32768 + 0 * 8192, tid);
    asm volatile("s_waitcnt vmcnt(2)" ::: "memory");
    __builtin_amdgcn_s_barrier();
    __builtin_amdgcn_sched_barrier(0);
  }

  for (int t = 0; t < NT; ++t) {
    const int d = t & 1;
    bf16_t* bufc = lds8 + d * 32768;
    bf16_t* bufn = lds8 + (d ^ 1) * 32768;
    const bf16_t* Ah = bufc + wm * 8192;
    const bf16_t* Bh = bufc + 16384 + (wn >> 1) * 8192;
    const long ka1 = mapk<1>((long)(t + 1) * 64, 9);
    const long kb1 = mapk<2>((long)(t + 1) * 64, 9);
    const long ka2 = mapk<1>((long)(t + 2) * 64, 9);

    // phase 0
#pragma unroll
    for (int r = 0; r < 4; ++r)
#pragma unroll
      for (int kk = 0; kk < 2; ++kk) {
        int lrow = r * 16 + l15;
        int off = (lrow << 7) + (((kk << 6) + kgb) ^ ((lrow & 7) << 4));
        afr[r][kk] = *(const bf16x8*)((const char*)Ah + off);
      }
#pragma unroll
    for (int c = 0; c < 2; ++c)
#pragma unroll
      for (int kk = 0; kk < 2; ++kk) {
        int lrow = (wn & 1) * 64 + c * 16 + l15;
        int off = (lrow << 7) + (((kk << 6) + kgb) ^ ((lrow & 7) << 4));
        bfr[0][c][kk] = *(const bf16x8*)((const char*)Bh + off);
      }
    if (t + 1 < NT) stage_half8(A, LDA, rowBase, ka1, 1, bufn + 1 * 8192, tid);
    PH_PRE();
#pragma unroll
    for (int r = 0; r < 4; ++r)
#pragma unroll
      for (int c = 0; c < 2; ++c)
#pragma unroll
        for (int kk = 0; kk < 2; ++kk)
          acc[r][c] = __builtin_amdgcn_mfma_f32_16x16x32_bf16(
              afr[r][kk], bfr[0][c][kk], acc[r][c], 0, 0, 0);
    PH_POST();

    // phase 1
#pragma unroll
    for (int c = 0; c < 2; ++c)
#pragma unroll
      for (int kk = 0; kk < 2; ++kk) {
        int lrow = (wn & 1) * 64 + 32 + c * 16 + l15;
        int off = (lrow << 7) + (((kk << 6) + kgb) ^ ((lrow & 7) << 4));
        bfr[1][c][kk] = *(const bf16x8*)((const char*)Bh + off);
      }
    if (t + 1 < NT) stage_half8(B, LDB, colBase, kb1, 0, bufn + 2 * 8192, tid);
    PH_PRE();
#pragma unroll
    for (int r = 0; r < 4; ++r)
#pragma unroll
      for (int c = 0; c < 2; ++c)
#pragma unroll
        for (int kk = 0; kk < 2; ++kk)
          acc[r][2 + c] = __builtin_amdgcn_mfma_f32_16x16x32_bf16(
              afr[r][kk], bfr[1][c][kk], acc[r][2 + c], 0, 0, 0);
    PH_POST();

    // phase 2
#pragma unroll
    for (int r = 0; r < 4; ++r)
#pragma unroll
      for (int kk = 0; kk < 2; ++kk) {
        int lrow = 64 + r * 16 + l15;
        int off = (lrow << 7) + (((kk << 6) + kgb) ^ ((lrow & 7) << 4));
        afr[r][kk] = *(const bf16x8*)((const char*)Ah + off);
      }
    if (t + 1 < NT) stage_half8(B, LDB, colBase, kb1, 1, bufn + 3 * 8192, tid);
    PH_PRE();
#pragma unroll
    for (int r = 0; r < 4; ++r)
#pragma unroll
      for (int c = 0; c < 2; ++c)
#pragma unroll
        for (int kk = 0; kk < 2; ++kk)
          acc[4 + r][c] = __builtin_amdgcn_mfma_f32_16x16x32_bf16(
              afr[r][kk], bfr[0][c][kk], acc[4 + r][c], 0, 0, 0);
    PH_POST();

    // phase 3
    if (t + 2 < NT) stage_half8(A, LDA, rowBase, ka2, 0, bufc + 0 * 8192, tid);
    __builtin_amdgcn_s_barrier();
    __builtin_amdgcn_s_setprio(1);
#pragma unroll
    for (int r = 0; r < 4; ++r)
#pragma unroll
      for (int c = 0; c < 2; ++c)
#pragma unroll
        for (int kk = 0; kk < 2; ++kk)
          acc[4 + r][2 + c] = __builtin_amdgcn_mfma_f32_16x16x32_bf16(
              afr[r][kk], bfr[1][c][kk], acc[4 + r][2 + c], 0, 0, 0);
    __builtin_amdgcn_s_setprio(0);
    if (t < NT - 2) { asm volatile("s_waitcnt vmcnt(2)" ::: "memory"); }
    else            { asm volatile("s_waitcnt vmcnt(0)" ::: "memory"); }
    __builtin_amdgcn_s_barrier();
    __builtin_amdgcn_sched_barrier(0);
  }

  // epilogue: exp + ra + store + fused column partial sums
  __syncthreads();
  float* cs = (float*)lds8;
  float csum[4] = {0.f, 0.f, 0.f, 0.f};
#pragma unroll
  for (int qr = 0; qr < 2; ++qr)
#pragma unroll
    for (int r = 0; r < 4; ++r) {
      long row0 = rowBase + wm * 128 + qr * 64 + r * 16 + ((lane >> 4) << 2);
      float4 ra4 = *(const float4*)(ra + (long)z * M + row0);
#pragma unroll
      for (int cf = 0; cf < 4; ++cf) {
        long col = colBase + wn * 64 + cf * 16 + l15;
        f32x4 v4 = acc[qr * 4 + r][cf];
        float rr[4] = {ra4.x, ra4.y, ra4.z, ra4.w};
#pragma unroll
        for (int e = 0; e < 4; ++e) {
          float v = __expf(v4[e] + rr[e]);
          C[(row0 + e) * (long)N + col] = (bf16_t)v;
          csum[cf] += v;
        }
      }
    }
#pragma unroll
  for (int cf = 0; cf < 4; ++cf) {
    float s = csum[cf];
    s += __shfl_xor(s, 16);
    s += __shfl_xor(s, 32);
    if (lane < 16) cs[wm * 256 + wn * 64 + cf * 16 + lane] = s;
  }
  __syncthreads();
  if (tid < 256)
    part[((long)by * gridDim.z + z) * N + colBase + tid] = cs[tid] + cs[256 + tid];
}

// ------------------------------------------------------------------
// m97-structure GEMM, tile TM x 128 (TM = 128: 4 waves 2x2 of 64x64;
// TM = 64: 4 waves 1x4 of 64x32 -> doubles grid for occupancy).
// Runtime outm (0: (acc+bias)*scale, 2: h/l split). Second param set
// selected for z >= zSplit.
// ------------------------------------------------------------------
template <typename OutT, int AMAP, int BMAP, int TM>
__global__ __launch_bounds__(256) void gemm_bt(
    const bf16_t* __restrict__ A, const bf16_t* __restrict__ B,
    OutT* __restrict__ C, const float* __restrict__ bias,
    float scale, int M, int N, int K, long lda, long ldb,
    long sA, long sB, long sC, long kz, int sshift, int outm,
    const bf16_t* __restrict__ A2, const bf16_t* __restrict__ B2,
    OutT* __restrict__ C2, const float* __restrict__ bias2,
    int K2, long lda2, long ldb2, int outm2, int zSplit)
{
  constexpr int WN = (TM == 128) ? 2 : 4;   // waves along N
  constexpr int NR = 8 / WN;                // 16-col frags per wave
  constexpr int AITER = TM / 32;            // staging iters for A
  __shared__ __align__(16) bf16_t As[TM * 64];
  __shared__ __align__(16) bf16_t Bs[128 * 64];
  int z = blockIdx.z;
  if (zSplit > 0 && z >= zSplit) {
    A = A2; B = B2; C = C2; bias = bias2;
    K = K2; lda = lda2; ldb = ldb2; outm = outm2;
    z -= zSplit;
  }
  A += (long)z * sA; B += (long)z * sB; C += (long)z * sC;

  const int gx = gridDim.x;
  const int nwg = gx * gridDim.y;
  const int id = blockIdx.y * gx + blockIdx.x;
  const int qq = nwg >> 3, rr = nwg & 7;
  const int xcd = id & 7, jj = id >> 3;
  const int swz = (xcd < rr ? xcd * (qq + 1) : rr * (qq + 1) + (xcd - rr) * qq) + jj;
  const int bx = swz % gx, by = swz / gx;

  const int tid  = threadIdx.x;
  const int lane = tid & 63;
  const int wid  = tid >> 6;
  const int wr = (wid / WN) * 64;
  const int wc = (wid % WN) * (128 / WN);
  const long rowBase = (long)by * TM;
  const long colBase = (long)bx * 128;

  f32x4 acc[4][NR] = {};

  int srow[4], scol[4];
#pragma unroll
  for (int i = 0; i < 4; ++i) {
    int li = i * 256 + tid;
    int row = li >> 3;
    int inner = (li & 7) << 4;
    int src = inner ^ ((row & 7) << 4);
    srow[i] = row;
    scol[i] = src >> 1;
  }

  for (int k0 = 0; k0 < K; k0 += 64) {
    const long k0L = kz * z + k0;
    const long ka = mapk<AMAP>(k0L, sshift);
    const long kb = mapk<BMAP>(k0L, sshift);
    __syncthreads();
#pragma unroll
    for (int i = 0; i < AITER; ++i) {
      int li = i * 256 + tid;
      gload_lds16(A + (rowBase + srow[i]) * lda + ka + scol[i], (char*)As + li * 16);
    }
#pragma unroll
    for (int i = 0; i < 4; ++i) {
      int li = i * 256 + tid;
      gload_lds16(B + (colBase + srow[i]) * ldb + kb + scol[i], (char*)Bs + li * 16);
    }
    __syncthreads();
#pragma unroll
    for (int kk = 0; kk < 64; kk += 32) {
      const int kbyte = (kk + ((lane >> 4) << 3)) << 1;
      bf16x8 af[4], bfr[NR];
#pragma unroll
      for (int m = 0; m < 4; ++m) {
        int row = wr + m * 16 + (lane & 15);
        int off = (row << 7) + (kbyte ^ ((row & 7) << 4));
        af[m] = *(const bf16x8*)((const char*)As + off);
      }
#pragma unroll
      for (int n = 0; n < NR; ++n) {
        int row = wc + n * 16 + (lane & 15);
        int off = (row << 7) + (kbyte ^ ((row & 7) << 4));
        bfr[n] = *(const bf16x8*)((const char*)Bs + off);
      }
#pragma unroll
      for (int m = 0; m < 4; ++m)
#pragma unroll
        for (int n = 0; n < NR; ++n)
          acc[m][n] = __builtin_amdgcn_mfma_f32_16x16x32_bf16(af[m], bfr[n], acc[m][n], 0, 0, 0);
    }
  }

  if (outm == 2) {
#pragma unroll
    for (int n = 0; n < NR; ++n) {
      const long col = colBase + wc + n * 16 + (lane & 15);
#pragma unroll
      for (int m = 0; m < 4; ++m) {
#pragma unroll
        for (int e = 0; e < 4; ++e) {
          const long row = rowBase + wr + m * 16 + (lane >> 4) * 4 + e;
          float v = acc[m][n][e] * scale;
          bf16_t h = (bf16_t)v;
          bf16_t l = (bf16_t)(v - (float)h);
          C[row * (2L * N) + col] = (OutT)h;
          C[row * (2L * N) + N + col] = (OutT)l;
        }
      }
    }
  } else {
#pragma unroll
    for (int n = 0; n < NR; ++n) {
      const long col = colBase + wc + n * 16 + (lane & 15);
      const float bv_ = bias ? bias[col] : 0.0f;
#pragma unroll
      for (int m = 0; m < 4; ++m) {
#pragma unroll
        for (int e = 0; e < 4; ++e) {
          const long row = rowBase + wr + m * 16 + (lane >> 4) * 4 + e;
          C[row * (long)N + col] = (OutT)((acc[m][n][e] + bv_) * scale);
        }
      }
    }
  }
}

// merged input/weight prep, 7 y-planes:
// y0 q->qcat (h|l), y1 k->kcat (h|l), y2 v->vbf (cast),
// y3 Wk->GA, y4 Wq->GB, y5 Wv->WvS (h|l), y6 Wo->WoS (transpose h|l, 2 tiles/blk)
__global__ void splitAll(const float* __restrict__ q, const float* __restrict__ k,
                         const float* __restrict__ v, const float* __restrict__ Wk,
                         const float* __restrict__ Wq, const float* __restrict__ Wv,
                         const float* __restrict__ Wo,
                         bf16_t* __restrict__ qcat, bf16_t* __restrict__ kcat,
                         bf16_t* __restrict__ vbf, bf16_t* __restrict__ GA,
                         bf16_t* __restrict__ GB, bf16_t* __restrict__ WvS,
                         bf16_t* __restrict__ WoS) {
  __shared__ float tile[32][33];
  const int y = blockIdx.y;
  if (y < 6) {
    const float* in; bf16_t* out; long n; int cshift; bool castOnly = false;
    if      (y == 0) { in = q;  out = qcat; n = NROW * HID; cshift = 9; }
    else if (y == 1) { in = k;  out = kcat; n = NROW * HID; cshift = 9; }
    else if (y == 2) { in = v;  out = vbf;  n = NROW * HID; cshift = 9; castOnly = true; }
    else if (y == 3) { in = Wk; out = GA;  n = (long)HID * PROJ; cshift = 12; }
    else if (y == 4) { in = Wq; out = GB;  n = (long)HID * PROJ; cshift = 12; }
    else             { in = Wv; out = WvS; n = (long)HID * PROJ; cshift = 12; }
    long C = 1L << cshift;
    long i0 = ((long)blockIdx.x * blockDim.x + threadIdx.x) * 4;
    long stride = (long)gridDim.x * blockDim.x * 4;
    for (long i = i0; i < n; i += stride) {
      float4 f = *(const float4*)(in + i);
      union { ushort4 u; bf16_t h[4]; } H, L;
      float fv[4] = {f.x, f.y, f.z, f.w};
#pragma unroll
      for (int j = 0; j < 4; ++j) {
        bf16_t h = (bf16_t)fv[j];
        H.h[j] = h;
        L.h[j] = (bf16_t)(fv[j] - (float)h);
      }
      if (castOnly) {
        *(ushort4*)(out + i) = H.u;
      } else {
        long r = i >> cshift, c = i & (C - 1);
        *(ushort4*)(out + r * 2 * C + c) = H.u;
        *(ushort4*)(out + r * 2 * C + C + c) = L.u;
      }
    }
  } else {
    // Wo [PROJ, HID] -> WoS [HID, 2*PROJ]; 2048 32x32 tiles, 2 per block
    int tx = threadIdx.x & 31, ty = threadIdx.x >> 5;
    for (int tt = 0; tt < 2; ++tt) {
      int bx = blockIdx.x * 2 + tt;
      int c0 = (bx & 15) * 32, r0 = (bx >> 4) * 32;
      __syncthreads();
#pragma unroll
      for (int i = 0; i < 32; i += 8)
        tile[ty + i][tx] = Wo[(long)(r0 + ty + i) * HID + (c0 + tx)];
      __syncthreads();
#pragma unroll
      for (int i = 0; i < 32; i += 8) {
        float x = tile[tx][ty + i];
        bf16_t h = (bf16_t)x;
        bf16_t l = (bf16_t)(x - (float)h);
        long o = (long)(c0 + ty + i) * 2 * PROJ + (r0 + tx);
        WoS[o] = h;
        WoS[o + PROJ] = l;
      }
    }
  }
}

// merged: y=0 -> reduce partials into Gtcat (h|l, scaled) + WvoTb (bf16);
// y=1 wqbk[bx]=Wq[bx,:].bk; y=2 bvo[bx]=WoT[bx,:].bv; y=3 cdot=bq.bk
__global__ void reduce2rank1(const float* __restrict__ gp, const float* __restrict__ wp,
                             bf16_t* __restrict__ Gtcat, bf16_t* __restrict__ WvoTb,
                             const float* __restrict__ Wq, const float* __restrict__ bk,
                             const float* __restrict__ bq,
                             const bf16_t* __restrict__ WoS, const float* __restrict__ bv,
                             float* __restrict__ wqbk, float* __restrict__ bvo,
                             float* __restrict__ cdot,
                             float scale, int nElem, int nP1, int nP2) {
  __shared__ float red[256];
  const int y = blockIdx.y, bx = blockIdx.x, t = threadIdx.x;
  if (y == 0) {
    int i = bx * 256 + t;
    if (i < nElem) {
      float a = 0.f, b = 0.f;
      for (int p = 0; p < nP1; ++p) a += gp[(long)p * nElem + i];
      for (int p = 0; p < nP2; ++p) b += wp[(long)p * nElem + i];
      a *= scale;
      int r = i >> 9, c = i & 511;
      bf16_t h = (bf16_t)a;
      Gtcat[(long)r * 1024 + c] = h;
      Gtcat[(long)r * 1024 + 512 + c] = (bf16_t)(a - (float)h);
      WvoTb[i] = (bf16_t)b;
    }
    return;
  }
  if (bx >= HID || (y == 3 && bx != 0)) return;
  float s = 0.f;
  if (y == 1) {
    for (int j = t; j < PROJ; j += 256) s += Wq[(long)bx * PROJ + j] * bk[j];
  } else if (y == 2) {
    const bf16_t* row = WoS + (long)bx * 2 * PROJ;
    for (int j = t; j < PROJ; j += 256)
      s += ((float)row[j] + (float)row[PROJ + j]) * bv[j];
  } else {
    for (int j = t; j < PROJ; j += 256) s += bq[j] * bk[j];
  }
  red[t] = s; __syncthreads();
  for (int w = 128; w > 0; w >>= 1) {
    if (t < w) red[t] += red[t + w];
    __syncthreads();
  }
  if (t == 0) {
    if (y == 1) wqbk[bx] = red[0];
    else if (y == 2) bvo[bx] = red[0];
    else *cdot = red[0];
  }
}

// rav[r] = SCALE*(q[r].wqbk + cdot)
__global__ void rowdot_rav(const float* __restrict__ q, const float* __restrict__ wqbk,
                           const float* __restrict__ cdot, float* __restrict__ rav) {
  __shared__ float red[256];
  int r = blockIdx.x, t = threadIdx.x;
  float s = 0.f;
  for (int j = t; j < HID; j += 256) s += q[(long)r * HID + j] * wqbk[j];
  red[t] = s; __syncthreads();
  for (int w = 128; w > 0; w >>= 1) {
    if (t < w) red[t] += red[t + w];
    __syncthreads();
  }
  if (t == 0) rav[r] = SCALE * (red[0] + *cdot);
}

__device__ __forceinline__ float bf2f(unsigned short u) {
  union { unsigned u32; float f; } x; x.u32 = ((unsigned)u) << 16; return x.f;
}

// bf16 [R,C] -> bf16 [C,R], scaling input row r by 1/csum[r] where
// csum is reduced inline from the 8 column-sum partials.
__global__ void transpose_scale_cs(const bf16_t* __restrict__ in,
                                   const float* __restrict__ part,
                                   bf16_t* __restrict__ out, int R, int C,
                                   long sIn, long sOut, int nParts) {
  __shared__ bf16_t tile[64][68];
  __shared__ float rcL[64];
  int z = blockIdx.z;
  const bf16_t* ip = in + (long)z * sIn;
  bf16_t* op = out + (long)z * sOut;
  int c0 = blockIdx.x * 64, r0 = blockIdx.y * 64;
  if (threadIdx.x < 64) {
    int m = r0 + threadIdx.x;
    float s = 0.f;
    for (int p = 0; p < nParts; ++p)
      s += part[((long)p * gridDim.z + z) * R + m];
    rcL[threadIdx.x] = 1.0f / s;
  }
  __syncthreads();
#pragma unroll
  for (int i = 0; i < 4; ++i) {
    int chunk = i * 256 + threadIdx.x;
    int r = chunk >> 4, c4 = (chunk & 15) << 2;
    float s = rcL[r];
    ushort4 uv = *(const ushort4*)(ip + (long)(r0 + r) * C + (c0 + c4));
    tile[r][c4 + 0] = (bf16_t)(bf2f(uv.x) * s);
    tile[r][c4 + 1] = (bf16_t)(bf2f(uv.y) * s);
    tile[r][c4 + 2] = (bf16_t)(bf2f(uv.z) * s);
    tile[r][c4 + 3] = (bf16_t)(bf2f(uv.w) * s);
  }
  __syncthreads();
#pragma unroll
  for (int i = 0; i < 4; ++i) {
    int chunk = i * 256 + threadIdx.x;
    int oc = chunk >> 4, or4 = (chunk & 15) << 2;
    union { ushort4 u; bf16_t h[4]; } o;
    o.h[0] = tile[or4 + 0][oc];
    o.h[1] = tile[or4 + 1][oc];
    o.h[2] = tile[or4 + 2][oc];
    o.h[3] = tile[or4 + 3][oc];
    *(ushort4*)(op + (long)(c0 + oc) * R + (r0 + or4)) = o.u;
  }
}

extern "C" void kernel_launch(void* const* d_in, const int* in_sizes, int n_in,
                              void* d_out, int out_size, void* d_ws, size_t ws_size,
                              hipStream_t stream)
{
  (void)in_sizes; (void)n_in; (void)out_size; (void)ws_size;
  const float* q  = (const float*)d_in[0];
  const float* k  = (const float*)d_in[1];
  const float* v  = (const float*)d_in[2];
  const float* Wq = (const float*)d_in[3];
  const float* bq = (const float*)d_in[4];
  const float* Wk = (const float*)d_in[5];
  const float* bk = (const float*)d_in[6];
  const float* Wv = (const float*)d_in[7];
  const float* bv = (const float*)d_in[8];
  const float* Wo = (const float*)d_in[9];
  const float* bo = (const float*)d_in[10];
  float* out = (float*)d_out;

  char* ws = (char*)d_ws;
  const size_t MB = 1u << 20;
  bf16_t* qcat  = (bf16_t*)(ws);              // [0,16)   [8192,1024] (h|l)
  bf16_t* kcat  = (bf16_t*)(ws + 16 * MB);    // [16,32)
  bf16_t* GA    = (bf16_t*)(ws + 32 * MB);    // [32,40)  Wk  [512,8192]
  bf16_t* GB    = (bf16_t*)(ws + 40 * MB);    // [40,48)  Wq
  bf16_t* WoS   = (bf16_t*)(ws + 48 * MB);    // [48,56)  Wo^T [512,8192]
  bf16_t* WvS   = (bf16_t*)(ws + 56 * MB);    // [56,64)  Wv
  float*  Gpart = (float*)(ws + 64 * MB);     // [64,80)  16x[512,512]
  float*  WvoTp = (float*)(ws + 80 * MB);     // [80,96)  6x[512,512]
  bf16_t* Gtcat = (bf16_t*)(ws + 97 * MB);    // [97,98)  [512,1024]
  bf16_t* WvoTb = (bf16_t*)(ws + 98 * MB);    // [98,98.5)
  float*  bvo   = (float*)(ws + 99 * MB);
  float*  wqbk  = (float*)(ws + 99 * MB + 16 * 1024);
  float*  cdot  = (float*)(ws + 99 * MB + 48 * 1024);
  float*  rav   = (float*)(ws + 99 * MB + 64 * 1024);   // 32 KB
  float*  part  = (float*)(ws + 99 * MB + 256 * 1024);  // 256 KB
  bf16_t* tcat  = (bf16_t*)(ws + 100 * MB);   // [100,116) [8192,1024]
  bf16_t* vbf   = (bf16_t*)(ws + 116 * MB);   // [116,124)
  bf16_t* vo    = (bf16_t*)(ws + 124 * MB);   // [124,132) [8192,512]
  bf16_t* vosT  = (bf16_t*)(ws + 132 * MB);   // [132,140) [B][512,2048]
  bf16_t* P     = (bf16_t*)(ws + 140 * MB);   // [140,172) [B][2048,2048]

  // all input/weight prep in one dispatch
  splitAll<<<dim3(1024, 7), 256, 0, stream>>>(q, k, v, Wk, Wq, Wv, Wo,
      qcat, kcat, vbf, GA, GB, WvS, WoS);

  // merged weight GEMM: z<16 -> Gt partials (3-term); z>=16 -> WvoT (h*h)
  gemm_bt<float, 1, 2, 128><<<dim3(4, 4, 22), 256, 0, stream>>>(GA, GB, Gpart,
      nullptr, 1.0f, HID, HID, 768, 2L * PROJ, 2L * PROJ,
      0, 0, (long)HID * HID, 768, 12, 0,
      WoS, WvS, WvoTp, nullptr, 768, 2L * PROJ, 2L * PROJ, 0, 16);
  // reduce partials + rank-1 bias prep, one dispatch
  reduce2rank1<<<dim3(1024, 4), 256, 0, stream>>>(Gpart, WvoTp, Gtcat, WvoTb,
      Wq, bk, bq, WoS, bv, wqbk, bvo, cdot, SCALE, HID * HID, 16, 6);
  rowdot_rav<<<(int)NROW, 256, 0, stream>>>(q, wqbk, cdot, rav);

  // merged: z=0 t = q.Gt^T (K=1536, h/l split out); z=1 vo = v.Wvo + bvo
  gemm_bt<bf16_t, 1, 2, 128><<<dim3(4, 64, 2), 256, 0, stream>>>(qcat, Gtcat, tcat,
      nullptr, 1.0f, (int)NROW, HID, 1536, 1024, 1024, 0, 0, 0, 0, 9, 2,
      vbf, WvoTb, vo, bvo, HID, HID, HID, 0, 1);

  // P = exp(t.k^T + ra) — 8-phase 256^2, fused col partial sums
  gemm8exp<<<dim3(8, 8, BSZ), 512, 0, stream>>>(tcat, kcat, P, rav, part);

  // vosT[z][d,m] = vo[z][m,d] / csum[z][m]  (csum reduced inline from part)
  transpose_scale_cs<<<dim3(HID / 64, SEQ / 64, BSZ), 256, 0, stream>>>(
      vo, part, vosT, SEQ, HID, (long)SEQ * HID, (long)HID * SEQ, 8);

  // out = P.vosT^T + bo  (64x128 tile -> 512 blocks, 2/CU)
  gemm_bt<float, 0, 0, 64><<<dim3(4, 32, BSZ), 256, 0, stream>>>(P, vosT, out,
      bo, 1.0f, SEQ, HID, SEQ, SEQ, SEQ,
      (long)SEQ * SEQ, (long)HID * SEQ, (long)SEQ * HID, 0, 0, 0,
      nullptr, nullptr, nullptr, nullptr, 0, 0, 0, 0, 0);
}